// Round 1
// baseline (2443.390 us; speedup 1.0000x reference)
//
#include <hip/hip_runtime.h>
#include <math.h>

#define B_SZ 4
#define SEQ 2048
#define DM 256
#define DI 512
#define DS 16
#define DTR 16
#define NH 4
#define HD 64
#define T_TOK (B_SZ*SEQ)   // 8192

__device__ __forceinline__ float sigmoidf_(float x){ return 1.f/(1.f+__expf(-x)); }

// ---------------- LayerNorm: one wave per token ----------------
__global__ __launch_bounds__(256) void ln_kernel(const float* __restrict__ x,
    const float* __restrict__ g, const float* __restrict__ b,
    float* __restrict__ xn) {
  int wid = threadIdx.x >> 6;
  int lane = threadIdx.x & 63;
  int token = blockIdx.x*4 + wid;
  const float* xr = x + (size_t)token*DM;
  float4 v = *(const float4*)&xr[lane*4];
  float s  = v.x+v.y+v.z+v.w;
  float ss = v.x*v.x+v.y*v.y+v.z*v.z+v.w*v.w;
  for (int m=1;m<64;m<<=1){ s += __shfl_xor(s,m); ss += __shfl_xor(ss,m); }
  float mu  = s * (1.f/DM);
  float var = ss*(1.f/DM) - mu*mu;
  float rs  = rsqrtf(var + 1e-5f);
  float4 gv = *(const float4*)&g[lane*4];
  float4 bv = *(const float4*)&b[lane*4];
  float4 o;
  o.x = (v.x-mu)*rs*gv.x + bv.x;
  o.y = (v.y-mu)*rs*gv.y + bv.y;
  o.z = (v.z-mu)*rs*gv.z + bv.z;
  o.w = (v.w-mu)*rs*gv.w + bv.w;
  *(float4*)&xn[(size_t)token*DM + lane*4] = o;
}

// ---------------- Generic fp32 tiled GEMM: C[M,N] = A[M,K] @ W[K,N] (+bias)(+act) ----------------
// BM=64, BN=64, BK=16, 256 threads, 4x4 per thread. All dims assumed divisible.
#define GBM 64
#define GBN 64
#define GBK 16
template<int ACT>   // 0 = none, 1 = sigmoid
__global__ __launch_bounds__(256) void gemm_k(const float* __restrict__ A, int lda,
    const float* __restrict__ W, int ldw,
    const float* __restrict__ bias,
    float* __restrict__ C, int ldc, int K) {
  __shared__ float As[GBK][GBM+4];
  __shared__ float Ws[GBK][GBN+4];
  int tid = threadIdx.x;
  int m0 = blockIdx.y * GBM;
  int n0 = blockIdx.x * GBN;
  int tx = tid & 15, ty = tid >> 4;
  float acc[4][4] = {};
  for (int k0 = 0; k0 < K; k0 += GBK) {
    {
      int m  = tid >> 2;
      int kq = (tid & 3) * 4;
      float4 av = *(const float4*)&A[(size_t)(m0+m)*lda + k0 + kq];
      As[kq+0][m] = av.x; As[kq+1][m] = av.y; As[kq+2][m] = av.z; As[kq+3][m] = av.w;
      int n  = (tid & 15) * 4;
      int kk = tid >> 4;
      *(float4*)&Ws[kk][n] = *(const float4*)&W[(size_t)(k0+kk)*ldw + n0 + n];
    }
    __syncthreads();
#pragma unroll
    for (int kk = 0; kk < GBK; ++kk) {
      float4 a4 = *(const float4*)&As[kk][ty*4];
      float4 b4 = *(const float4*)&Ws[kk][tx*4];
      float a[4] = {a4.x,a4.y,a4.z,a4.w};
      float b[4] = {b4.x,b4.y,b4.z,b4.w};
#pragma unroll
      for (int i=0;i<4;++i)
#pragma unroll
        for (int j=0;j<4;++j) acc[i][j] += a[i]*b[j];
    }
    __syncthreads();
  }
#pragma unroll
  for (int i=0;i<4;++i) {
#pragma unroll
    for (int j=0;j<4;++j) {
      float v = acc[i][j];
      if (bias) v += bias[n0 + tx*4 + j];
      if (ACT==1) v = sigmoidf_(v);
      C[(size_t)(m0+ty*4+i)*ldc + n0 + tx*4 + j] = v;
    }
  }
}

// ---------------- depthwise conv (k=4) + SiLU ----------------
__global__ __launch_bounds__(256) void conv_kernel(const float* __restrict__ xz,
    const float* __restrict__ cw, const float* __restrict__ cb,
    float* __restrict__ xc) {
  int idx = blockIdx.x*256 + threadIdx.x;  // t*512 + d
  int d = idx & (DI-1);
  int t = idx >> 9;
  int l = t & (SEQ-1);
  float acc = cb[d];
  float w0=cw[d*4+0], w1=cw[d*4+1], w2=cw[d*4+2], w3=cw[d*4+3];
  const float* base = xz + (size_t)t*1024 + d;   // xm region (cols 0..511)
  if (l>=3) acc += base[-3*1024]*w0;
  if (l>=2) acc += base[-2*1024]*w1;
  if (l>=1) acc += base[-1*1024]*w2;
  acc += base[0]*w3;
  xc[idx] = acc * sigmoidf_(acc);
}

// ---------------- x_proj (512->48) + dt = softplus(dbl[:16] @ W_dt + b_dt) ----------------
__global__ __launch_bounds__(256) void xproj_dt_kernel(const float* __restrict__ xc,
    const float* __restrict__ Wx, const float* __restrict__ Wdt,
    const float* __restrict__ bdt, float* __restrict__ dbl, float* __restrict__ dt) {
  __shared__ float sxc[4][DI];
  __shared__ float sdbl[4][48];
  int wid = threadIdx.x>>6, lane = threadIdx.x&63;
  int token = blockIdx.x*4 + wid;
  {
    float4 a = *(const float4*)&xc[(size_t)token*DI + lane*4];
    float4 b = *(const float4*)&xc[(size_t)token*DI + 256 + lane*4];
    *(float4*)&sxc[wid][lane*4]       = a;
    *(float4*)&sxc[wid][256 + lane*4] = b;
  }
  __syncthreads();
  if (lane < 48) {
    float acc = 0.f;
    for (int k=0;k<DI;++k) acc += sxc[wid][k]*Wx[k*48+lane];
    dbl[(size_t)token*48+lane] = acc;
    sdbl[wid][lane] = acc;
  }
  __syncthreads();
#pragma unroll
  for (int r=0;r<8;++r){
    int d = lane + r*64;
    float acc = bdt[d];
#pragma unroll
    for (int k=0;k<DTR;++k) acc += sdbl[wid][k]*Wdt[k*DI+d];
    float sp = (acc > 20.f) ? acc : log1pf(__expf(acc));
    dt[(size_t)token*DI+d] = sp;
  }
}

// ---------------- selective scan: 16 lanes per (b,d) channel ----------------
__global__ __launch_bounds__(256) void scan_kernel(const float* __restrict__ xc,
    const float* __restrict__ dt, const float* __restrict__ dbl,
    const float* __restrict__ A_log, const float* __restrict__ Dp,
    const float* __restrict__ xz, float* __restrict__ ygate) {
  int tid = threadIdx.x;
  int wid = tid>>6, lane = tid&63;
  int c = lane>>4;
  int n = lane&15;
  int ch = wid*4 + c;                 // 0..15 channels per block
  int b  = blockIdx.x >> 5;
  int d  = (blockIdx.x & 31)*16 + ch;
  float An = -__expf(A_log[d*DS + n]);
  float Dd = Dp[d];
  float h = 0.f;
  size_t tok0 = (size_t)b*SEQ;
  for (int t=0;t<SEQ;++t){
    size_t token = tok0 + t;
    float dtv = dt[token*DI + d];
    float xcv = xc[token*DI + d];
    float Bv  = dbl[token*48 + DTR + n];
    float Cv  = dbl[token*48 + DTR + DS + n];
    float dA  = __expf(dtv*An);
    h = dA*h + (dtv*xcv)*Bv;
    float p = h*Cv;
    p += __shfl_xor(p,1);
    p += __shfl_xor(p,2);
    p += __shfl_xor(p,4);
    p += __shfl_xor(p,8);
    if (n==0){
      float y  = p + xcv*Dd;
      float zv = xz[token*1024 + DI + d];
      ygate[token*DI + d] = y * (zv*sigmoidf_(zv));
    }
  }
}

// ---------------- flash attention fp32: 4 lanes/query, 16 q/wave, 32-key tiles ----------------
#define KT 32
__global__ __launch_bounds__(256) void attn_kernel(const float* __restrict__ qkv,
    float* __restrict__ o_out) {
  __shared__ float Ks[KT][HD];
  __shared__ float Vs[KT][HD];
  int bh = blockIdx.y; int b = bh>>2, h = bh&3;
  int tid = threadIdx.x;
  int wv = tid>>6, lane = tid&63;
  int qw = lane>>2, l4 = lane&3;
  int qi = blockIdx.x*64 + wv*16 + qw;
  size_t tokq = (size_t)b*SEQ + qi;
  float qf[16];
#pragma unroll
  for (int i=0;i<4;++i){
    float4 v = *(const float4*)&qkv[tokq*768 + h*HD + l4*16 + i*4];
    qf[i*4+0]=v.x; qf[i*4+1]=v.y; qf[i*4+2]=v.z; qf[i*4+3]=v.w;
  }
  float m = -1e30f, l = 0.f;
  float acc[16] = {};
  for (int kt=0; kt<SEQ/KT; ++kt){
#pragma unroll
    for (int i=0;i<2;++i){
      int f = i*256 + tid;            // 0..511, coalesced per instruction
      int key = f>>4;
      int c4  = (f&15)*4;
      size_t tokk = (size_t)b*SEQ + kt*KT + key;
      *(float4*)&Ks[key][c4] = *(const float4*)&qkv[tokk*768 + 256 + h*HD + c4];
      *(float4*)&Vs[key][c4] = *(const float4*)&qkv[tokk*768 + 512 + h*HD + c4];
    }
    __syncthreads();
    float s[KT];
#pragma unroll
    for (int key=0;key<KT;++key){
      float dotv = 0.f;
#pragma unroll
      for (int i=0;i<4;++i){
        float4 kv = *(const float4*)&Ks[key][l4*16 + i*4];
        dotv += qf[i*4+0]*kv.x + qf[i*4+1]*kv.y + qf[i*4+2]*kv.z + qf[i*4+3]*kv.w;
      }
      dotv += __shfl_xor(dotv,1);
      dotv += __shfl_xor(dotv,2);
      s[key] = dotv*0.125f;
    }
    float tm = s[0];
#pragma unroll
    for (int key=1;key<KT;++key) tm = fmaxf(tm, s[key]);
    float mn = fmaxf(m, tm);
    float sc = __expf(m - mn);
    l *= sc;
#pragma unroll
    for (int j=0;j<16;++j) acc[j]*=sc;
#pragma unroll
    for (int key=0;key<KT;++key){
      float p = __expf(s[key]-mn);
      l += p;
#pragma unroll
      for (int i=0;i<4;++i){
        float4 vv = *(const float4*)&Vs[key][l4*16+i*4];
        acc[i*4+0] += p*vv.x; acc[i*4+1] += p*vv.y; acc[i*4+2] += p*vv.z; acc[i*4+3] += p*vv.w;
      }
    }
    m = mn;
    __syncthreads();
  }
  float inv = 1.f/l;
#pragma unroll
  for (int i=0;i<4;++i){
    float4 ov; ov.x=acc[i*4+0]*inv; ov.y=acc[i*4+1]*inv; ov.z=acc[i*4+2]*inv; ov.w=acc[i*4+3]*inv;
    *(float4*)&o_out[tokq*DM + h*HD + l4*16 + i*4] = ov;
  }
}

// ---------------- final: out = x + g*ssm + (1-g)*attn ----------------
__global__ __launch_bounds__(256) void final_kernel(const float* __restrict__ x,
    const float* __restrict__ cat, const float* __restrict__ gate,
    float* __restrict__ out) {
  int idx = blockIdx.x*256 + threadIdx.x;  // over T*64 float4 groups
  int token = idx >> 6;
  int q = (idx & 63)*4;
  float4 g4 = *(const float4*)&gate[(size_t)token*DM + q];
  float4 s4 = *(const float4*)&cat[(size_t)token*512 + q];
  float4 a4 = *(const float4*)&cat[(size_t)token*512 + 256 + q];
  float4 x4 = *(const float4*)&x[(size_t)token*DM + q];
  float4 o;
  o.x = x4.x + g4.x*s4.x + (1.f-g4.x)*a4.x;
  o.y = x4.y + g4.y*s4.y + (1.f-g4.y)*a4.y;
  o.z = x4.z + g4.z*s4.z + (1.f-g4.z)*a4.z;
  o.w = x4.w + g4.w*s4.w + (1.f-g4.w)*a4.w;
  *(float4*)&out[(size_t)token*DM + q] = o;
}

extern "C" void kernel_launch(void* const* d_in, const int* in_sizes, int n_in,
                              void* d_out, int out_size, void* d_ws, size_t ws_size,
                              hipStream_t stream) {
  const float* x      = (const float*)d_in[0];
  const float* ln_g   = (const float*)d_in[1];
  const float* ln_b   = (const float*)d_in[2];
  const float* W_in   = (const float*)d_in[3];
  const float* conv_w = (const float*)d_in[4];
  const float* conv_b = (const float*)d_in[5];
  const float* W_xproj= (const float*)d_in[6];
  const float* W_dt   = (const float*)d_in[7];
  const float* b_dt   = (const float*)d_in[8];
  const float* A_log  = (const float*)d_in[9];
  const float* Dp     = (const float*)d_in[10];
  const float* W_out_m= (const float*)d_in[11];
  const float* W_qkv  = (const float*)d_in[12];
  const float* b_qkv  = (const float*)d_in[13];
  const float* W_o    = (const float*)d_in[14];
  const float* b_o    = (const float*)d_in[15];
  const float* W_gate = (const float*)d_in[16];
  const float* b_gate = (const float*)d_in[17];
  float* out = (float*)d_out;

  float* ws = (float*)d_ws;
  float* xn     = ws;                  // 2,097,152
  float* xz     = xn     + 2097152;    // 8,388,608  (xm | z)
  float* qkv    = xz     + 8388608;    // 6,291,456
  float* xc     = qkv    + 6291456;    // 4,194,304
  float* dblb   = xc     + 4194304;    //   393,216
  float* dtb    = dblb   + 393216;     // 4,194,304
  float* ygate  = dtb    + 4194304;    // 4,194,304
  float* attn_o = ygate  + 4194304;    // 2,097,152
  float* catb   = attn_o + 2097152;    // 4,194,304  (ssm | attn), ldc=512
  float* gateb  = catb   + 4194304;    // 2,097,152

  ln_kernel<<<T_TOK/4, 256, 0, stream>>>(x, ln_g, ln_b, xn);
  gemm_k<0><<<dim3(1024/GBN, T_TOK/GBM), 256, 0, stream>>>(xn, DM, W_in, 1024, nullptr, xz, 1024, DM);
  gemm_k<0><<<dim3(768/GBN,  T_TOK/GBM), 256, 0, stream>>>(xn, DM, W_qkv, 768, b_qkv, qkv, 768, DM);
  conv_kernel<<<T_TOK*DI/256, 256, 0, stream>>>(xz, conv_w, conv_b, xc);
  xproj_dt_kernel<<<T_TOK/4, 256, 0, stream>>>(xc, W_xproj, W_dt, b_dt, dblb, dtb);
  scan_kernel<<<128, 256, 0, stream>>>(xc, dtb, dblb, A_log, Dp, xz, ygate);
  attn_kernel<<<dim3(SEQ/64, B_SZ*NH), 256, 0, stream>>>(qkv, attn_o);
  gemm_k<0><<<dim3(256/GBN, T_TOK/GBM), 256, 0, stream>>>(ygate, DI, W_out_m, DM, nullptr, catb, 512, DI);
  gemm_k<0><<<dim3(256/GBN, T_TOK/GBM), 256, 0, stream>>>(attn_o, DM, W_o, DM, b_o, catb+256, 512, DM);
  gemm_k<1><<<dim3(256/GBN, T_TOK/GBM), 256, 0, stream>>>(catb, 512, W_gate, DM, b_gate, gateb, DM, DI);
  final_kernel<<<T_TOK*64/256, 256, 0, stream>>>(x, catb, gateb, out);
}

// Round 2
// 1092.711 us; speedup vs baseline: 2.2361x; 2.2361x over previous
//
#include <hip/hip_runtime.h>
#include <math.h>

#define B_SZ 4
#define SEQ 2048
#define DM 256
#define DI 512
#define DS 16
#define DTR 16
#define NH 4
#define HD 64
#define T_TOK (B_SZ*SEQ)   // 8192
#define NC 16              // scan time-chunks
#define CHUNK (SEQ/NC)     // 128

__device__ __forceinline__ float sigmoidf_(float x){ return 1.f/(1.f+__expf(-x)); }

// ---------------- LayerNorm: one wave per token ----------------
__global__ __launch_bounds__(256) void ln_kernel(const float* __restrict__ x,
    const float* __restrict__ g, const float* __restrict__ b,
    float* __restrict__ xn) {
  int wid = threadIdx.x >> 6;
  int lane = threadIdx.x & 63;
  int token = blockIdx.x*4 + wid;
  const float* xr = x + (size_t)token*DM;
  float4 v = *(const float4*)&xr[lane*4];
  float s  = v.x+v.y+v.z+v.w;
  float ss = v.x*v.x+v.y*v.y+v.z*v.z+v.w*v.w;
  for (int m=1;m<64;m<<=1){ s += __shfl_xor(s,m); ss += __shfl_xor(ss,m); }
  float mu  = s * (1.f/DM);
  float var = ss*(1.f/DM) - mu*mu;
  float rs  = rsqrtf(var + 1e-5f);
  float4 gv = *(const float4*)&g[lane*4];
  float4 bv = *(const float4*)&b[lane*4];
  float4 o;
  o.x = (v.x-mu)*rs*gv.x + bv.x;
  o.y = (v.y-mu)*rs*gv.y + bv.y;
  o.z = (v.z-mu)*rs*gv.z + bv.z;
  o.w = (v.w-mu)*rs*gv.w + bv.w;
  *(float4*)&xn[(size_t)token*DM + lane*4] = o;
}

// ---------------- Generic fp32 tiled GEMM ----------------
#define GBM 64
#define GBN 64
#define GBK 16
template<int ACT>   // 0 = none, 1 = sigmoid
__global__ __launch_bounds__(256) void gemm_k(const float* __restrict__ A, int lda,
    const float* __restrict__ W, int ldw,
    const float* __restrict__ bias,
    float* __restrict__ C, int ldc, int K) {
  __shared__ float As[GBK][GBM+4];
  __shared__ float Ws[GBK][GBN+4];
  int tid = threadIdx.x;
  int m0 = blockIdx.y * GBM;
  int n0 = blockIdx.x * GBN;
  int tx = tid & 15, ty = tid >> 4;
  float acc[4][4] = {};
  for (int k0 = 0; k0 < K; k0 += GBK) {
    {
      int m  = tid >> 2;
      int kq = (tid & 3) * 4;
      float4 av = *(const float4*)&A[(size_t)(m0+m)*lda + k0 + kq];
      As[kq+0][m] = av.x; As[kq+1][m] = av.y; As[kq+2][m] = av.z; As[kq+3][m] = av.w;
      int n  = (tid & 15) * 4;
      int kk = tid >> 4;
      *(float4*)&Ws[kk][n] = *(const float4*)&W[(size_t)(k0+kk)*ldw + n0 + n];
    }
    __syncthreads();
#pragma unroll
    for (int kk = 0; kk < GBK; ++kk) {
      float4 a4 = *(const float4*)&As[kk][ty*4];
      float4 b4 = *(const float4*)&Ws[kk][tx*4];
      float a[4] = {a4.x,a4.y,a4.z,a4.w};
      float b[4] = {b4.x,b4.y,b4.z,b4.w};
#pragma unroll
      for (int i=0;i<4;++i)
#pragma unroll
        for (int j=0;j<4;++j) acc[i][j] += a[i]*b[j];
    }
    __syncthreads();
  }
#pragma unroll
  for (int i=0;i<4;++i) {
#pragma unroll
    for (int j=0;j<4;++j) {
      float v = acc[i][j];
      if (bias) v += bias[n0 + tx*4 + j];
      if (ACT==1) v = sigmoidf_(v);
      C[(size_t)(m0+ty*4+i)*ldc + n0 + tx*4 + j] = v;
    }
  }
}

// ---------------- depthwise conv (k=4) + SiLU ----------------
__global__ __launch_bounds__(256) void conv_kernel(const float* __restrict__ xz,
    const float* __restrict__ cw, const float* __restrict__ cb,
    float* __restrict__ xc) {
  int idx = blockIdx.x*256 + threadIdx.x;  // t*512 + d
  int d = idx & (DI-1);
  int t = idx >> 9;
  int l = t & (SEQ-1);
  float acc = cb[d];
  float w0=cw[d*4+0], w1=cw[d*4+1], w2=cw[d*4+2], w3=cw[d*4+3];
  const float* base = xz + (size_t)t*1024 + d;   // xm region (cols 0..511)
  if (l>=3) acc += base[-3*1024]*w0;
  if (l>=2) acc += base[-2*1024]*w1;
  if (l>=1) acc += base[-1*1024]*w2;
  acc += base[0]*w3;
  xc[idx] = acc * sigmoidf_(acc);
}

// ---------------- x_proj (512->48) + dt = softplus ----------------
__global__ __launch_bounds__(256) void xproj_dt_kernel(const float* __restrict__ xc,
    const float* __restrict__ Wx, const float* __restrict__ Wdt,
    const float* __restrict__ bdt, float* __restrict__ dbl, float* __restrict__ dt) {
  __shared__ float sxc[4][DI];
  __shared__ float sdbl[4][48];
  int wid = threadIdx.x>>6, lane = threadIdx.x&63;
  int token = blockIdx.x*4 + wid;
  {
    float4 a = *(const float4*)&xc[(size_t)token*DI + lane*4];
    float4 b = *(const float4*)&xc[(size_t)token*DI + 256 + lane*4];
    *(float4*)&sxc[wid][lane*4]       = a;
    *(float4*)&sxc[wid][256 + lane*4] = b;
  }
  __syncthreads();
  if (lane < 48) {
    float acc = 0.f;
    for (int k=0;k<DI;++k) acc += sxc[wid][k]*Wx[k*48+lane];
    dbl[(size_t)token*48+lane] = acc;
    sdbl[wid][lane] = acc;
  }
  __syncthreads();
#pragma unroll
  for (int r=0;r<8;++r){
    int d = lane + r*64;
    float acc = bdt[d];
#pragma unroll
    for (int k=0;k<DTR;++k) acc += sdbl[wid][k]*Wdt[k*DI+d];
    float sp = (acc > 20.f) ? acc : log1pf(__expf(acc));
    dt[(size_t)token*DI+d] = sp;
  }
}

// ---------------- chunked selective scan ----------------
// Wave layout: slot = lane>>4 (4 consecutive d), n = lane&15 (state index).
// Wave id W -> dblk = W & 127, c = (W>>7)&15, b = W>>11.
__global__ __launch_bounds__(256) void scan_pass1(const float* __restrict__ xc,
    const float* __restrict__ dt, const float* __restrict__ dbl,
    const float* __restrict__ A_log, float* __restrict__ Pws, float* __restrict__ Hws) {
  int tid = threadIdx.x;
  int wid = tid>>6, lane = tid&63;
  int slot = lane>>4, n = lane&15;
  int W = blockIdx.x*4 + wid;          // 0..8191
  int dblk = W & 127;
  int c    = (W>>7) & 15;
  int b    = W>>11;
  int d    = dblk*4 + slot;
  float An = -__expf(A_log[d*DS+n]);
  float P = 1.f, h = 0.f;
  size_t tok = (size_t)b*SEQ + c*CHUNK;
  for (int t=0;t<CHUNK;++t,++tok){
    float dtv = dt[tok*DI+d];
    float xcv = xc[tok*DI+d];
    float Bv  = dbl[tok*48 + DTR + n];
    float dA  = __expf(dtv*An);
    P *= dA;
    h = dA*h + (dtv*xcv)*Bv;
  }
  size_t idx = ((size_t)(b*NC+c)*DI + d)*DS + n;
  Pws[idx] = P; Hws[idx] = h;
}

__global__ __launch_bounds__(256) void scan_combine(const float* __restrict__ Pws,
    const float* __restrict__ Hws, float* __restrict__ H0ws) {
  int gid = blockIdx.x*256 + threadIdx.x;  // 0..32767 = (b, d*DS+n)
  int b  = gid >> 13;
  int dn = gid & 8191;
  float h0 = 0.f;
#pragma unroll
  for (int c=0;c<NC;++c){
    size_t idx = ((size_t)(b*NC+c)<<13) + dn;
    H0ws[idx] = h0;
    h0 = Pws[idx]*h0 + Hws[idx];
  }
}

__global__ __launch_bounds__(256) void scan_pass2(const float* __restrict__ xc,
    const float* __restrict__ dt, const float* __restrict__ dbl,
    const float* __restrict__ A_log, const float* __restrict__ Dp,
    const float* __restrict__ xz, const float* __restrict__ H0ws,
    float* __restrict__ ygate) {
  int tid = threadIdx.x;
  int wid = tid>>6, lane = tid&63;
  int slot = lane>>4, n = lane&15;
  int W = blockIdx.x*4 + wid;
  int dblk = W & 127;
  int c    = (W>>7) & 15;
  int b    = W>>11;
  int d    = dblk*4 + slot;
  float An = -__expf(A_log[d*DS+n]);
  float Dd = Dp[d];
  size_t idx = ((size_t)(b*NC+c)*DI + d)*DS + n;
  float h = H0ws[idx];
  size_t tok = (size_t)b*SEQ + c*CHUNK;
  for (int t=0;t<CHUNK;++t,++tok){
    float dtv = dt[tok*DI+d];
    float xcv = xc[tok*DI+d];
    float Bv  = dbl[tok*48 + DTR + n];
    float Cv  = dbl[tok*48 + DTR + DS + n];
    float dA  = __expf(dtv*An);
    h = dA*h + (dtv*xcv)*Bv;
    float p = h*Cv;
    p += __shfl_xor(p,1);
    p += __shfl_xor(p,2);
    p += __shfl_xor(p,4);
    p += __shfl_xor(p,8);
    if (n==0){
      float y  = p + xcv*Dd;
      float zv = xz[tok*1024 + DI + d];
      ygate[tok*DI + d] = y * (zv*sigmoidf_(zv));
    }
  }
}

// ---------------- flash attention fp32 ----------------
#define KT 32
__global__ __launch_bounds__(256) void attn_kernel(const float* __restrict__ qkv,
    float* __restrict__ o_out) {
  __shared__ float Ks[KT][HD];
  __shared__ float Vs[KT][HD];
  int bh = blockIdx.y; int b = bh>>2, h = bh&3;
  int tid = threadIdx.x;
  int wv = tid>>6, lane = tid&63;
  int qw = lane>>2, l4 = lane&3;
  int qi = blockIdx.x*64 + wv*16 + qw;
  size_t tokq = (size_t)b*SEQ + qi;
  float qf[16];
#pragma unroll
  for (int i=0;i<4;++i){
    float4 v = *(const float4*)&qkv[tokq*768 + h*HD + l4*16 + i*4];
    qf[i*4+0]=v.x; qf[i*4+1]=v.y; qf[i*4+2]=v.z; qf[i*4+3]=v.w;
  }
  float m = -1e30f, l = 0.f;
  float acc[16] = {};
  for (int kt=0; kt<SEQ/KT; ++kt){
#pragma unroll
    for (int i=0;i<2;++i){
      int f = i*256 + tid;
      int key = f>>4;
      int c4  = (f&15)*4;
      size_t tokk = (size_t)b*SEQ + kt*KT + key;
      *(float4*)&Ks[key][c4] = *(const float4*)&qkv[tokk*768 + 256 + h*HD + c4];
      *(float4*)&Vs[key][c4] = *(const float4*)&qkv[tokk*768 + 512 + h*HD + c4];
    }
    __syncthreads();
    float s[KT];
#pragma unroll
    for (int key=0;key<KT;++key){
      float dotv = 0.f;
#pragma unroll
      for (int i=0;i<4;++i){
        float4 kv = *(const float4*)&Ks[key][l4*16 + i*4];
        dotv += qf[i*4+0]*kv.x + qf[i*4+1]*kv.y + qf[i*4+2]*kv.z + qf[i*4+3]*kv.w;
      }
      dotv += __shfl_xor(dotv,1);
      dotv += __shfl_xor(dotv,2);
      s[key] = dotv*0.125f;
    }
    float tm = s[0];
#pragma unroll
    for (int key=1;key<KT;++key) tm = fmaxf(tm, s[key]);
    float mn = fmaxf(m, tm);
    float sc = __expf(m - mn);
    l *= sc;
#pragma unroll
    for (int j=0;j<16;++j) acc[j]*=sc;
#pragma unroll
    for (int key=0;key<KT;++key){
      float p = __expf(s[key]-mn);
      l += p;
#pragma unroll
      for (int i=0;i<4;++i){
        float4 vv = *(const float4*)&Vs[key][l4*16+i*4];
        acc[i*4+0] += p*vv.x; acc[i*4+1] += p*vv.y; acc[i*4+2] += p*vv.z; acc[i*4+3] += p*vv.w;
      }
    }
    m = mn;
    __syncthreads();
  }
  float inv = 1.f/l;
#pragma unroll
  for (int i=0;i<4;++i){
    float4 ov; ov.x=acc[i*4+0]*inv; ov.y=acc[i*4+1]*inv; ov.z=acc[i*4+2]*inv; ov.w=acc[i*4+3]*inv;
    *(float4*)&o_out[tokq*DM + h*HD + l4*16 + i*4] = ov;
  }
}

// ---------------- final: out = x + g*ssm + (1-g)*attn ----------------
__global__ __launch_bounds__(256) void final_kernel(const float* __restrict__ x,
    const float* __restrict__ cat, const float* __restrict__ gate,
    float* __restrict__ out) {
  int idx = blockIdx.x*256 + threadIdx.x;
  int token = idx >> 6;
  int q = (idx & 63)*4;
  float4 g4 = *(const float4*)&gate[(size_t)token*DM + q];
  float4 s4 = *(const float4*)&cat[(size_t)token*512 + q];
  float4 a4 = *(const float4*)&cat[(size_t)token*512 + 256 + q];
  float4 x4 = *(const float4*)&x[(size_t)token*DM + q];
  float4 o;
  o.x = x4.x + g4.x*s4.x + (1.f-g4.x)*a4.x;
  o.y = x4.y + g4.y*s4.y + (1.f-g4.y)*a4.y;
  o.z = x4.z + g4.z*s4.z + (1.f-g4.z)*a4.z;
  o.w = x4.w + g4.w*s4.w + (1.f-g4.w)*a4.w;
  *(float4*)&out[(size_t)token*DM + q] = o;
}

extern "C" void kernel_launch(void* const* d_in, const int* in_sizes, int n_in,
                              void* d_out, int out_size, void* d_ws, size_t ws_size,
                              hipStream_t stream) {
  const float* x      = (const float*)d_in[0];
  const float* ln_g   = (const float*)d_in[1];
  const float* ln_b   = (const float*)d_in[2];
  const float* W_in   = (const float*)d_in[3];
  const float* conv_w = (const float*)d_in[4];
  const float* conv_b = (const float*)d_in[5];
  const float* W_xproj= (const float*)d_in[6];
  const float* W_dt   = (const float*)d_in[7];
  const float* b_dt   = (const float*)d_in[8];
  const float* A_log  = (const float*)d_in[9];
  const float* Dp     = (const float*)d_in[10];
  const float* W_out_m= (const float*)d_in[11];
  const float* W_qkv  = (const float*)d_in[12];
  const float* b_qkv  = (const float*)d_in[13];
  const float* W_o    = (const float*)d_in[14];
  const float* b_o    = (const float*)d_in[15];
  const float* W_gate = (const float*)d_in[16];
  const float* b_gate = (const float*)d_in[17];
  float* out = (float*)d_out;

  float* ws = (float*)d_ws;
  float* xn     = ws;                  // 2,097,152
  float* xz     = xn     + 2097152;    // 8,388,608  (xm | z)
  float* qkv    = xz     + 8388608;    // 6,291,456
  float* xc     = qkv    + 6291456;    // 4,194,304
  float* dblb   = xc     + 4194304;    //   393,216
  float* dtb    = dblb   + 393216;     // 4,194,304
  float* ygate  = dtb    + 4194304;    // 4,194,304
  float* attn_o = ygate  + 4194304;    // 2,097,152
  float* catb   = attn_o + 2097152;    // 4,194,304  (ssm | attn), ldc=512
  float* gateb  = catb   + 4194304;    // 2,097,152

  // scan summaries alias attn_o region (written only after scan completes)
  float* Pws  = attn_o;            // 524,288
  float* Hws  = attn_o + 524288;   // 524,288
  float* H0ws = attn_o + 1048576;  // 524,288

  ln_kernel<<<T_TOK/4, 256, 0, stream>>>(x, ln_g, ln_b, xn);
  gemm_k<0><<<dim3(1024/GBN, T_TOK/GBM), 256, 0, stream>>>(xn, DM, W_in, 1024, nullptr, xz, 1024, DM);
  gemm_k<0><<<dim3(768/GBN,  T_TOK/GBM), 256, 0, stream>>>(xn, DM, W_qkv, 768, b_qkv, qkv, 768, DM);
  conv_kernel<<<T_TOK*DI/256, 256, 0, stream>>>(xz, conv_w, conv_b, xc);
  xproj_dt_kernel<<<T_TOK/4, 256, 0, stream>>>(xc, W_xproj, W_dt, b_dt, dblb, dtb);
  scan_pass1<<<2048, 256, 0, stream>>>(xc, dtb, dblb, A_log, Pws, Hws);
  scan_combine<<<128, 256, 0, stream>>>(Pws, Hws, H0ws);
  scan_pass2<<<2048, 256, 0, stream>>>(xc, dtb, dblb, A_log, Dp, xz, H0ws, ygate);
  attn_kernel<<<dim3(SEQ/64, B_SZ*NH), 256, 0, stream>>>(qkv, attn_o);
  gemm_k<0><<<dim3(256/GBN, T_TOK/GBM), 256, 0, stream>>>(ygate, DI, W_out_m, DM, nullptr, catb, 512, DI);
  gemm_k<0><<<dim3(256/GBN, T_TOK/GBM), 256, 0, stream>>>(attn_o, DM, W_o, DM, b_o, catb+256, 512, DM);
  gemm_k<1><<<dim3(256/GBN, T_TOK/GBM), 256, 0, stream>>>(catb, 512, W_gate, DM, b_gate, gateb, DM, DI);
  final_kernel<<<T_TOK*64/256, 256, 0, stream>>>(x, catb, gateb, out);
}

// Round 3
// 621.234 us; speedup vs baseline: 3.9331x; 1.7589x over previous
//
#include <hip/hip_runtime.h>
#include <math.h>

#define B_SZ 4
#define SEQ 2048
#define DM 256
#define DI 512
#define DS 16
#define DTR 16
#define NH 4
#define HD 64
#define T_TOK (B_SZ*SEQ)   // 8192
#define NC 16              // scan time-chunks
#define CHUNK (SEQ/NC)     // 128

typedef short bf16x8 __attribute__((ext_vector_type(8)));
typedef float f32x4  __attribute__((ext_vector_type(4)));

__device__ __forceinline__ float sigmoidf_(float x){ return 1.f/(1.f+__expf(-x)); }
__device__ __forceinline__ unsigned short f2bf(float x){
  unsigned int u = __float_as_uint(x);
  u += 0x7fffu + ((u>>16)&1u);
  return (unsigned short)(u>>16);
}

// ---------------- LayerNorm: one wave per token ----------------
__global__ __launch_bounds__(256) void ln_kernel(const float* __restrict__ x,
    const float* __restrict__ g, const float* __restrict__ b,
    float* __restrict__ xn) {
  int wid = threadIdx.x >> 6;
  int lane = threadIdx.x & 63;
  int token = blockIdx.x*4 + wid;
  const float* xr = x + (size_t)token*DM;
  float4 v = *(const float4*)&xr[lane*4];
  float s  = v.x+v.y+v.z+v.w;
  float ss = v.x*v.x+v.y*v.y+v.z*v.z+v.w*v.w;
  for (int m=1;m<64;m<<=1){ s += __shfl_xor(s,m); ss += __shfl_xor(ss,m); }
  float mu  = s * (1.f/DM);
  float var = ss*(1.f/DM) - mu*mu;
  float rs  = rsqrtf(var + 1e-5f);
  float4 gv = *(const float4*)&g[lane*4];
  float4 bv = *(const float4*)&b[lane*4];
  float4 o;
  o.x = (v.x-mu)*rs*gv.x + bv.x;
  o.y = (v.y-mu)*rs*gv.y + bv.y;
  o.z = (v.z-mu)*rs*gv.z + bv.z;
  o.w = (v.w-mu)*rs*gv.w + bv.w;
  *(float4*)&xn[(size_t)token*DM + lane*4] = o;
}

// ---------------- Generic fp32 tiled GEMM ----------------
#define GBM 64
#define GBN 64
#define GBK 16
template<int ACT>   // 0 = none, 1 = sigmoid
__global__ __launch_bounds__(256) void gemm_k(const float* __restrict__ A, int lda,
    const float* __restrict__ W, int ldw,
    const float* __restrict__ bias,
    float* __restrict__ C, int ldc, int K) {
  __shared__ float As[GBK][GBM+4];
  __shared__ float Ws[GBK][GBN+4];
  int tid = threadIdx.x;
  int m0 = blockIdx.y * GBM;
  int n0 = blockIdx.x * GBN;
  int tx = tid & 15, ty = tid >> 4;
  float acc[4][4] = {};
  for (int k0 = 0; k0 < K; k0 += GBK) {
    {
      int m  = tid >> 2;
      int kq = (tid & 3) * 4;
      float4 av = *(const float4*)&A[(size_t)(m0+m)*lda + k0 + kq];
      As[kq+0][m] = av.x; As[kq+1][m] = av.y; As[kq+2][m] = av.z; As[kq+3][m] = av.w;
      int n  = (tid & 15) * 4;
      int kk = tid >> 4;
      *(float4*)&Ws[kk][n] = *(const float4*)&W[(size_t)(k0+kk)*ldw + n0 + n];
    }
    __syncthreads();
#pragma unroll
    for (int kk = 0; kk < GBK; ++kk) {
      float4 a4 = *(const float4*)&As[kk][ty*4];
      float4 b4 = *(const float4*)&Ws[kk][tx*4];
      float a[4] = {a4.x,a4.y,a4.z,a4.w};
      float b[4] = {b4.x,b4.y,b4.z,b4.w};
#pragma unroll
      for (int i=0;i<4;++i)
#pragma unroll
        for (int j=0;j<4;++j) acc[i][j] += a[i]*b[j];
    }
    __syncthreads();
  }
#pragma unroll
  for (int i=0;i<4;++i) {
#pragma unroll
    for (int j=0;j<4;++j) {
      float v = acc[i][j];
      if (bias) v += bias[n0 + tx*4 + j];
      if (ACT==1) v = sigmoidf_(v);
      C[(size_t)(m0+ty*4+i)*ldc + n0 + tx*4 + j] = v;
    }
  }
}

// ---------------- depthwise conv (k=4) + SiLU ----------------
__global__ __launch_bounds__(256) void conv_kernel(const float* __restrict__ xz,
    const float* __restrict__ cw, const float* __restrict__ cb,
    float* __restrict__ xc) {
  int idx = blockIdx.x*256 + threadIdx.x;  // t*512 + d
  int d = idx & (DI-1);
  int t = idx >> 9;
  int l = t & (SEQ-1);
  float acc = cb[d];
  float w0=cw[d*4+0], w1=cw[d*4+1], w2=cw[d*4+2], w3=cw[d*4+3];
  const float* base = xz + (size_t)t*1024 + d;   // xm region (cols 0..511)
  if (l>=3) acc += base[-3*1024]*w0;
  if (l>=2) acc += base[-2*1024]*w1;
  if (l>=1) acc += base[-1*1024]*w2;
  acc += base[0]*w3;
  xc[idx] = acc * sigmoidf_(acc);
}

// ---------------- x_proj (512->48) + dt = softplus ----------------
__global__ __launch_bounds__(256) void xproj_dt_kernel(const float* __restrict__ xc,
    const float* __restrict__ Wx, const float* __restrict__ Wdt,
    const float* __restrict__ bdt, float* __restrict__ dbl, float* __restrict__ dt) {
  __shared__ float sxc[4][DI];
  __shared__ float sdbl[4][48];
  int wid = threadIdx.x>>6, lane = threadIdx.x&63;
  int token = blockIdx.x*4 + wid;
  {
    float4 a = *(const float4*)&xc[(size_t)token*DI + lane*4];
    float4 b = *(const float4*)&xc[(size_t)token*DI + 256 + lane*4];
    *(float4*)&sxc[wid][lane*4]       = a;
    *(float4*)&sxc[wid][256 + lane*4] = b;
  }
  __syncthreads();
  if (lane < 48) {
    float acc = 0.f;
    for (int k=0;k<DI;++k) acc += sxc[wid][k]*Wx[k*48+lane];
    dbl[(size_t)token*48+lane] = acc;
    sdbl[wid][lane] = acc;
  }
  __syncthreads();
#pragma unroll
  for (int r=0;r<8;++r){
    int d = lane + r*64;
    float acc = bdt[d];
#pragma unroll
    for (int k=0;k<DTR;++k) acc += sdbl[wid][k]*Wdt[k*DI+d];
    float sp = (acc > 20.f) ? acc : log1pf(__expf(acc));
    dt[(size_t)token*DI+d] = sp;
  }
}

// ---------------- chunked selective scan ----------------
__global__ __launch_bounds__(256) void scan_pass1(const float* __restrict__ xc,
    const float* __restrict__ dt, const float* __restrict__ dbl,
    const float* __restrict__ A_log, float* __restrict__ Pws, float* __restrict__ Hws) {
  int tid = threadIdx.x;
  int wid = tid>>6, lane = tid&63;
  int slot = lane>>4, n = lane&15;
  int W = blockIdx.x*4 + wid;          // 0..8191
  int dblk = W & 127;
  int c    = (W>>7) & 15;
  int b    = W>>11;
  int d    = dblk*4 + slot;
  float An = -__expf(A_log[d*DS+n]);
  float P = 1.f, h = 0.f;
  size_t tok = (size_t)b*SEQ + c*CHUNK;
  for (int t=0;t<CHUNK;++t,++tok){
    float dtv = dt[tok*DI+d];
    float xcv = xc[tok*DI+d];
    float Bv  = dbl[tok*48 + DTR + n];
    float dA  = __expf(dtv*An);
    P *= dA;
    h = dA*h + (dtv*xcv)*Bv;
  }
  size_t idx = ((size_t)(b*NC+c)*DI + d)*DS + n;
  Pws[idx] = P; Hws[idx] = h;
}

__global__ __launch_bounds__(256) void scan_combine(const float* __restrict__ Pws,
    const float* __restrict__ Hws, float* __restrict__ H0ws) {
  int gid = blockIdx.x*256 + threadIdx.x;  // 0..32767 = (b, d*DS+n)
  int b  = gid >> 13;
  int dn = gid & 8191;
  float h0 = 0.f;
#pragma unroll
  for (int c=0;c<NC;++c){
    size_t idx = ((size_t)(b*NC+c)<<13) + dn;
    H0ws[idx] = h0;
    h0 = Pws[idx]*h0 + Hws[idx];
  }
}

__global__ __launch_bounds__(256) void scan_pass2(const float* __restrict__ xc,
    const float* __restrict__ dt, const float* __restrict__ dbl,
    const float* __restrict__ A_log, const float* __restrict__ Dp,
    const float* __restrict__ xz, const float* __restrict__ H0ws,
    float* __restrict__ ygate) {
  int tid = threadIdx.x;
  int wid = tid>>6, lane = tid&63;
  int slot = lane>>4, n = lane&15;
  int W = blockIdx.x*4 + wid;
  int dblk = W & 127;
  int c    = (W>>7) & 15;
  int b    = W>>11;
  int d    = dblk*4 + slot;
  float An = -__expf(A_log[d*DS+n]);
  float Dd = Dp[d];
  size_t idx = ((size_t)(b*NC+c)*DI + d)*DS + n;
  float h = H0ws[idx];
  size_t tok = (size_t)b*SEQ + c*CHUNK;
  for (int t=0;t<CHUNK;++t,++tok){
    float dtv = dt[tok*DI+d];
    float xcv = xc[tok*DI+d];
    float Bv  = dbl[tok*48 + DTR + n];
    float Cv  = dbl[tok*48 + DTR + DS + n];
    float dA  = __expf(dtv*An);
    h = dA*h + (dtv*xcv)*Bv;
    float p = h*Cv;
    p += __shfl_xor(p,1);
    p += __shfl_xor(p,2);
    p += __shfl_xor(p,4);
    p += __shfl_xor(p,8);
    if (n==0){
      float y  = p + xcv*Dd;
      float zv = xz[tok*1024 + DI + d];
      ygate[tok*DI + d] = y * (zv*sigmoidf_(zv));
    }
  }
}

// ---------------- MFMA bf16 flash attention ----------------
// Block: 4 waves, 64 q rows (16/wave), KV tiles of 64 keys.
// LDS (ushort units): K_lds [64][64] @0, V_T [64][64] @4096, P[wave][16][64] @8192+w*1024.
// All tiles XOR-swizzled on 16B granules: gran ^= (row&7).
__global__ __launch_bounds__(256) void attn_mfma_kernel(const float* __restrict__ qkv,
    float* __restrict__ o_out) {
  __shared__ unsigned short lds[12288];   // 24 KB
  int bh = blockIdx.y; int b = bh>>2, h = bh&3;
  int tid = threadIdx.x;
  int w = tid>>6, l = tid&63;
  int lq = l & 15;       // quarter lane
  int lg = l >> 4;       // lane group 0..3
  size_t bbase = (size_t)b*SEQ;
  int q0 = blockIdx.x*64 + w*16;

  // ---- preload Q fragments: A-layout: row=lq, k(d) = lg*8 + ds*32 + j ----
  bf16x8 qf[2];
#pragma unroll
  for (int dsl=0; dsl<2; ++dsl){
    const float* qp = &qkv[(bbase + q0 + lq)*768 + h*HD + lg*8 + dsl*32];
    float4 a = *(const float4*)&qp[0];
    float4 c = *(const float4*)&qp[4];
    bf16x8 f;
    f[0]=(short)f2bf(a.x); f[1]=(short)f2bf(a.y); f[2]=(short)f2bf(a.z); f[3]=(short)f2bf(a.w);
    f[4]=(short)f2bf(c.x); f[5]=(short)f2bf(c.y); f[6]=(short)f2bf(c.z); f[7]=(short)f2bf(c.w);
    qf[dsl] = f;
  }

  float mrow[4] = {-1e30f,-1e30f,-1e30f,-1e30f};
  float lrow[4] = {0.f,0.f,0.f,0.f};
  f32x4 oacc[4] = {{0,0,0,0},{0,0,0,0},{0,0,0,0},{0,0,0,0}};
  int pbase = 8192 + w*1024;

  for (int kt=0; kt<SEQ/64; ++kt){
    __syncthreads();
    // ---- stage K tile row-major bf16, swizzled ----
    {
      int d4 = (tid & 15)*4;
#pragma unroll
      for (int r=0;r<4;++r){
        int krow = (tid>>4) + r*16;
        float4 v = *(const float4*)&qkv[(bbase + kt*64 + krow)*768 + 256 + h*HD + d4];
        unsigned int p0 = (unsigned)f2bf(v.x) | ((unsigned)f2bf(v.y)<<16);
        unsigned int p1 = (unsigned)f2bf(v.z) | ((unsigned)f2bf(v.w)<<16);
        int off = krow*64 + (((d4>>3) ^ (krow&7))*8) + (d4&7);
        uint2 pk; pk.x = p0; pk.y = p1;
        *(uint2*)&lds[off] = pk;
      }
    }
    // ---- stage V transposed (V_T[d][k]) bf16, swizzled ----
    {
      int d = tid & 63;
#pragma unroll
      for (int i=0;i<8;++i){
        int k2 = (tid>>6)*2 + i*8;
        float v0 = qkv[(bbase + kt*64 + k2    )*768 + 512 + h*HD + d];
        float v1 = qkv[(bbase + kt*64 + k2 + 1)*768 + 512 + h*HD + d];
        unsigned int pk = (unsigned)f2bf(v0) | ((unsigned)f2bf(v1)<<16);
        int off = 4096 + d*64 + (((k2>>3) ^ (d&7))*8) + (k2&7);
        *(unsigned int*)&lds[off] = pk;
      }
    }
    __syncthreads();

    // ---- S = Q K^T : 4 kg tiles, 2 d-slices each ----
    f32x4 sacc[4] = {{0,0,0,0},{0,0,0,0},{0,0,0,0},{0,0,0,0}};
#pragma unroll
    for (int kg=0;kg<4;++kg){
#pragma unroll
      for (int dsl=0;dsl<2;++dsl){
        int row = kg*16 + lq;
        int off = row*64 + (((dsl*4 + lg) ^ (row&7))*8);
        bf16x8 kf = *(bf16x8*)&lds[off];
        sacc[kg] = __builtin_amdgcn_mfma_f32_16x16x32_bf16(qf[dsl], kf, sacc[kg], 0,0,0);
      }
    }
    // ---- online softmax (rows = lg*4 + r, cols = lq within kg tile) ----
    float pv[4][4];
#pragma unroll
    for (int r=0;r<4;++r){
      float tm = fmaxf(fmaxf(sacc[0][r],sacc[1][r]),fmaxf(sacc[2][r],sacc[3][r]));
      tm *= 0.125f;
      tm = fmaxf(tm, __shfl_xor(tm,1));
      tm = fmaxf(tm, __shfl_xor(tm,2));
      tm = fmaxf(tm, __shfl_xor(tm,4));
      tm = fmaxf(tm, __shfl_xor(tm,8));
      float mn = fmaxf(mrow[r], tm);
      float sc = __expf(mrow[r] - mn);
      mrow[r] = mn;
      float ps = 0.f;
#pragma unroll
      for (int kg=0;kg<4;++kg){
        float p = __expf(sacc[kg][r]*0.125f - mn);
        pv[kg][r] = p;
        ps += p;
      }
      ps += __shfl_xor(ps,1);
      ps += __shfl_xor(ps,2);
      ps += __shfl_xor(ps,4);
      ps += __shfl_xor(ps,8);
      lrow[r] = lrow[r]*sc + ps;
#pragma unroll
      for (int dg=0;dg<4;++dg) oacc[dg][r] *= sc;
    }
    // ---- write P (bf16) to per-wave LDS, swizzled ----
#pragma unroll
    for (int kg=0;kg<4;++kg){
      int k = kg*16 + lq;
#pragma unroll
      for (int r=0;r<4;++r){
        int row = lg*4 + r;
        int off = pbase + row*64 + (((k>>3) ^ (row&7))*8) + (k&7);
        lds[off] = f2bf(pv[kg][r]);
      }
    }
    // ---- O += P V : A = P frag, B = V_T-as-B frag ----
#pragma unroll
    for (int ks=0;ks<2;++ks){
      int poff = pbase + lq*64 + (((ks*4 + lg) ^ (lq&7))*8);
      bf16x8 pf = *(bf16x8*)&lds[poff];
#pragma unroll
      for (int dg=0;dg<4;++dg){
        int row = dg*16 + lq;
        int voff = 4096 + row*64 + (((ks*4 + lg) ^ (row&7))*8);
        bf16x8 vf = *(bf16x8*)&lds[voff];
        oacc[dg] = __builtin_amdgcn_mfma_f32_16x16x32_bf16(pf, vf, oacc[dg], 0,0,0);
      }
    }
  }

  // ---- epilogue: O/l, write ----
#pragma unroll
  for (int r=0;r<4;++r){
    float inv = 1.f/lrow[r];
    size_t tok = bbase + q0 + lg*4 + r;
#pragma unroll
    for (int dg=0;dg<4;++dg){
      o_out[tok*DM + h*HD + dg*16 + lq] = oacc[dg][r]*inv;
    }
  }
}

// ---------------- final: out = x + g*ssm + (1-g)*attn ----------------
__global__ __launch_bounds__(256) void final_kernel(const float* __restrict__ x,
    const float* __restrict__ cat, const float* __restrict__ gate,
    float* __restrict__ out) {
  int idx = blockIdx.x*256 + threadIdx.x;
  int token = idx >> 6;
  int q = (idx & 63)*4;
  float4 g4 = *(const float4*)&gate[(size_t)token*DM + q];
  float4 s4 = *(const float4*)&cat[(size_t)token*512 + q];
  float4 a4 = *(const float4*)&cat[(size_t)token*512 + 256 + q];
  float4 x4 = *(const float4*)&x[(size_t)token*DM + q];
  float4 o;
  o.x = x4.x + g4.x*s4.x + (1.f-g4.x)*a4.x;
  o.y = x4.y + g4.y*s4.y + (1.f-g4.y)*a4.y;
  o.z = x4.z + g4.z*s4.z + (1.f-g4.z)*a4.z;
  o.w = x4.w + g4.w*s4.w + (1.f-g4.w)*a4.w;
  *(float4*)&out[(size_t)token*DM + q] = o;
}

extern "C" void kernel_launch(void* const* d_in, const int* in_sizes, int n_in,
                              void* d_out, int out_size, void* d_ws, size_t ws_size,
                              hipStream_t stream) {
  const float* x      = (const float*)d_in[0];
  const float* ln_g   = (const float*)d_in[1];
  const float* ln_b   = (const float*)d_in[2];
  const float* W_in   = (const float*)d_in[3];
  const float* conv_w = (const float*)d_in[4];
  const float* conv_b = (const float*)d_in[5];
  const float* W_xproj= (const float*)d_in[6];
  const float* W_dt   = (const float*)d_in[7];
  const float* b_dt   = (const float*)d_in[8];
  const float* A_log  = (const float*)d_in[9];
  const float* Dp     = (const float*)d_in[10];
  const float* W_out_m= (const float*)d_in[11];
  const float* W_qkv  = (const float*)d_in[12];
  const float* b_qkv  = (const float*)d_in[13];
  const float* W_o    = (const float*)d_in[14];
  const float* b_o    = (const float*)d_in[15];
  const float* W_gate = (const float*)d_in[16];
  const float* b_gate = (const float*)d_in[17];
  float* out = (float*)d_out;

  float* ws = (float*)d_ws;
  float* xn     = ws;                  // 2,097,152
  float* xz     = xn     + 2097152;    // 8,388,608  (xm | z)
  float* qkv    = xz     + 8388608;    // 6,291,456
  float* xc     = qkv    + 6291456;    // 4,194,304
  float* dblb   = xc     + 4194304;    //   393,216
  float* dtb    = dblb   + 393216;     // 4,194,304
  float* ygate  = dtb    + 4194304;    // 4,194,304
  float* attn_o = ygate  + 4194304;    // 2,097,152
  float* catb   = attn_o + 2097152;    // 4,194,304  (ssm | attn), ldc=512
  float* gateb  = catb   + 4194304;    // 2,097,152

  // scan summaries alias attn_o region (written only after scan completes)
  float* Pws  = attn_o;            // 524,288
  float* Hws  = attn_o + 524288;   // 524,288
  float* H0ws = attn_o + 1048576;  // 524,288

  ln_kernel<<<T_TOK/4, 256, 0, stream>>>(x, ln_g, ln_b, xn);
  gemm_k<0><<<dim3(1024/GBN, T_TOK/GBM), 256, 0, stream>>>(xn, DM, W_in, 1024, nullptr, xz, 1024, DM);
  gemm_k<0><<<dim3(768/GBN,  T_TOK/GBM), 256, 0, stream>>>(xn, DM, W_qkv, 768, b_qkv, qkv, 768, DM);
  conv_kernel<<<T_TOK*DI/256, 256, 0, stream>>>(xz, conv_w, conv_b, xc);
  xproj_dt_kernel<<<T_TOK/4, 256, 0, stream>>>(xc, W_xproj, W_dt, b_dt, dblb, dtb);
  scan_pass1<<<2048, 256, 0, stream>>>(xc, dtb, dblb, A_log, Pws, Hws);
  scan_combine<<<128, 256, 0, stream>>>(Pws, Hws, H0ws);
  scan_pass2<<<2048, 256, 0, stream>>>(xc, dtb, dblb, A_log, Dp, xz, H0ws, ygate);
  attn_mfma_kernel<<<dim3(SEQ/64, B_SZ*NH), 256, 0, stream>>>(qkv, attn_o);
  gemm_k<0><<<dim3(256/GBN, T_TOK/GBM), 256, 0, stream>>>(ygate, DI, W_out_m, DM, nullptr, catb, 512, DI);
  gemm_k<0><<<dim3(256/GBN, T_TOK/GBM), 256, 0, stream>>>(attn_o, DM, W_o, DM, b_o, catb+256, 512, DM);
  gemm_k<1><<<dim3(256/GBN, T_TOK/GBM), 256, 0, stream>>>(catb, 512, W_gate, DM, b_gate, gateb, DM, DI);
  final_kernel<<<T_TOK*64/256, 256, 0, stream>>>(x, catb, gateb, out);
}

// Round 4
// 416.506 us; speedup vs baseline: 5.8664x; 1.4915x over previous
//
#include <hip/hip_runtime.h>
#include <math.h>

#define B_SZ 4
#define SEQ 2048
#define DM 256
#define DI 512
#define DS 16
#define DTR 16
#define NH 4
#define HD 64
#define T_TOK (B_SZ*SEQ)   // 8192
#define NC 16              // scan time-chunks
#define CHUNK (SEQ/NC)     // 128

typedef short bf16x8 __attribute__((ext_vector_type(8)));
typedef float f32x4  __attribute__((ext_vector_type(4)));
typedef unsigned short u16;

__device__ __forceinline__ float sigmoidf_(float x){ return 1.f/(1.f+__expf(-x)); }
__device__ __forceinline__ u16 f2bf(float x){
  unsigned int u = __float_as_uint(x);
  u += 0x7fffu + ((u>>16)&1u);
  return (u16)(u>>16);
}

// ---------------- weight transpose+convert: dst[n][k] = bf16(src[k][n]) ----------------
__global__ __launch_bounds__(64) void tcvt_kernel(const float* __restrict__ src,
    u16* __restrict__ dst, int N, int K) {
  int n = blockIdx.x*64 + threadIdx.x;
  int k = blockIdx.y;
  dst[(size_t)n*K + k] = f2bf(src[(size_t)k*N + n]);
}

// ---------------- LayerNorm: one wave per token -> bf16 ----------------
__global__ __launch_bounds__(256) void ln_kernel(const float* __restrict__ x,
    const float* __restrict__ g, const float* __restrict__ b,
    u16* __restrict__ xn_bf) {
  int wid = threadIdx.x >> 6;
  int lane = threadIdx.x & 63;
  int token = blockIdx.x*4 + wid;
  const float* xr = x + (size_t)token*DM;
  float4 v = *(const float4*)&xr[lane*4];
  float s  = v.x+v.y+v.z+v.w;
  float ss = v.x*v.x+v.y*v.y+v.z*v.z+v.w*v.w;
  for (int m=1;m<64;m<<=1){ s += __shfl_xor(s,m); ss += __shfl_xor(ss,m); }
  float mu  = s * (1.f/DM);
  float var = ss*(1.f/DM) - mu*mu;
  float rs  = rsqrtf(var + 1e-5f);
  float4 gv = *(const float4*)&g[lane*4];
  float4 bv = *(const float4*)&b[lane*4];
  ushort4 o;
  o.x = f2bf((v.x-mu)*rs*gv.x + bv.x);
  o.y = f2bf((v.y-mu)*rs*gv.y + bv.y);
  o.z = f2bf((v.z-mu)*rs*gv.z + bv.z);
  o.w = f2bf((v.w-mu)*rs*gv.w + bv.w);
  *(ushort4*)&xn_bf[(size_t)token*DM + lane*4] = o;
}

// ---------------- MFMA bf16 GEMM: C[M,N] = A[M,K](bf16) @ Wt[N,K](bf16) ----------------
// BM=128, BN=64, BK=64; 4 waves 2x2; wave tile 64x32 (4x2 frags of 16x16).
template<int ACT>  // 0=none, 1=sigmoid
__global__ __launch_bounds__(256) void gemm_mfma(const u16* __restrict__ A,
    const u16* __restrict__ Wt, const float* __restrict__ bias,
    float* __restrict__ C, u16* __restrict__ Cbf, int K, int ldc) {
  __shared__ u16 lds[12288];    // As 128x64 @0 (8192), Bs 64x64 @8192 (4096)
  int tid = threadIdx.x;
  int m0 = blockIdx.y*128, n0 = blockIdx.x*64;
  int w = tid>>6, l = tid&63, lq = l&15, lg = l>>4;
  int wm = w>>1, wn = w&1;
  f32x4 acc[4][2] = {};
  for (int k0 = 0; k0 < K; k0 += 64) {
#pragma unroll
    for (int i=0;i<4;++i){
      int gid = i*256 + tid;
      int row = gid>>3, g = gid&7;
      *(bf16x8*)&lds[row*64 + ((g ^ (row&7))*8)] =
          *(const bf16x8*)&A[(size_t)(m0+row)*K + k0 + g*8];
    }
#pragma unroll
    for (int i=0;i<2;++i){
      int gid = i*256 + tid;
      int row = gid>>3, g = gid&7;
      *(bf16x8*)&lds[8192 + row*64 + ((g ^ (row&7))*8)] =
          *(const bf16x8*)&Wt[(size_t)(n0+row)*K + k0 + g*8];
    }
    __syncthreads();
#pragma unroll
    for (int ks=0;ks<2;++ks){
      bf16x8 af[4], bfv[2];
#pragma unroll
      for (int mi=0;mi<4;++mi){
        int row = wm*64 + mi*16 + lq;
        af[mi] = *(bf16x8*)&lds[row*64 + (((ks*4+lg) ^ (row&7))*8)];
      }
#pragma unroll
      for (int nj=0;nj<2;++nj){
        int row = wn*32 + nj*16 + lq;
        bfv[nj] = *(bf16x8*)&lds[8192 + row*64 + (((ks*4+lg) ^ (row&7))*8)];
      }
#pragma unroll
      for (int mi=0;mi<4;++mi)
#pragma unroll
        for (int nj=0;nj<2;++nj)
          acc[mi][nj] = __builtin_amdgcn_mfma_f32_16x16x32_bf16(af[mi], bfv[nj], acc[mi][nj], 0,0,0);
    }
    __syncthreads();
  }
#pragma unroll
  for (int mi=0;mi<4;++mi){
#pragma unroll
    for (int nj=0;nj<2;++nj){
#pragma unroll
      for (int r=0;r<4;++r){
        int row = m0 + wm*64 + mi*16 + lg*4 + r;
        int col = n0 + wn*32 + nj*16 + lq;
        float v = acc[mi][nj][r];
        if (bias) v += bias[col];
        if (ACT==1) v = sigmoidf_(v);
        if (C)   C[(size_t)row*ldc + col] = v;
        if (Cbf) Cbf[(size_t)row*ldc + col] = f2bf(v);
      }
    }
  }
}

// ---------------- depthwise conv (k=4) + SiLU ----------------
__global__ __launch_bounds__(256) void conv_kernel(const float* __restrict__ xz,
    const float* __restrict__ cw, const float* __restrict__ cb,
    float* __restrict__ xc) {
  int idx = blockIdx.x*256 + threadIdx.x;  // t*512 + d
  int d = idx & (DI-1);
  int t = idx >> 9;
  int l = t & (SEQ-1);
  float acc = cb[d];
  float w0=cw[d*4+0], w1=cw[d*4+1], w2=cw[d*4+2], w3=cw[d*4+3];
  const float* base = xz + (size_t)t*1024 + d;
  if (l>=3) acc += base[-3*1024]*w0;
  if (l>=2) acc += base[-2*1024]*w1;
  if (l>=1) acc += base[-1*1024]*w2;
  acc += base[0]*w3;
  xc[idx] = acc * sigmoidf_(acc);
}

// ---------------- x_proj (512->48) + dt = softplus ----------------
__global__ __launch_bounds__(256) void xproj_dt_kernel(const float* __restrict__ xc,
    const float* __restrict__ Wx, const float* __restrict__ Wdt,
    const float* __restrict__ bdt, float* __restrict__ dbl, float* __restrict__ dt) {
  __shared__ float sxc[4][DI];
  __shared__ float sdbl[4][48];
  int wid = threadIdx.x>>6, lane = threadIdx.x&63;
  int token = blockIdx.x*4 + wid;
  {
    float4 a = *(const float4*)&xc[(size_t)token*DI + lane*4];
    float4 b = *(const float4*)&xc[(size_t)token*DI + 256 + lane*4];
    *(float4*)&sxc[wid][lane*4]       = a;
    *(float4*)&sxc[wid][256 + lane*4] = b;
  }
  __syncthreads();
  if (lane < 48) {
    float acc = 0.f;
    for (int k=0;k<DI;++k) acc += sxc[wid][k]*Wx[k*48+lane];
    dbl[(size_t)token*48+lane] = acc;
    sdbl[wid][lane] = acc;
  }
  __syncthreads();
#pragma unroll
  for (int r=0;r<8;++r){
    int d = lane + r*64;
    float acc = bdt[d];
#pragma unroll
    for (int k=0;k<DTR;++k) acc += sdbl[wid][k]*Wdt[k*DI+d];
    float sp = (acc > 20.f) ? acc : log1pf(__expf(acc));
    dt[(size_t)token*DI+d] = sp;
  }
}

// ---------------- chunked selective scan ----------------
__global__ __launch_bounds__(256) void scan_pass1(const float* __restrict__ xc,
    const float* __restrict__ dt, const float* __restrict__ dbl,
    const float* __restrict__ A_log, float* __restrict__ Pws, float* __restrict__ Hws) {
  int tid = threadIdx.x;
  int wid = tid>>6, lane = tid&63;
  int slot = lane>>4, n = lane&15;
  int W = blockIdx.x*4 + wid;          // 0..8191
  int dblk = W & 127;
  int c    = (W>>7) & 15;
  int b    = W>>11;
  int d    = dblk*4 + slot;
  float An = -__expf(A_log[d*DS+n]);
  float P = 1.f, h = 0.f;
  size_t tok = (size_t)b*SEQ + c*CHUNK;
  for (int t=0;t<CHUNK;++t,++tok){
    float dtv = dt[tok*DI+d];
    float xcv = xc[tok*DI+d];
    float Bv  = dbl[tok*48 + DTR + n];
    float dA  = __expf(dtv*An);
    P *= dA;
    h = dA*h + (dtv*xcv)*Bv;
  }
  size_t idx = ((size_t)(b*NC+c)*DI + d)*DS + n;
  Pws[idx] = P; Hws[idx] = h;
}

__global__ __launch_bounds__(256) void scan_combine(const float* __restrict__ Pws,
    const float* __restrict__ Hws, float* __restrict__ H0ws) {
  int gid = blockIdx.x*256 + threadIdx.x;  // 0..32767 = (b, d*DS+n)
  int b  = gid >> 13;
  int dn = gid & 8191;
  float h0 = 0.f;
#pragma unroll
  for (int c=0;c<NC;++c){
    size_t idx = ((size_t)(b*NC+c)<<13) + dn;
    H0ws[idx] = h0;
    h0 = Pws[idx]*h0 + Hws[idx];
  }
}

__global__ __launch_bounds__(256) void scan_pass2(const float* __restrict__ xc,
    const float* __restrict__ dt, const float* __restrict__ dbl,
    const float* __restrict__ A_log, const float* __restrict__ Dp,
    const float* __restrict__ xz, const float* __restrict__ H0ws,
    u16* __restrict__ ygate_bf) {
  int tid = threadIdx.x;
  int wid = tid>>6, lane = tid&63;
  int slot = lane>>4, n = lane&15;
  int W = blockIdx.x*4 + wid;
  int dblk = W & 127;
  int c    = (W>>7) & 15;
  int b    = W>>11;
  int d    = dblk*4 + slot;
  float An = -__expf(A_log[d*DS+n]);
  float Dd = Dp[d];
  size_t idx = ((size_t)(b*NC+c)*DI + d)*DS + n;
  float h = H0ws[idx];
  size_t tok = (size_t)b*SEQ + c*CHUNK;
  for (int t=0;t<CHUNK;++t,++tok){
    float dtv = dt[tok*DI+d];
    float xcv = xc[tok*DI+d];
    float Bv  = dbl[tok*48 + DTR + n];
    float Cv  = dbl[tok*48 + DTR + DS + n];
    float dA  = __expf(dtv*An);
    h = dA*h + (dtv*xcv)*Bv;
    float p = h*Cv;
    p += __shfl_xor(p,1);
    p += __shfl_xor(p,2);
    p += __shfl_xor(p,4);
    p += __shfl_xor(p,8);
    if (n==0){
      float y  = p + xcv*Dd;
      float zv = xz[tok*1024 + DI + d];
      ygate_bf[tok*DI + d] = f2bf(y * (zv*sigmoidf_(zv)));
    }
  }
}

// ---------------- MFMA bf16 flash attention, KV-split 4 ----------------
// grid (SEQ/64, 16 bh, 4 chunks); 4 waves x 16 q rows; KV tiles of 64.
__global__ __launch_bounds__(256) void attn_mfma_kernel(const u16* __restrict__ qkvb,
    float* __restrict__ Opart, float* __restrict__ ml) {
  __shared__ u16 lds[12288];   // K 64x64 @0, V_T 64x64 @4096, P per-wave @8192+w*1024
  int bh = blockIdx.y; int b = bh>>2, h = bh&3;
  int s = blockIdx.z;
  int tid = threadIdx.x;
  int w = tid>>6, l = tid&63;
  int lq = l & 15;
  int lg = l >> 4;
  size_t bbase = (size_t)b*SEQ;
  int q0 = blockIdx.x*64 + w*16;

  bf16x8 qf[2];
#pragma unroll
  for (int dsl=0; dsl<2; ++dsl)
    qf[dsl] = *(const bf16x8*)&qkvb[(bbase + q0 + lq)*768 + h*HD + lg*8 + dsl*32];

  float mrow[4] = {-1e30f,-1e30f,-1e30f,-1e30f};
  float lrow[4] = {0.f,0.f,0.f,0.f};
  f32x4 oacc[4] = {{0,0,0,0},{0,0,0,0},{0,0,0,0},{0,0,0,0}};
  int pbase = 8192 + w*1024;

  for (int kt=s*8; kt<s*8+8; ++kt){
    __syncthreads();
    // K tile: 512 granules, 2 per thread (direct bf16 16B copies)
#pragma unroll
    for (int i=0;i<2;++i){
      int gid = i*256 + tid;
      int row = gid>>3, g = gid&7;
      *(bf16x8*)&lds[row*64 + ((g ^ (row&7))*8)] =
          *(const bf16x8*)&qkvb[(bbase + kt*64 + row)*768 + 256 + h*HD + g*8];
    }
    // V transposed: 2048 u32, 8 per thread
#pragma unroll
    for (int i=0;i<8;++i){
      int u = i*256 + tid;
      int d = u&63, k2 = (u>>6)*2;
      u16 s0 = qkvb[(bbase + kt*64 + k2    )*768 + 512 + h*HD + d];
      u16 s1 = qkvb[(bbase + kt*64 + k2 + 1)*768 + 512 + h*HD + d];
      unsigned pk = (unsigned)s0 | ((unsigned)s1<<16);
      *(unsigned*)&lds[4096 + d*64 + (((k2>>3) ^ (d&7))*8) + (k2&7)] = pk;
    }
    __syncthreads();

    // S = Q K^T
    f32x4 sacc[4] = {{0,0,0,0},{0,0,0,0},{0,0,0,0},{0,0,0,0}};
    __builtin_amdgcn_s_setprio(1);
#pragma unroll
    for (int kg=0;kg<4;++kg){
#pragma unroll
      for (int dsl=0;dsl<2;++dsl){
        int row = kg*16 + lq;
        bf16x8 kf = *(bf16x8*)&lds[row*64 + (((dsl*4 + lg) ^ (row&7))*8)];
        sacc[kg] = __builtin_amdgcn_mfma_f32_16x16x32_bf16(qf[dsl], kf, sacc[kg], 0,0,0);
      }
    }
    __builtin_amdgcn_s_setprio(0);
    // online softmax
    float pv[4][4];
#pragma unroll
    for (int r=0;r<4;++r){
      float tm = fmaxf(fmaxf(sacc[0][r],sacc[1][r]),fmaxf(sacc[2][r],sacc[3][r]));
      tm *= 0.125f;
      tm = fmaxf(tm, __shfl_xor(tm,1));
      tm = fmaxf(tm, __shfl_xor(tm,2));
      tm = fmaxf(tm, __shfl_xor(tm,4));
      tm = fmaxf(tm, __shfl_xor(tm,8));
      float mn = fmaxf(mrow[r], tm);
      float sc = __expf(mrow[r] - mn);
      mrow[r] = mn;
      float ps = 0.f;
#pragma unroll
      for (int kg=0;kg<4;++kg){
        float p = __expf(sacc[kg][r]*0.125f - mn);
        pv[kg][r] = p;
        ps += p;
      }
      ps += __shfl_xor(ps,1);
      ps += __shfl_xor(ps,2);
      ps += __shfl_xor(ps,4);
      ps += __shfl_xor(ps,8);
      lrow[r] = lrow[r]*sc + ps;
#pragma unroll
      for (int dg=0;dg<4;++dg) oacc[dg][r] *= sc;
    }
    // P -> LDS (bf16)
#pragma unroll
    for (int kg=0;kg<4;++kg){
      int k = kg*16 + lq;
#pragma unroll
      for (int r=0;r<4;++r){
        int row = lg*4 + r;
        lds[pbase + row*64 + (((k>>3) ^ (row&7))*8) + (k&7)] = f2bf(pv[kg][r]);
      }
    }
    // O += P V
    __builtin_amdgcn_s_setprio(1);
#pragma unroll
    for (int ks=0;ks<2;++ks){
      bf16x8 pf = *(bf16x8*)&lds[pbase + lq*64 + (((ks*4 + lg) ^ (lq&7))*8)];
#pragma unroll
      for (int dg=0;dg<4;++dg){
        int row = dg*16 + lq;
        bf16x8 vf = *(bf16x8*)&lds[4096 + row*64 + (((ks*4 + lg) ^ (row&7))*8)];
        oacc[dg] = __builtin_amdgcn_mfma_f32_16x16x32_bf16(pf, vf, oacc[dg], 0,0,0);
      }
    }
    __builtin_amdgcn_s_setprio(0);
  }

  // write partials
  int sidx = bh*4 + s;
#pragma unroll
  for (int r=0;r<4;++r){
    int q = q0 + lg*4 + r;
    size_t rb = ((size_t)sidx*SEQ + q)*64;
#pragma unroll
    for (int dg=0;dg<4;++dg) Opart[rb + dg*16 + lq] = oacc[dg][r];
    if (lq==0){
      ml[((size_t)sidx*SEQ + q)*2    ] = mrow[r];
      ml[((size_t)sidx*SEQ + q)*2 + 1] = lrow[r];
    }
  }
}

// ---------------- merge 4 KV-chunk partials -> bf16 attn_o ----------------
__global__ __launch_bounds__(256) void attn_merge_kernel(const float* __restrict__ Opart,
    const float* __restrict__ ml, u16* __restrict__ attn_bf) {
  int w = threadIdx.x>>6, lane = threadIdx.x&63;
  int R = blockIdx.x*4 + w;        // 0..32767
  int bh = R>>11, q = R&2047;
  float m[4], lv[4];
#pragma unroll
  for (int s=0;s<4;++s){
    m[s]  = ml[((size_t)(bh*4+s)*SEQ + q)*2];
    lv[s] = ml[((size_t)(bh*4+s)*SEQ + q)*2 + 1];
  }
  float ms = fmaxf(fmaxf(m[0],m[1]),fmaxf(m[2],m[3]));
  float o = 0.f, lsum = 0.f;
#pragma unroll
  for (int s=0;s<4;++s){
    float wsc = __expf(m[s]-ms);
    lsum += wsc*lv[s];
    o += wsc*Opart[((size_t)(bh*4+s)*SEQ + q)*64 + lane];
  }
  size_t token = (size_t)(bh>>2)*SEQ + q;
  attn_bf[token*DM + (bh&3)*HD + lane] = f2bf(o/lsum);
}

// ---------------- final: out = x + g*ssm + (1-g)*attn ----------------
__global__ __launch_bounds__(256) void final_kernel(const float* __restrict__ x,
    const float* __restrict__ cat, const float* __restrict__ gate,
    float* __restrict__ out) {
  int idx = blockIdx.x*256 + threadIdx.x;
  int token = idx >> 6;
  int q = (idx & 63)*4;
  float4 g4 = *(const float4*)&gate[(size_t)token*DM + q];
  float4 s4 = *(const float4*)&cat[(size_t)token*512 + q];
  float4 a4 = *(const float4*)&cat[(size_t)token*512 + 256 + q];
  float4 x4 = *(const float4*)&x[(size_t)token*DM + q];
  float4 o;
  o.x = x4.x + g4.x*s4.x + (1.f-g4.x)*a4.x;
  o.y = x4.y + g4.y*s4.y + (1.f-g4.y)*a4.y;
  o.z = x4.z + g4.z*s4.z + (1.f-g4.z)*a4.z;
  o.w = x4.w + g4.w*s4.w + (1.f-g4.w)*a4.w;
  *(float4*)&out[(size_t)token*DM + q] = o;
}

extern "C" void kernel_launch(void* const* d_in, const int* in_sizes, int n_in,
                              void* d_out, int out_size, void* d_ws, size_t ws_size,
                              hipStream_t stream) {
  const float* x      = (const float*)d_in[0];
  const float* ln_g   = (const float*)d_in[1];
  const float* ln_b   = (const float*)d_in[2];
  const float* W_in   = (const float*)d_in[3];
  const float* conv_w = (const float*)d_in[4];
  const float* conv_b = (const float*)d_in[5];
  const float* W_xproj= (const float*)d_in[6];
  const float* W_dt   = (const float*)d_in[7];
  const float* b_dt   = (const float*)d_in[8];
  const float* A_log  = (const float*)d_in[9];
  const float* Dp     = (const float*)d_in[10];
  const float* W_out_m= (const float*)d_in[11];
  const float* W_qkv  = (const float*)d_in[12];
  const float* b_qkv  = (const float*)d_in[13];
  const float* W_o    = (const float*)d_in[14];
  const float* b_o    = (const float*)d_in[15];
  const float* W_gate = (const float*)d_in[16];
  const float* b_gate = (const float*)d_in[17];
  float* out = (float*)d_out;

  float* ws = (float*)d_ws;
  // float-unit offsets
  u16*   xn_bf   = (u16*)(ws);                       // 2,097,152 u (1,048,576 f)
  float* xz      = ws + 1048576;                     // 8,388,608 f
  u16*   qkv_bf  = (u16*)(ws + 9437184);             // 6,291,456 u
  float* xc      = ws + 12582912;                    // 4,194,304
  float* dblb    = ws + 16777216;                    //   393,216
  float* dtb     = ws + 17170432;                    // 4,194,304
  u16*   ygate_bf= (u16*)(ws + 21364736);            // 4,194,304 u
  u16*   attn_bf = (u16*)(ws + 23461888);            // 2,097,152 u
  float* catb    = ws + 24510464;                    // 4,194,304
  u16*   catb_bf = (u16*)(ws + 28704768);            // 4,194,304 u
  float* gateb   = ws + 30801920;                    // 2,097,152
  u16*   Wt_all  = (u16*)(ws + 32899072);            //   786,432 u
  // aliases (lifetime-disjoint):
  float* Opart = xz;                 // attention partials after xz dead (post scan_pass2)
  float* mlb   = (float*)xn_bf;      // 262,144 f, after xn_bf dead (post qkv gemm)
  float* Pws   = catb;               // scan summaries before catb written
  float* Hws   = catb + 524288;
  float* H0ws  = catb + 1048576;

  u16* Wt_in   = Wt_all;             // 1024x256
  u16* Wt_qkv  = Wt_all + 262144;    // 768x256
  u16* Wt_out  = Wt_all + 458752;    // 256x512
  u16* Wt_o    = Wt_all + 589824;    // 256x256
  u16* Wt_gate = Wt_all + 655360;    // 256x512

  tcvt_kernel<<<dim3(16,256), 64, 0, stream>>>(W_in,    Wt_in,   1024, 256);
  tcvt_kernel<<<dim3(12,256), 64, 0, stream>>>(W_qkv,   Wt_qkv,   768, 256);
  tcvt_kernel<<<dim3(4,512),  64, 0, stream>>>(W_out_m, Wt_out,   256, 512);
  tcvt_kernel<<<dim3(4,256),  64, 0, stream>>>(W_o,     Wt_o,     256, 256);
  tcvt_kernel<<<dim3(4,512),  64, 0, stream>>>(W_gate,  Wt_gate,  256, 512);

  ln_kernel<<<T_TOK/4, 256, 0, stream>>>(x, ln_g, ln_b, xn_bf);
  gemm_mfma<0><<<dim3(16,64), 256, 0, stream>>>(xn_bf, Wt_in, nullptr, xz, nullptr, 256, 1024);
  gemm_mfma<0><<<dim3(12,64), 256, 0, stream>>>(xn_bf, Wt_qkv, b_qkv, nullptr, qkv_bf, 256, 768);
  conv_kernel<<<T_TOK*DI/256, 256, 0, stream>>>(xz, conv_w, conv_b, xc);
  xproj_dt_kernel<<<T_TOK/4, 256, 0, stream>>>(xc, W_xproj, W_dt, b_dt, dblb, dtb);
  scan_pass1<<<2048, 256, 0, stream>>>(xc, dtb, dblb, A_log, Pws, Hws);
  scan_combine<<<128, 256, 0, stream>>>(Pws, Hws, H0ws);
  scan_pass2<<<2048, 256, 0, stream>>>(xc, dtb, dblb, A_log, Dp, xz, H0ws, ygate_bf);
  attn_mfma_kernel<<<dim3(SEQ/64, 16, 4), 256, 0, stream>>>(qkv_bf, Opart, mlb);
  attn_merge_kernel<<<8192, 256, 0, stream>>>(Opart, mlb, attn_bf);
  gemm_mfma<0><<<dim3(4,64), 256, 0, stream>>>(ygate_bf, Wt_out, nullptr, catb, catb_bf, 512, 512);
  gemm_mfma<0><<<dim3(4,64), 256, 0, stream>>>(attn_bf, Wt_o, b_o, catb+256, catb_bf+256, 256, 512);
  gemm_mfma<1><<<dim3(4,64), 256, 0, stream>>>(catb_bf, Wt_gate, b_gate, gateb, nullptr, 512, 256);
  final_kernel<<<T_TOK*64/256, 256, 0, stream>>>(x, catb, gateb, out);
}

// Round 5
// 337.334 us; speedup vs baseline: 7.2432x; 1.2347x over previous
//
#include <hip/hip_runtime.h>
#include <math.h>

#define B_SZ 4
#define SEQ 2048
#define DM 256
#define DI 512
#define DS 16
#define DTR 16
#define NH 4
#define HD 64
#define T_TOK (B_SZ*SEQ)   // 8192
#define NCH 64             // scan time-chunks
#define CL (SEQ/NCH)       // 32

typedef short bf16x8 __attribute__((ext_vector_type(8)));
typedef float f32x4  __attribute__((ext_vector_type(4)));
typedef unsigned short u16;

__device__ __forceinline__ float sigmoidf_(float x){ return 1.f/(1.f+__expf(-x)); }
__device__ __forceinline__ u16 f2bf(float x){
  unsigned int u = __float_as_uint(x);
  u += 0x7fffu + ((u>>16)&1u);
  return (u16)(u>>16);
}

// ---------------- weight transpose+convert: dst[n][k] = bf16(src[k][n]) ----------------
__global__ __launch_bounds__(64) void tcvt_kernel(const float* __restrict__ src,
    u16* __restrict__ dst, int N, int K) {
  int n = blockIdx.x*64 + threadIdx.x;
  int k = blockIdx.y;
  dst[(size_t)n*K + k] = f2bf(src[(size_t)k*N + n]);
}

// ---------------- LayerNorm: one wave per token -> bf16 ----------------
__global__ __launch_bounds__(256) void ln_kernel(const float* __restrict__ x,
    const float* __restrict__ g, const float* __restrict__ b,
    u16* __restrict__ xn_bf) {
  int wid = threadIdx.x >> 6;
  int lane = threadIdx.x & 63;
  int token = blockIdx.x*4 + wid;
  const float* xr = x + (size_t)token*DM;
  float4 v = *(const float4*)&xr[lane*4];
  float s  = v.x+v.y+v.z+v.w;
  float ss = v.x*v.x+v.y*v.y+v.z*v.z+v.w*v.w;
  for (int m=1;m<64;m<<=1){ s += __shfl_xor(s,m); ss += __shfl_xor(ss,m); }
  float mu  = s * (1.f/DM);
  float var = ss*(1.f/DM) - mu*mu;
  float rs  = rsqrtf(var + 1e-5f);
  float4 gv = *(const float4*)&g[lane*4];
  float4 bv = *(const float4*)&b[lane*4];
  ushort4 o;
  o.x = f2bf((v.x-mu)*rs*gv.x + bv.x);
  o.y = f2bf((v.y-mu)*rs*gv.y + bv.y);
  o.z = f2bf((v.z-mu)*rs*gv.z + bv.z);
  o.w = f2bf((v.w-mu)*rs*gv.w + bv.w);
  *(ushort4*)&xn_bf[(size_t)token*DM + lane*4] = o;
}

// ---------------- MFMA bf16 GEMM: C[M,N] = A[M,K](bf16) @ Wt[N,K](bf16) ----------------
template<int ACT>  // 0=none, 1=sigmoid
__global__ __launch_bounds__(256) void gemm_mfma(const u16* __restrict__ A,
    const u16* __restrict__ Wt, const float* __restrict__ bias,
    float* __restrict__ C, u16* __restrict__ Cbf, int K, int ldc) {
  __shared__ u16 lds[12288];    // As 128x64 @0 (8192), Bs 64x64 @8192 (4096)
  int tid = threadIdx.x;
  int m0 = blockIdx.y*128, n0 = blockIdx.x*64;
  int w = tid>>6, l = tid&63, lq = l&15, lg = l>>4;
  int wm = w>>1, wn = w&1;
  f32x4 acc[4][2] = {};
  for (int k0 = 0; k0 < K; k0 += 64) {
#pragma unroll
    for (int i=0;i<4;++i){
      int gid = i*256 + tid;
      int row = gid>>3, g = gid&7;
      *(bf16x8*)&lds[row*64 + ((g ^ (row&7))*8)] =
          *(const bf16x8*)&A[(size_t)(m0+row)*K + k0 + g*8];
    }
#pragma unroll
    for (int i=0;i<2;++i){
      int gid = i*256 + tid;
      int row = gid>>3, g = gid&7;
      *(bf16x8*)&lds[8192 + row*64 + ((g ^ (row&7))*8)] =
          *(const bf16x8*)&Wt[(size_t)(n0+row)*K + k0 + g*8];
    }
    __syncthreads();
#pragma unroll
    for (int ks=0;ks<2;++ks){
      bf16x8 af[4], bfv[2];
#pragma unroll
      for (int mi=0;mi<4;++mi){
        int row = wm*64 + mi*16 + lq;
        af[mi] = *(bf16x8*)&lds[row*64 + (((ks*4+lg) ^ (row&7))*8)];
      }
#pragma unroll
      for (int nj=0;nj<2;++nj){
        int row = wn*32 + nj*16 + lq;
        bfv[nj] = *(bf16x8*)&lds[8192 + row*64 + (((ks*4+lg) ^ (row&7))*8)];
      }
#pragma unroll
      for (int mi=0;mi<4;++mi)
#pragma unroll
        for (int nj=0;nj<2;++nj)
          acc[mi][nj] = __builtin_amdgcn_mfma_f32_16x16x32_bf16(af[mi], bfv[nj], acc[mi][nj], 0,0,0);
    }
    __syncthreads();
  }
#pragma unroll
  for (int mi=0;mi<4;++mi){
#pragma unroll
    for (int nj=0;nj<2;++nj){
#pragma unroll
      for (int r=0;r<4;++r){
        int row = m0 + wm*64 + mi*16 + lg*4 + r;
        int col = n0 + wn*32 + nj*16 + lq;
        float v = acc[mi][nj][r];
        if (bias) v += bias[col];
        if (ACT==1) v = sigmoidf_(v);
        if (C)   C[(size_t)row*ldc + col] = v;
        if (Cbf) Cbf[(size_t)row*ldc + col] = f2bf(v);
      }
    }
  }
}

// ---------------- depthwise conv (k=4) + SiLU ----------------
__global__ __launch_bounds__(256) void conv_kernel(const float* __restrict__ xz,
    const float* __restrict__ cw, const float* __restrict__ cb,
    float* __restrict__ xc) {
  int idx = blockIdx.x*256 + threadIdx.x;  // t*512 + d
  int d = idx & (DI-1);
  int t = idx >> 9;
  int l = t & (SEQ-1);
  float acc = cb[d];
  float w0=cw[d*4+0], w1=cw[d*4+1], w2=cw[d*4+2], w3=cw[d*4+3];
  const float* base = xz + (size_t)t*1024 + d;
  if (l>=3) acc += base[-3*1024]*w0;
  if (l>=2) acc += base[-2*1024]*w1;
  if (l>=1) acc += base[-1*1024]*w2;
  acc += base[0]*w3;
  xc[idx] = acc * sigmoidf_(acc);
}

// ---------------- x_proj (512->48) + dt = softplus ----------------
__global__ __launch_bounds__(256) void xproj_dt_kernel(const float* __restrict__ xc,
    const float* __restrict__ Wx, const float* __restrict__ Wdt,
    const float* __restrict__ bdt, float* __restrict__ dbl, float* __restrict__ dt) {
  __shared__ float sxc[4][DI];
  __shared__ float sdbl[4][48];
  int wid = threadIdx.x>>6, lane = threadIdx.x&63;
  int token = blockIdx.x*4 + wid;
  {
    float4 a = *(const float4*)&xc[(size_t)token*DI + lane*4];
    float4 b = *(const float4*)&xc[(size_t)token*DI + 256 + lane*4];
    *(float4*)&sxc[wid][lane*4]       = a;
    *(float4*)&sxc[wid][256 + lane*4] = b;
  }
  __syncthreads();
  if (lane < 48) {
    float acc = 0.f;
    for (int k=0;k<DI;++k) acc += sxc[wid][k]*Wx[k*48+lane];
    dbl[(size_t)token*48+lane] = acc;
    sdbl[wid][lane] = acc;
  }
  __syncthreads();
#pragma unroll
  for (int r=0;r<8;++r){
    int d = lane + r*64;
    float acc = bdt[d];
#pragma unroll
    for (int k=0;k<DTR;++k) acc += sdbl[wid][k]*Wdt[k*DI+d];
    float sp = (acc > 20.f) ? acc : log1pf(__expf(acc));
    dt[(size_t)token*DI+d] = sp;
  }
}

// ---------------- chunked selective scan, thread-per-channel (16 states in regs) ----------------
// Block: 512 threads = one (b, c) pair, thread = d. B/C staged in LDS.
__global__ __launch_bounds__(512) void scan_p1(const float* __restrict__ xc,
    const float* __restrict__ dt, const float* __restrict__ dbl,
    const float* __restrict__ A_log, float* __restrict__ Pws, float* __restrict__ Hws) {
  __shared__ float sB[CL][16];
  int d = threadIdx.x;
  int bc = blockIdx.x;          // 0..255
  int b = bc >> 6, c = bc & 63;
  {
    int t = threadIdx.x >> 4, n = threadIdx.x & 15;
    sB[t][n] = dbl[((size_t)b*SEQ + c*CL + t)*48 + DTR + n];
  }
  __syncthreads();
  float An[16];
#pragma unroll
  for (int i=0;i<4;++i){
    float4 a = *(const float4*)&A_log[d*16 + i*4];
    An[i*4+0] = -__expf(a.x); An[i*4+1] = -__expf(a.y);
    An[i*4+2] = -__expf(a.z); An[i*4+3] = -__expf(a.w);
  }
  float h[16] = {};
  float P[16];
#pragma unroll
  for (int n=0;n<16;++n) P[n] = 1.f;
  size_t tok = (size_t)b*SEQ + c*CL;
  for (int t=0;t<CL;++t,++tok){
    float dtv = dt[tok*DI+d];
    float xcv = xc[tok*DI+d];
    float u = dtv*xcv;
    float4 B0 = *(float4*)&sB[t][0];
    float4 B1 = *(float4*)&sB[t][4];
    float4 B2 = *(float4*)&sB[t][8];
    float4 B3 = *(float4*)&sB[t][12];
    float Bv[16] = {B0.x,B0.y,B0.z,B0.w,B1.x,B1.y,B1.z,B1.w,
                    B2.x,B2.y,B2.z,B2.w,B3.x,B3.y,B3.z,B3.w};
#pragma unroll
    for (int n=0;n<16;++n){
      float e = __expf(dtv*An[n]);
      P[n] *= e;
      h[n] = e*h[n] + u*Bv[n];
    }
  }
  size_t base = (((size_t)b*NCH + c)*DI + d)*16;
#pragma unroll
  for (int n=0;n<16;++n){ Pws[base+n] = P[n]; Hws[base+n] = h[n]; }
}

__global__ __launch_bounds__(256) void scan_combine(const float* __restrict__ Pws,
    const float* __restrict__ Hws, float* __restrict__ H0ws) {
  int gid = blockIdx.x*256 + threadIdx.x;  // 0..32767 = (b, d*16+n)
  int b  = gid >> 13;
  int dn = gid & 8191;
  float h0 = 0.f;
#pragma unroll 4
  for (int c=0;c<NCH;++c){
    size_t idx = ((size_t)(b*NCH+c)<<13) + dn;
    H0ws[idx] = h0;
    h0 = Pws[idx]*h0 + Hws[idx];
  }
}

__global__ __launch_bounds__(512) void scan_p2(const float* __restrict__ xc,
    const float* __restrict__ dt, const float* __restrict__ dbl,
    const float* __restrict__ A_log, const float* __restrict__ Dp,
    const float* __restrict__ xz, const float* __restrict__ H0ws,
    u16* __restrict__ ygate_bf) {
  __shared__ float sBC[CL][32];
  int d = threadIdx.x;
  int bc = blockIdx.x;
  int b = bc >> 6, c = bc & 63;
#pragma unroll
  for (int i=0;i<2;++i){
    int idx = i*512 + threadIdx.x;
    int t = idx >> 5, q = idx & 31;
    sBC[t][q] = dbl[((size_t)b*SEQ + c*CL + t)*48 + DTR + q];
  }
  __syncthreads();
  float An[16];
#pragma unroll
  for (int i=0;i<4;++i){
    float4 a = *(const float4*)&A_log[d*16 + i*4];
    An[i*4+0] = -__expf(a.x); An[i*4+1] = -__expf(a.y);
    An[i*4+2] = -__expf(a.z); An[i*4+3] = -__expf(a.w);
  }
  float Dd = Dp[d];
  float h[16];
  size_t base = (((size_t)b*NCH + c)*DI + d)*16;
#pragma unroll
  for (int i=0;i<4;++i){
    float4 h4 = *(const float4*)&H0ws[base + i*4];
    h[i*4+0]=h4.x; h[i*4+1]=h4.y; h[i*4+2]=h4.z; h[i*4+3]=h4.w;
  }
  size_t tok = (size_t)b*SEQ + c*CL;
  for (int t=0;t<CL;++t,++tok){
    float dtv = dt[tok*DI+d];
    float xcv = xc[tok*DI+d];
    float zv  = xz[tok*1024 + DI + d];
    float u = dtv*xcv;
    float4 B0 = *(float4*)&sBC[t][0];
    float4 B1 = *(float4*)&sBC[t][4];
    float4 B2 = *(float4*)&sBC[t][8];
    float4 B3 = *(float4*)&sBC[t][12];
    float4 C0 = *(float4*)&sBC[t][16];
    float4 C1 = *(float4*)&sBC[t][20];
    float4 C2 = *(float4*)&sBC[t][24];
    float4 C3 = *(float4*)&sBC[t][28];
    float Bv[16] = {B0.x,B0.y,B0.z,B0.w,B1.x,B1.y,B1.z,B1.w,
                    B2.x,B2.y,B2.z,B2.w,B3.x,B3.y,B3.z,B3.w};
    float Cv[16] = {C0.x,C0.y,C0.z,C0.w,C1.x,C1.y,C1.z,C1.w,
                    C2.x,C2.y,C2.z,C2.w,C3.x,C3.y,C3.z,C3.w};
    float y = 0.f;
#pragma unroll
    for (int n=0;n<16;++n){
      float e = __expf(dtv*An[n]);
      h[n] = e*h[n] + u*Bv[n];
      y += h[n]*Cv[n];
    }
    y += xcv*Dd;
    ygate_bf[tok*DI + d] = f2bf(y * (zv*sigmoidf_(zv)));
  }
}

// ---------------- MFMA bf16 flash attention, KV-split 4 ----------------
__global__ __launch_bounds__(256) void attn_mfma_kernel(const u16* __restrict__ qkvb,
    float* __restrict__ Opart, float* __restrict__ ml) {
  __shared__ u16 lds[12288];   // K 64x64 @0, V_T 64x64 @4096, P per-wave @8192+w*1024
  int bh = blockIdx.y; int b = bh>>2, h = bh&3;
  int s = blockIdx.z;
  int tid = threadIdx.x;
  int w = tid>>6, l = tid&63;
  int lq = l & 15;
  int lg = l >> 4;
  size_t bbase = (size_t)b*SEQ;
  int q0 = blockIdx.x*64 + w*16;

  bf16x8 qf[2];
#pragma unroll
  for (int dsl=0; dsl<2; ++dsl)
    qf[dsl] = *(const bf16x8*)&qkvb[(bbase + q0 + lq)*768 + h*HD + lg*8 + dsl*32];

  float mrow[4] = {-1e30f,-1e30f,-1e30f,-1e30f};
  float lrow[4] = {0.f,0.f,0.f,0.f};
  f32x4 oacc[4] = {{0,0,0,0},{0,0,0,0},{0,0,0,0},{0,0,0,0}};
  int pbase = 8192 + w*1024;

  for (int kt=s*8; kt<s*8+8; ++kt){
    __syncthreads();
#pragma unroll
    for (int i=0;i<2;++i){
      int gid = i*256 + tid;
      int row = gid>>3, g = gid&7;
      *(bf16x8*)&lds[row*64 + ((g ^ (row&7))*8)] =
          *(const bf16x8*)&qkvb[(bbase + kt*64 + row)*768 + 256 + h*HD + g*8];
    }
#pragma unroll
    for (int i=0;i<8;++i){
      int u = i*256 + tid;
      int d = u&63, k2 = (u>>6)*2;
      u16 s0 = qkvb[(bbase + kt*64 + k2    )*768 + 512 + h*HD + d];
      u16 s1 = qkvb[(bbase + kt*64 + k2 + 1)*768 + 512 + h*HD + d];
      unsigned pk = (unsigned)s0 | ((unsigned)s1<<16);
      *(unsigned*)&lds[4096 + d*64 + (((k2>>3) ^ (d&7))*8) + (k2&7)] = pk;
    }
    __syncthreads();

    f32x4 sacc[4] = {{0,0,0,0},{0,0,0,0},{0,0,0,0},{0,0,0,0}};
    __builtin_amdgcn_s_setprio(1);
#pragma unroll
    for (int kg=0;kg<4;++kg){
#pragma unroll
      for (int dsl=0;dsl<2;++dsl){
        int row = kg*16 + lq;
        bf16x8 kf = *(bf16x8*)&lds[row*64 + (((dsl*4 + lg) ^ (row&7))*8)];
        sacc[kg] = __builtin_amdgcn_mfma_f32_16x16x32_bf16(qf[dsl], kf, sacc[kg], 0,0,0);
      }
    }
    __builtin_amdgcn_s_setprio(0);
    float pv[4][4];
#pragma unroll
    for (int r=0;r<4;++r){
      float tm = fmaxf(fmaxf(sacc[0][r],sacc[1][r]),fmaxf(sacc[2][r],sacc[3][r]));
      tm *= 0.125f;
      tm = fmaxf(tm, __shfl_xor(tm,1));
      tm = fmaxf(tm, __shfl_xor(tm,2));
      tm = fmaxf(tm, __shfl_xor(tm,4));
      tm = fmaxf(tm, __shfl_xor(tm,8));
      float mn = fmaxf(mrow[r], tm);
      float sc = __expf(mrow[r] - mn);
      mrow[r] = mn;
      float ps = 0.f;
#pragma unroll
      for (int kg=0;kg<4;++kg){
        float p = __expf(sacc[kg][r]*0.125f - mn);
        pv[kg][r] = p;
        ps += p;
      }
      ps += __shfl_xor(ps,1);
      ps += __shfl_xor(ps,2);
      ps += __shfl_xor(ps,4);
      ps += __shfl_xor(ps,8);
      lrow[r] = lrow[r]*sc + ps;
#pragma unroll
      for (int dg=0;dg<4;++dg) oacc[dg][r] *= sc;
    }
#pragma unroll
    for (int kg=0;kg<4;++kg){
      int k = kg*16 + lq;
#pragma unroll
      for (int r=0;r<4;++r){
        int row = lg*4 + r;
        lds[pbase + row*64 + (((k>>3) ^ (row&7))*8) + (k&7)] = f2bf(pv[kg][r]);
      }
    }
    __builtin_amdgcn_s_setprio(1);
#pragma unroll
    for (int ks=0;ks<2;++ks){
      bf16x8 pf = *(bf16x8*)&lds[pbase + lq*64 + (((ks*4 + lg) ^ (lq&7))*8)];
#pragma unroll
      for (int dg=0;dg<4;++dg){
        int row = dg*16 + lq;
        bf16x8 vf = *(bf16x8*)&lds[4096 + row*64 + (((ks*4 + lg) ^ (row&7))*8)];
        oacc[dg] = __builtin_amdgcn_mfma_f32_16x16x32_bf16(pf, vf, oacc[dg], 0,0,0);
      }
    }
    __builtin_amdgcn_s_setprio(0);
  }

  int sidx = bh*4 + s;
#pragma unroll
  for (int r=0;r<4;++r){
    int q = q0 + lg*4 + r;
    size_t rb = ((size_t)sidx*SEQ + q)*64;
#pragma unroll
    for (int dg=0;dg<4;++dg) Opart[rb + dg*16 + lq] = oacc[dg][r];
    if (lq==0){
      ml[((size_t)sidx*SEQ + q)*2    ] = mrow[r];
      ml[((size_t)sidx*SEQ + q)*2 + 1] = lrow[r];
    }
  }
}

// ---------------- merge 4 KV-chunk partials -> bf16 attn_o ----------------
__global__ __launch_bounds__(256) void attn_merge_kernel(const float* __restrict__ Opart,
    const float* __restrict__ ml, u16* __restrict__ attn_bf) {
  int w = threadIdx.x>>6, lane = threadIdx.x&63;
  int R = blockIdx.x*4 + w;        // 0..32767
  int bh = R>>11, q = R&2047;
  float m[4], lv[4];
#pragma unroll
  for (int s=0;s<4;++s){
    m[s]  = ml[((size_t)(bh*4+s)*SEQ + q)*2];
    lv[s] = ml[((size_t)(bh*4+s)*SEQ + q)*2 + 1];
  }
  float ms = fmaxf(fmaxf(m[0],m[1]),fmaxf(m[2],m[3]));
  float o = 0.f, lsum = 0.f;
#pragma unroll
  for (int s=0;s<4;++s){
    float wsc = __expf(m[s]-ms);
    lsum += wsc*lv[s];
    o += wsc*Opart[((size_t)(bh*4+s)*SEQ + q)*64 + lane];
  }
  size_t token = (size_t)(bh>>2)*SEQ + q;
  attn_bf[token*DM + (bh&3)*HD + lane] = f2bf(o/lsum);
}

// ---------------- final: out = x + g*ssm + (1-g)*attn ----------------
__global__ __launch_bounds__(256) void final_kernel(const float* __restrict__ x,
    const float* __restrict__ cat, const float* __restrict__ gate,
    float* __restrict__ out) {
  int idx = blockIdx.x*256 + threadIdx.x;
  int token = idx >> 6;
  int q = (idx & 63)*4;
  float4 g4 = *(const float4*)&gate[(size_t)token*DM + q];
  float4 s4 = *(const float4*)&cat[(size_t)token*512 + q];
  float4 a4 = *(const float4*)&cat[(size_t)token*512 + 256 + q];
  float4 x4 = *(const float4*)&x[(size_t)token*DM + q];
  float4 o;
  o.x = x4.x + g4.x*s4.x + (1.f-g4.x)*a4.x;
  o.y = x4.y + g4.y*s4.y + (1.f-g4.y)*a4.y;
  o.z = x4.z + g4.z*s4.z + (1.f-g4.z)*a4.z;
  o.w = x4.w + g4.w*s4.w + (1.f-g4.w)*a4.w;
  *(float4*)&out[(size_t)token*DM + q] = o;
}

extern "C" void kernel_launch(void* const* d_in, const int* in_sizes, int n_in,
                              void* d_out, int out_size, void* d_ws, size_t ws_size,
                              hipStream_t stream) {
  const float* x      = (const float*)d_in[0];
  const float* ln_g   = (const float*)d_in[1];
  const float* ln_b   = (const float*)d_in[2];
  const float* W_in   = (const float*)d_in[3];
  const float* conv_w = (const float*)d_in[4];
  const float* conv_b = (const float*)d_in[5];
  const float* W_xproj= (const float*)d_in[6];
  const float* W_dt   = (const float*)d_in[7];
  const float* b_dt   = (const float*)d_in[8];
  const float* A_log  = (const float*)d_in[9];
  const float* Dp     = (const float*)d_in[10];
  const float* W_out_m= (const float*)d_in[11];
  const float* W_qkv  = (const float*)d_in[12];
  const float* b_qkv  = (const float*)d_in[13];
  const float* W_o    = (const float*)d_in[14];
  const float* b_o    = (const float*)d_in[15];
  const float* W_gate = (const float*)d_in[16];
  const float* b_gate = (const float*)d_in[17];
  float* out = (float*)d_out;

  float* ws = (float*)d_ws;
  u16*   xn_bf   = (u16*)(ws);                       // 2,097,152 u
  float* xz      = ws + 1048576;                     // 8,388,608 f
  u16*   qkv_bf  = (u16*)(ws + 9437184);             // 6,291,456 u
  float* xc      = ws + 12582912;                    // 4,194,304
  float* dblb    = ws + 16777216;                    //   393,216
  float* dtb     = ws + 17170432;                    // 4,194,304
  u16*   ygate_bf= (u16*)(ws + 21364736);            // 4,194,304 u
  u16*   attn_bf = (u16*)(ws + 23461888);            // 2,097,152 u
  float* catb    = ws + 24510464;                    // 4,194,304
  u16*   catb_bf = (u16*)(ws + 28704768);            // 4,194,304 u
  float* gateb   = ws + 30801920;                    // 2,097,152
  u16*   Wt_all  = (u16*)(ws + 32899072);            //   786,432 u
  // aliases (lifetime-disjoint):
  float* Opart = xz;                 // attention partials after xz dead (post scan_p2)
  float* mlb   = (float*)xn_bf;      // after xn_bf dead (post qkv gemm)
  float* Pws   = catb;               // 2,097,152 — scan summaries before catb written
  float* Hws   = catb + 2097152;     // 2,097,152 (into catb_bf region)
  float* H0ws  = catb + 4194304;     // 2,097,152 (catb_bf tail + gateb head)

  u16* Wt_in   = Wt_all;             // 1024x256
  u16* Wt_qkv  = Wt_all + 262144;    // 768x256
  u16* Wt_out  = Wt_all + 458752;    // 256x512
  u16* Wt_o    = Wt_all + 589824;    // 256x256
  u16* Wt_gate = Wt_all + 655360;    // 256x512

  tcvt_kernel<<<dim3(16,256), 64, 0, stream>>>(W_in,    Wt_in,   1024, 256);
  tcvt_kernel<<<dim3(12,256), 64, 0, stream>>>(W_qkv,   Wt_qkv,   768, 256);
  tcvt_kernel<<<dim3(4,512),  64, 0, stream>>>(W_out_m, Wt_out,   256, 512);
  tcvt_kernel<<<dim3(4,256),  64, 0, stream>>>(W_o,     Wt_o,     256, 256);
  tcvt_kernel<<<dim3(4,512),  64, 0, stream>>>(W_gate,  Wt_gate,  256, 512);

  ln_kernel<<<T_TOK/4, 256, 0, stream>>>(x, ln_g, ln_b, xn_bf);
  gemm_mfma<0><<<dim3(16,64), 256, 0, stream>>>(xn_bf, Wt_in, nullptr, xz, nullptr, 256, 1024);
  gemm_mfma<0><<<dim3(12,64), 256, 0, stream>>>(xn_bf, Wt_qkv, b_qkv, nullptr, qkv_bf, 256, 768);
  conv_kernel<<<T_TOK*DI/256, 256, 0, stream>>>(xz, conv_w, conv_b, xc);
  xproj_dt_kernel<<<T_TOK/4, 256, 0, stream>>>(xc, W_xproj, W_dt, b_dt, dblb, dtb);
  scan_p1<<<B_SZ*NCH, 512, 0, stream>>>(xc, dtb, dblb, A_log, Pws, Hws);
  scan_combine<<<128, 256, 0, stream>>>(Pws, Hws, H0ws);
  scan_p2<<<B_SZ*NCH, 512, 0, stream>>>(xc, dtb, dblb, A_log, Dp, xz, H0ws, ygate_bf);
  attn_mfma_kernel<<<dim3(SEQ/64, 16, 4), 256, 0, stream>>>(qkv_bf, Opart, mlb);
  attn_merge_kernel<<<8192, 256, 0, stream>>>(Opart, mlb, attn_bf);
  gemm_mfma<0><<<dim3(4,64), 256, 0, stream>>>(ygate_bf, Wt_out, nullptr, catb, catb_bf, 512, 512);
  gemm_mfma<0><<<dim3(4,64), 256, 0, stream>>>(attn_bf, Wt_o, b_o, catb+256, catb_bf+256, 256, 512);
  gemm_mfma<1><<<dim3(4,64), 256, 0, stream>>>(catb_bf, Wt_gate, b_gate, gateb, nullptr, 512, 256);
  final_kernel<<<T_TOK*64/256, 256, 0, stream>>>(x, catb, gateb, out);
}

// Round 6
// 276.032 us; speedup vs baseline: 8.8518x; 1.2221x over previous
//
#include <hip/hip_runtime.h>
#include <math.h>

#define B_SZ 4
#define SEQ 2048
#define DM 256
#define DI 512
#define DS 16
#define DTR 16
#define NH 4
#define HD 64
#define T_TOK (B_SZ*SEQ)   // 8192
#define NCH 64             // scan time-chunks
#define CL (SEQ/NCH)       // 32

typedef short bf16x8 __attribute__((ext_vector_type(8)));
typedef float f32x4  __attribute__((ext_vector_type(4)));
typedef unsigned short u16;

__device__ __forceinline__ float sigmoidf_(float x){ return 1.f/(1.f+__expf(-x)); }
__device__ __forceinline__ u16 f2bf(float x){
  unsigned int u = __float_as_uint(x);
  u += 0x7fffu + ((u>>16)&1u);
  return (u16)(u>>16);
}

// ---------------- weight transpose+convert: dst[n][k] = bf16(src[k][n]) ----------------
__global__ __launch_bounds__(64) void tcvt_kernel(const float* __restrict__ src,
    u16* __restrict__ dst, int N, int K) {
  int n = blockIdx.x*64 + threadIdx.x;
  int k = blockIdx.y;
  dst[(size_t)n*K + k] = f2bf(src[(size_t)k*N + n]);
}

// ---------------- LayerNorm: one wave per token -> bf16 ----------------
__global__ __launch_bounds__(256) void ln_kernel(const float* __restrict__ x,
    const float* __restrict__ g, const float* __restrict__ b,
    u16* __restrict__ xn_bf) {
  int wid = threadIdx.x >> 6;
  int lane = threadIdx.x & 63;
  int token = blockIdx.x*4 + wid;
  const float* xr = x + (size_t)token*DM;
  float4 v = *(const float4*)&xr[lane*4];
  float s  = v.x+v.y+v.z+v.w;
  float ss = v.x*v.x+v.y*v.y+v.z*v.z+v.w*v.w;
  for (int m=1;m<64;m<<=1){ s += __shfl_xor(s,m); ss += __shfl_xor(ss,m); }
  float mu  = s * (1.f/DM);
  float var = ss*(1.f/DM) - mu*mu;
  float rs  = rsqrtf(var + 1e-5f);
  float4 gv = *(const float4*)&g[lane*4];
  float4 bv = *(const float4*)&b[lane*4];
  ushort4 o;
  o.x = f2bf((v.x-mu)*rs*gv.x + bv.x);
  o.y = f2bf((v.y-mu)*rs*gv.y + bv.y);
  o.z = f2bf((v.z-mu)*rs*gv.z + bv.z);
  o.w = f2bf((v.w-mu)*rs*gv.w + bv.w);
  *(ushort4*)&xn_bf[(size_t)token*DM + lane*4] = o;
}

// ---------------- MFMA bf16 GEMM: C[M,N] = A[M,K](bf16) @ Wt[N,K](bf16) ----------------
template<int ACT>  // 0=none, 1=sigmoid
__global__ __launch_bounds__(256) void gemm_mfma(const u16* __restrict__ A,
    const u16* __restrict__ Wt, const float* __restrict__ bias,
    float* __restrict__ C, u16* __restrict__ Cbf, int K, int ldc) {
  __shared__ u16 lds[12288];    // As 128x64 @0 (8192), Bs 64x64 @8192 (4096)
  int tid = threadIdx.x;
  int m0 = blockIdx.y*128, n0 = blockIdx.x*64;
  int w = tid>>6, l = tid&63, lq = l&15, lg = l>>4;
  int wm = w>>1, wn = w&1;
  f32x4 acc[4][2] = {};
  for (int k0 = 0; k0 < K; k0 += 64) {
#pragma unroll
    for (int i=0;i<4;++i){
      int gid = i*256 + tid;
      int row = gid>>3, g = gid&7;
      *(bf16x8*)&lds[row*64 + ((g ^ (row&7))*8)] =
          *(const bf16x8*)&A[(size_t)(m0+row)*K + k0 + g*8];
    }
#pragma unroll
    for (int i=0;i<2;++i){
      int gid = i*256 + tid;
      int row = gid>>3, g = gid&7;
      *(bf16x8*)&lds[8192 + row*64 + ((g ^ (row&7))*8)] =
          *(const bf16x8*)&Wt[(size_t)(n0+row)*K + k0 + g*8];
    }
    __syncthreads();
#pragma unroll
    for (int ks=0;ks<2;++ks){
      bf16x8 af[4], bfv[2];
#pragma unroll
      for (int mi=0;mi<4;++mi){
        int row = wm*64 + mi*16 + lq;
        af[mi] = *(bf16x8*)&lds[row*64 + (((ks*4+lg) ^ (row&7))*8)];
      }
#pragma unroll
      for (int nj=0;nj<2;++nj){
        int row = wn*32 + nj*16 + lq;
        bfv[nj] = *(bf16x8*)&lds[8192 + row*64 + (((ks*4+lg) ^ (row&7))*8)];
      }
#pragma unroll
      for (int mi=0;mi<4;++mi)
#pragma unroll
        for (int nj=0;nj<2;++nj)
          acc[mi][nj] = __builtin_amdgcn_mfma_f32_16x16x32_bf16(af[mi], bfv[nj], acc[mi][nj], 0,0,0);
    }
    __syncthreads();
  }
#pragma unroll
  for (int mi=0;mi<4;++mi){
#pragma unroll
    for (int nj=0;nj<2;++nj){
#pragma unroll
      for (int r=0;r<4;++r){
        int row = m0 + wm*64 + mi*16 + lg*4 + r;
        int col = n0 + wn*32 + nj*16 + lq;
        float v = acc[mi][nj][r];
        if (bias) v += bias[col];
        if (ACT==1) v = sigmoidf_(v);
        if (C)   C[(size_t)row*ldc + col] = v;
        if (Cbf) Cbf[(size_t)row*ldc + col] = f2bf(v);
      }
    }
  }
}

// ---------------- depthwise conv (k=4) + SiLU ----------------
__global__ __launch_bounds__(256) void conv_kernel(const float* __restrict__ xz,
    const float* __restrict__ cw, const float* __restrict__ cb,
    float* __restrict__ xc) {
  int idx = blockIdx.x*256 + threadIdx.x;  // t*512 + d
  int d = idx & (DI-1);
  int t = idx >> 9;
  int l = t & (SEQ-1);
  float acc = cb[d];
  float w0=cw[d*4+0], w1=cw[d*4+1], w2=cw[d*4+2], w3=cw[d*4+3];
  const float* base = xz + (size_t)t*1024 + d;
  if (l>=3) acc += base[-3*1024]*w0;
  if (l>=2) acc += base[-2*1024]*w1;
  if (l>=1) acc += base[-1*1024]*w2;
  acc += base[0]*w3;
  xc[idx] = acc * sigmoidf_(acc);
}

// ---------------- x_proj (512->48) + dt = softplus ----------------
__global__ __launch_bounds__(256) void xproj_dt_kernel(const float* __restrict__ xc,
    const float* __restrict__ Wx, const float* __restrict__ Wdt,
    const float* __restrict__ bdt, float* __restrict__ dbl, float* __restrict__ dt) {
  __shared__ float sxc[4][DI];
  __shared__ float sdbl[4][48];
  int wid = threadIdx.x>>6, lane = threadIdx.x&63;
  int token = blockIdx.x*4 + wid;
  {
    float4 a = *(const float4*)&xc[(size_t)token*DI + lane*4];
    float4 b = *(const float4*)&xc[(size_t)token*DI + 256 + lane*4];
    *(float4*)&sxc[wid][lane*4]       = a;
    *(float4*)&sxc[wid][256 + lane*4] = b;
  }
  __syncthreads();
  if (lane < 48) {
    float acc = 0.f;
    for (int k=0;k<DI;++k) acc += sxc[wid][k]*Wx[k*48+lane];
    dbl[(size_t)token*48+lane] = acc;
    sdbl[wid][lane] = acc;
  }
  __syncthreads();
#pragma unroll
  for (int r=0;r<8;++r){
    int d = lane + r*64;
    float acc = bdt[d];
#pragma unroll
    for (int k=0;k<DTR;++k) acc += sdbl[wid][k]*Wdt[k*DI+d];
    float sp = (acc > 20.f) ? acc : log1pf(__expf(acc));
    dt[(size_t)token*DI+d] = sp;
  }
}

// ---------------- chunked selective scan, thread-per-channel ----------------
__global__ __launch_bounds__(512) void scan_p1(const float* __restrict__ xc,
    const float* __restrict__ dt, const float* __restrict__ dbl,
    const float* __restrict__ A_log, float* __restrict__ Pws, float* __restrict__ Hws) {
  __shared__ float sB[CL][16];
  int d = threadIdx.x;
  int bc = blockIdx.x;          // 0..255
  int b = bc >> 6, c = bc & 63;
  {
    int t = threadIdx.x >> 4, n = threadIdx.x & 15;
    sB[t][n] = dbl[((size_t)b*SEQ + c*CL + t)*48 + DTR + n];
  }
  __syncthreads();
  float An[16];
#pragma unroll
  for (int i=0;i<4;++i){
    float4 a = *(const float4*)&A_log[d*16 + i*4];
    An[i*4+0] = -__expf(a.x); An[i*4+1] = -__expf(a.y);
    An[i*4+2] = -__expf(a.z); An[i*4+3] = -__expf(a.w);
  }
  float h[16] = {};
  float P[16];
#pragma unroll
  for (int n=0;n<16;++n) P[n] = 1.f;
  size_t tok = (size_t)b*SEQ + c*CL;
  for (int t=0;t<CL;++t,++tok){
    float dtv = dt[tok*DI+d];
    float xcv = xc[tok*DI+d];
    float u = dtv*xcv;
    float4 B0 = *(float4*)&sB[t][0];
    float4 B1 = *(float4*)&sB[t][4];
    float4 B2 = *(float4*)&sB[t][8];
    float4 B3 = *(float4*)&sB[t][12];
    float Bv[16] = {B0.x,B0.y,B0.z,B0.w,B1.x,B1.y,B1.z,B1.w,
                    B2.x,B2.y,B2.z,B2.w,B3.x,B3.y,B3.z,B3.w};
#pragma unroll
    for (int n=0;n<16;++n){
      float e = __expf(dtv*An[n]);
      P[n] *= e;
      h[n] = e*h[n] + u*Bv[n];
    }
  }
  size_t base = (((size_t)b*NCH + c)*DI + d)*16;
#pragma unroll
  for (int n=0;n<16;++n){ Pws[base+n] = P[n]; Hws[base+n] = h[n]; }
}

__global__ __launch_bounds__(256) void scan_combine(const float* __restrict__ Pws,
    const float* __restrict__ Hws, float* __restrict__ H0ws) {
  int gid = blockIdx.x*256 + threadIdx.x;  // 0..32767 = (b, d*16+n)
  int b  = gid >> 13;
  int dn = gid & 8191;
  float h0 = 0.f;
#pragma unroll 4
  for (int c=0;c<NCH;++c){
    size_t idx = ((size_t)(b*NCH+c)<<13) + dn;
    H0ws[idx] = h0;
    h0 = Pws[idx]*h0 + Hws[idx];
  }
}

__global__ __launch_bounds__(512) void scan_p2(const float* __restrict__ xc,
    const float* __restrict__ dt, const float* __restrict__ dbl,
    const float* __restrict__ A_log, const float* __restrict__ Dp,
    const float* __restrict__ xz, const float* __restrict__ H0ws,
    u16* __restrict__ ygate_bf) {
  __shared__ float sBC[CL][32];
  int d = threadIdx.x;
  int bc = blockIdx.x;
  int b = bc >> 6, c = bc & 63;
#pragma unroll
  for (int i=0;i<2;++i){
    int idx = i*512 + threadIdx.x;
    int t = idx >> 5, q = idx & 31;
    sBC[t][q] = dbl[((size_t)b*SEQ + c*CL + t)*48 + DTR + q];
  }
  __syncthreads();
  float An[16];
#pragma unroll
  for (int i=0;i<4;++i){
    float4 a = *(const float4*)&A_log[d*16 + i*4];
    An[i*4+0] = -__expf(a.x); An[i*4+1] = -__expf(a.y);
    An[i*4+2] = -__expf(a.z); An[i*4+3] = -__expf(a.w);
  }
  float Dd = Dp[d];
  float h[16];
  size_t base = (((size_t)b*NCH + c)*DI + d)*16;
#pragma unroll
  for (int i=0;i<4;++i){
    float4 h4 = *(const float4*)&H0ws[base + i*4];
    h[i*4+0]=h4.x; h[i*4+1]=h4.y; h[i*4+2]=h4.z; h[i*4+3]=h4.w;
  }
  size_t tok = (size_t)b*SEQ + c*CL;
  for (int t=0;t<CL;++t,++tok){
    float dtv = dt[tok*DI+d];
    float xcv = xc[tok*DI+d];
    float zv  = xz[tok*1024 + DI + d];
    float u = dtv*xcv;
    float4 B0 = *(float4*)&sBC[t][0];
    float4 B1 = *(float4*)&sBC[t][4];
    float4 B2 = *(float4*)&sBC[t][8];
    float4 B3 = *(float4*)&sBC[t][12];
    float4 C0 = *(float4*)&sBC[t][16];
    float4 C1 = *(float4*)&sBC[t][20];
    float4 C2 = *(float4*)&sBC[t][24];
    float4 C3 = *(float4*)&sBC[t][28];
    float Bv[16] = {B0.x,B0.y,B0.z,B0.w,B1.x,B1.y,B1.z,B1.w,
                    B2.x,B2.y,B2.z,B2.w,B3.x,B3.y,B3.z,B3.w};
    float Cv[16] = {C0.x,C0.y,C0.z,C0.w,C1.x,C1.y,C1.z,C1.w,
                    C2.x,C2.y,C2.z,C2.w,C3.x,C3.y,C3.z,C3.w};
    float y = 0.f;
#pragma unroll
    for (int n=0;n<16;++n){
      float e = __expf(dtv*An[n]);
      h[n] = e*h[n] + u*Bv[n];
      y += h[n]*Cv[n];
    }
    y += xcv*Dd;
    ygate_bf[tok*DI + d] = f2bf(y * (zv*sigmoidf_(zv)));
  }
}

// ---------------- V transpose: vT[bh][d][seq] = qkv_bf V part ----------------
__global__ __launch_bounds__(256) void vt_kernel(const u16* __restrict__ qkvb,
    u16* __restrict__ vT) {
  int bh = blockIdx.y; int b = bh>>2, h = bh&3;
  int l0 = blockIdx.x*64;
  int d = threadIdx.x & 63;
  int oct = threadIdx.x >> 6;   // 0..3
  u16 tmp[16];
#pragma unroll
  for (int i=0;i<16;++i){
    int l = l0 + oct*16 + i;
    tmp[i] = qkvb[((size_t)b*SEQ + l)*768 + 512 + h*HD + d];
  }
  size_t dst = ((size_t)bh*HD + d)*SEQ + l0 + oct*16;
  *(bf16x8*)&vT[dst]   = *(bf16x8*)&tmp[0];
  *(bf16x8*)&vT[dst+8] = *(bf16x8*)&tmp[8];
}

// ---------------- MFMA bf16 flash attention (S^T form), KV-split 4 ----------------
// Each lane owns ONE query (q=lq): in-lane softmax + 2 shfl. P in per-wave LDS.
__global__ __launch_bounds__(256) void attn_mfma_kernel(const u16* __restrict__ qkvb,
    const u16* __restrict__ vT,
    float* __restrict__ Opart, float* __restrict__ ml) {
  __shared__ u16 lds[12288];   // K 64x64 @0, V_T 64x64 @4096, P[w] 16x64 @8192+w*1024
  int bh = blockIdx.y; int b = bh>>2, h = bh&3;
  int s = blockIdx.z;
  int tid = threadIdx.x;
  int w = tid>>6, l = tid&63;
  int lq = l & 15;
  int lg = l >> 4;
  size_t bbase = (size_t)b*SEQ;
  size_t vbase = (size_t)bh*HD*SEQ;
  int q0 = blockIdx.x*64 + w*16;

  bf16x8 qf[2];
#pragma unroll
  for (int dsl=0; dsl<2; ++dsl)
    qf[dsl] = *(const bf16x8*)&qkvb[(bbase + q0 + lq)*768 + h*HD + lg*8 + dsl*32];

  float m_ = -1e30f, l_ = 0.f;
  f32x4 oacc[4] = {{0,0,0,0},{0,0,0,0},{0,0,0,0},{0,0,0,0}};
  int pbase = 8192 + w*1024;

  for (int kt=s*8; kt<s*8+8; ++kt){
    __syncthreads();
    // stage K (row-major bf16, swizzled) — 2 b128 copies/thread
#pragma unroll
    for (int i=0;i<2;++i){
      int gid = i*256 + tid;
      int row = gid>>3, g = gid&7;
      *(bf16x8*)&lds[row*64 + ((g ^ (row&7))*8)] =
          *(const bf16x8*)&qkvb[(bbase + kt*64 + row)*768 + 256 + h*HD + g*8];
    }
    // stage V^T from pre-transposed vT — 2 b128 copies/thread
#pragma unroll
    for (int i=0;i<2;++i){
      int gid = i*256 + tid;
      int row = gid>>3, g = gid&7;
      *(bf16x8*)&lds[4096 + row*64 + ((g ^ (row&7))*8)] =
          *(const bf16x8*)&vT[vbase + (size_t)row*SEQ + kt*64 + g*8];
    }
    __syncthreads();

    // S^T = K·Q^T : lane holds scores for q=lq, keys kg*16+lg*4+r
    f32x4 sacc[4] = {{0,0,0,0},{0,0,0,0},{0,0,0,0},{0,0,0,0}};
    __builtin_amdgcn_s_setprio(1);
#pragma unroll
    for (int kg=0;kg<4;++kg){
#pragma unroll
      for (int dsl=0;dsl<2;++dsl){
        int row = kg*16 + lq;
        bf16x8 kf = *(bf16x8*)&lds[row*64 + (((dsl*4 + lg) ^ (row&7))*8)];
        sacc[kg] = __builtin_amdgcn_mfma_f32_16x16x32_bf16(kf, qf[dsl], sacc[kg], 0,0,0);
      }
    }
    __builtin_amdgcn_s_setprio(0);

    // per-lane online softmax for q=lq
    float tm = sacc[0][0];
#pragma unroll
    for (int kg=0;kg<4;++kg){
      float a = fmaxf(fmaxf(sacc[kg][0],sacc[kg][1]),fmaxf(sacc[kg][2],sacc[kg][3]));
      tm = fmaxf(tm, a);
    }
    tm *= 0.125f;
    tm = fmaxf(tm, __shfl_xor(tm,16));
    tm = fmaxf(tm, __shfl_xor(tm,32));
    float mn = fmaxf(m_, tm);
    float sc = __expf(m_ - mn);
    m_ = mn;
    float p[4][4];
    float ps = 0.f;
#pragma unroll
    for (int kg=0;kg<4;++kg)
#pragma unroll
      for (int r=0;r<4;++r){
        float pe = __expf(sacc[kg][r]*0.125f - mn);
        p[kg][r] = pe;
        ps += pe;
      }
    ps += __shfl_xor(ps,16);
    ps += __shfl_xor(ps,32);
    l_ = l_*sc + ps;
#pragma unroll
    for (int dg=0;dg<4;++dg){
      oacc[dg][0]*=sc; oacc[dg][1]*=sc; oacc[dg][2]*=sc; oacc[dg][3]*=sc;
    }

    // P^T -> LDS [q][key] as packed u32 (rows = lq: conflict-clean)
#pragma unroll
    for (int kg=0;kg<4;++kg)
#pragma unroll
      for (int rp=0;rp<2;++rp){
        unsigned pk = (unsigned)f2bf(p[kg][2*rp]) | ((unsigned)f2bf(p[kg][2*rp+1])<<16);
        int off = pbase + lq*64 + (((2*kg + (lg>>1)) ^ (lq&7))*8) + 4*(lg&1) + 2*rp;
        *(unsigned*)&lds[off] = pk;
      }

    // O^T += V^T · P : A = V^T rows d, B = P rows q
    __builtin_amdgcn_s_setprio(1);
#pragma unroll
    for (int ks=0;ks<2;++ks){
      bf16x8 pf = *(bf16x8*)&lds[pbase + lq*64 + (((ks*4 + lg) ^ (lq&7))*8)];
#pragma unroll
      for (int dg=0;dg<4;++dg){
        int row = dg*16 + lq;
        bf16x8 vf = *(bf16x8*)&lds[4096 + row*64 + (((ks*4 + lg) ^ (row&7))*8)];
        oacc[dg] = __builtin_amdgcn_mfma_f32_16x16x32_bf16(vf, pf, oacc[dg], 0,0,0);
      }
    }
    __builtin_amdgcn_s_setprio(0);
  }

  // write partials: O^T regs -> Opart[sidx][q][d]
  int sidx = bh*4 + s;
  size_t rb = ((size_t)sidx*SEQ + q0 + lq)*64;
#pragma unroll
  for (int dg=0;dg<4;++dg)
#pragma unroll
    for (int r=0;r<4;++r)
      Opart[rb + dg*16 + lg*4 + r] = oacc[dg][r];
  if (lg==0){
    ml[((size_t)sidx*SEQ + q0 + lq)*2    ] = m_;
    ml[((size_t)sidx*SEQ + q0 + lq)*2 + 1] = l_;
  }
}

// ---------------- merge 4 KV-chunk partials -> bf16 attn_o ----------------
__global__ __launch_bounds__(256) void attn_merge_kernel(const float* __restrict__ Opart,
    const float* __restrict__ ml, u16* __restrict__ attn_bf) {
  int w = threadIdx.x>>6, lane = threadIdx.x&63;
  int R = blockIdx.x*4 + w;        // 0..32767
  int bh = R>>11, q = R&2047;
  float m[4], lv[4];
#pragma unroll
  for (int s=0;s<4;++s){
    m[s]  = ml[((size_t)(bh*4+s)*SEQ + q)*2];
    lv[s] = ml[((size_t)(bh*4+s)*SEQ + q)*2 + 1];
  }
  float ms = fmaxf(fmaxf(m[0],m[1]),fmaxf(m[2],m[3]));
  float o = 0.f, lsum = 0.f;
#pragma unroll
  for (int s=0;s<4;++s){
    float wsc = __expf(m[s]-ms);
    lsum += wsc*lv[s];
    o += wsc*Opart[((size_t)(bh*4+s)*SEQ + q)*64 + lane];
  }
  size_t token = (size_t)(bh>>2)*SEQ + q;
  attn_bf[token*DM + (bh&3)*HD + lane] = f2bf(o/lsum);
}

// ---------------- final: out = x + g*ssm + (1-g)*attn ----------------
__global__ __launch_bounds__(256) void final_kernel(const float* __restrict__ x,
    const float* __restrict__ cat, const float* __restrict__ gate,
    float* __restrict__ out) {
  int idx = blockIdx.x*256 + threadIdx.x;
  int token = idx >> 6;
  int q = (idx & 63)*4;
  float4 g4 = *(const float4*)&gate[(size_t)token*DM + q];
  float4 s4 = *(const float4*)&cat[(size_t)token*512 + q];
  float4 a4 = *(const float4*)&cat[(size_t)token*512 + 256 + q];
  float4 x4 = *(const float4*)&x[(size_t)token*DM + q];
  float4 o;
  o.x = x4.x + g4.x*s4.x + (1.f-g4.x)*a4.x;
  o.y = x4.y + g4.y*s4.y + (1.f-g4.y)*a4.y;
  o.z = x4.z + g4.z*s4.z + (1.f-g4.z)*a4.z;
  o.w = x4.w + g4.w*s4.w + (1.f-g4.w)*a4.w;
  *(float4*)&out[(size_t)token*DM + q] = o;
}

extern "C" void kernel_launch(void* const* d_in, const int* in_sizes, int n_in,
                              void* d_out, int out_size, void* d_ws, size_t ws_size,
                              hipStream_t stream) {
  const float* x      = (const float*)d_in[0];
  const float* ln_g   = (const float*)d_in[1];
  const float* ln_b   = (const float*)d_in[2];
  const float* W_in   = (const float*)d_in[3];
  const float* conv_w = (const float*)d_in[4];
  const float* conv_b = (const float*)d_in[5];
  const float* W_xproj= (const float*)d_in[6];
  const float* W_dt   = (const float*)d_in[7];
  const float* b_dt   = (const float*)d_in[8];
  const float* A_log  = (const float*)d_in[9];
  const float* Dp     = (const float*)d_in[10];
  const float* W_out_m= (const float*)d_in[11];
  const float* W_qkv  = (const float*)d_in[12];
  const float* b_qkv  = (const float*)d_in[13];
  const float* W_o    = (const float*)d_in[14];
  const float* b_o    = (const float*)d_in[15];
  const float* W_gate = (const float*)d_in[16];
  const float* b_gate = (const float*)d_in[17];
  float* out = (float*)d_out;

  float* ws = (float*)d_ws;
  u16*   xn_bf   = (u16*)(ws);                       // 2,097,152 u
  float* xz      = ws + 1048576;                     // 8,388,608 f
  u16*   qkv_bf  = (u16*)(ws + 9437184);             // 6,291,456 u
  float* xc      = ws + 12582912;                    // 4,194,304
  float* dblb    = ws + 16777216;                    //   393,216
  float* dtb     = ws + 17170432;                    // 4,194,304
  u16*   ygate_bf= (u16*)(ws + 21364736);            // 4,194,304 u
  u16*   attn_bf = (u16*)(ws + 23461888);            // 2,097,152 u
  float* catb    = ws + 24510464;                    // 4,194,304
  u16*   catb_bf = (u16*)(ws + 28704768);            // 4,194,304 u
  float* gateb   = ws + 30801920;                    // 2,097,152
  u16*   Wt_all  = (u16*)(ws + 32899072);            //   786,432 u
  // aliases (lifetime-disjoint):
  float* Opart = xz;                 // attention partials after xz dead (post scan_p2)
  float* mlb   = (float*)xn_bf;      // after xn_bf dead (post qkv gemm)
  u16*   vTb   = (u16*)dtb;          // 4,194,304 u16 after dtb dead (post scan_p2)
  float* Pws   = catb;               // scan summaries before catb written
  float* Hws   = catb + 2097152;
  float* H0ws  = catb + 4194304;

  u16* Wt_in   = Wt_all;             // 1024x256
  u16* Wt_qkv  = Wt_all + 262144;    // 768x256
  u16* Wt_out  = Wt_all + 458752;    // 256x512
  u16* Wt_o    = Wt_all + 589824;    // 256x256
  u16* Wt_gate = Wt_all + 655360;    // 256x512

  tcvt_kernel<<<dim3(16,256), 64, 0, stream>>>(W_in,    Wt_in,   1024, 256);
  tcvt_kernel<<<dim3(12,256), 64, 0, stream>>>(W_qkv,   Wt_qkv,   768, 256);
  tcvt_kernel<<<dim3(4,512),  64, 0, stream>>>(W_out_m, Wt_out,   256, 512);
  tcvt_kernel<<<dim3(4,256),  64, 0, stream>>>(W_o,     Wt_o,     256, 256);
  tcvt_kernel<<<dim3(4,512),  64, 0, stream>>>(W_gate,  Wt_gate,  256, 512);

  ln_kernel<<<T_TOK/4, 256, 0, stream>>>(x, ln_g, ln_b, xn_bf);
  gemm_mfma<0><<<dim3(16,64), 256, 0, stream>>>(xn_bf, Wt_in, nullptr, xz, nullptr, 256, 1024);
  gemm_mfma<0><<<dim3(12,64), 256, 0, stream>>>(xn_bf, Wt_qkv, b_qkv, nullptr, qkv_bf, 256, 768);
  conv_kernel<<<T_TOK*DI/256, 256, 0, stream>>>(xz, conv_w, conv_b, xc);
  xproj_dt_kernel<<<T_TOK/4, 256, 0, stream>>>(xc, W_xproj, W_dt, b_dt, dblb, dtb);
  scan_p1<<<B_SZ*NCH, 512, 0, stream>>>(xc, dtb, dblb, A_log, Pws, Hws);
  scan_combine<<<128, 256, 0, stream>>>(Pws, Hws, H0ws);
  scan_p2<<<B_SZ*NCH, 512, 0, stream>>>(xc, dtb, dblb, A_log, Dp, xz, H0ws, ygate_bf);
  vt_kernel<<<dim3(SEQ/64, 16), 256, 0, stream>>>(qkv_bf, vTb);
  attn_mfma_kernel<<<dim3(SEQ/64, 16, 4), 256, 0, stream>>>(qkv_bf, vTb, Opart, mlb);
  attn_merge_kernel<<<8192, 256, 0, stream>>>(Opart, mlb, attn_bf);
  gemm_mfma<0><<<dim3(4,64), 256, 0, stream>>>(ygate_bf, Wt_out, nullptr, catb, catb_bf, 512, 512);
  gemm_mfma<0><<<dim3(4,64), 256, 0, stream>>>(attn_bf, Wt_o, b_o, catb+256, catb_bf+256, 256, 512);
  gemm_mfma<1><<<dim3(4,64), 256, 0, stream>>>(catb_bf, Wt_gate, b_gate, gateb, nullptr, 512, 256);
  final_kernel<<<T_TOK*64/256, 256, 0, stream>>>(x, catb, gateb, out);
}

// Round 7
// 264.658 us; speedup vs baseline: 9.2322x; 1.0430x over previous
//
#include <hip/hip_runtime.h>
#include <math.h>

#define B_SZ 4
#define SEQ 2048
#define DM 256
#define DI 512
#define DS 16
#define DTR 16
#define NH 4
#define HD 64
#define T_TOK (B_SZ*SEQ)   // 8192
#define NCH 64             // scan time-chunks
#define CL (SEQ/NCH)       // 32

typedef short bf16x8 __attribute__((ext_vector_type(8)));
typedef float f32x4  __attribute__((ext_vector_type(4)));
typedef unsigned short u16;

__device__ __forceinline__ float sigmoidf_(float x){ return 1.f/(1.f+__expf(-x)); }
__device__ __forceinline__ u16 f2bf(float x){
  unsigned int u = __float_as_uint(x);
  u += 0x7fffu + ((u>>16)&1u);
  return (u16)(u>>16);
}

// ---------------- weight transpose+convert: dst[n][k] = bf16(src[k][n]) ----------------
__global__ __launch_bounds__(64) void tcvt_kernel(const float* __restrict__ src,
    u16* __restrict__ dst, int N, int K) {
  int n = blockIdx.x*64 + threadIdx.x;
  int k = blockIdx.y;
  dst[(size_t)n*K + k] = f2bf(src[(size_t)k*N + n]);
}

// transpose+convert with zero-padding rows >= Nvalid (src row length = Nvalid)
__global__ __launch_bounds__(64) void tcvt_pad_kernel(const float* __restrict__ src,
    u16* __restrict__ dst, int K, int Nvalid) {
  int n = threadIdx.x;          // 0..63
  int k = blockIdx.y;
  dst[(size_t)n*K + k] = (n < Nvalid) ? f2bf(src[(size_t)k*Nvalid + n]) : (u16)0;
}

// ---------------- LayerNorm: one wave per token -> bf16 ----------------
__global__ __launch_bounds__(256) void ln_kernel(const float* __restrict__ x,
    const float* __restrict__ g, const float* __restrict__ b,
    u16* __restrict__ xn_bf) {
  int wid = threadIdx.x >> 6;
  int lane = threadIdx.x & 63;
  int token = blockIdx.x*4 + wid;
  const float* xr = x + (size_t)token*DM;
  float4 v = *(const float4*)&xr[lane*4];
  float s  = v.x+v.y+v.z+v.w;
  float ss = v.x*v.x+v.y*v.y+v.z*v.z+v.w*v.w;
  for (int m=1;m<64;m<<=1){ s += __shfl_xor(s,m); ss += __shfl_xor(ss,m); }
  float mu  = s * (1.f/DM);
  float var = ss*(1.f/DM) - mu*mu;
  float rs  = rsqrtf(var + 1e-5f);
  float4 gv = *(const float4*)&g[lane*4];
  float4 bv = *(const float4*)&b[lane*4];
  ushort4 o;
  o.x = f2bf((v.x-mu)*rs*gv.x + bv.x);
  o.y = f2bf((v.y-mu)*rs*gv.y + bv.y);
  o.z = f2bf((v.z-mu)*rs*gv.z + bv.z);
  o.w = f2bf((v.w-mu)*rs*gv.w + bv.w);
  *(ushort4*)&xn_bf[(size_t)token*DM + lane*4] = o;
}

// ---------------- MFMA bf16 GEMM: C[M,N] = A[M,K](bf16) @ Wt[N,K](bf16) ----------------
template<int ACT>  // 0=none, 1=sigmoid
__global__ __launch_bounds__(256) void gemm_mfma(const u16* __restrict__ A,
    const u16* __restrict__ Wt, const float* __restrict__ bias,
    float* __restrict__ C, u16* __restrict__ Cbf, int K, int ldc, int nvalid) {
  __shared__ u16 lds[12288];    // As 128x64 @0 (8192), Bs 64x64 @8192 (4096)
  int tid = threadIdx.x;
  int m0 = blockIdx.y*128, n0 = blockIdx.x*64;
  int w = tid>>6, l = tid&63, lq = l&15, lg = l>>4;
  int wm = w>>1, wn = w&1;
  f32x4 acc[4][2] = {};
  for (int k0 = 0; k0 < K; k0 += 64) {
#pragma unroll
    for (int i=0;i<4;++i){
      int gid = i*256 + tid;
      int row = gid>>3, g = gid&7;
      *(bf16x8*)&lds[row*64 + ((g ^ (row&7))*8)] =
          *(const bf16x8*)&A[(size_t)(m0+row)*K + k0 + g*8];
    }
#pragma unroll
    for (int i=0;i<2;++i){
      int gid = i*256 + tid;
      int row = gid>>3, g = gid&7;
      *(bf16x8*)&lds[8192 + row*64 + ((g ^ (row&7))*8)] =
          *(const bf16x8*)&Wt[(size_t)(n0+row)*K + k0 + g*8];
    }
    __syncthreads();
#pragma unroll
    for (int ks=0;ks<2;++ks){
      bf16x8 af[4], bfv[2];
#pragma unroll
      for (int mi=0;mi<4;++mi){
        int row = wm*64 + mi*16 + lq;
        af[mi] = *(bf16x8*)&lds[row*64 + (((ks*4+lg) ^ (row&7))*8)];
      }
#pragma unroll
      for (int nj=0;nj<2;++nj){
        int row = wn*32 + nj*16 + lq;
        bfv[nj] = *(bf16x8*)&lds[8192 + row*64 + (((ks*4+lg) ^ (row&7))*8)];
      }
#pragma unroll
      for (int mi=0;mi<4;++mi)
#pragma unroll
        for (int nj=0;nj<2;++nj)
          acc[mi][nj] = __builtin_amdgcn_mfma_f32_16x16x32_bf16(af[mi], bfv[nj], acc[mi][nj], 0,0,0);
    }
    __syncthreads();
  }
#pragma unroll
  for (int mi=0;mi<4;++mi){
#pragma unroll
    for (int nj=0;nj<2;++nj){
#pragma unroll
      for (int r=0;r<4;++r){
        int row = m0 + wm*64 + mi*16 + lg*4 + r;
        int col = n0 + wn*32 + nj*16 + lq;
        if (col < nvalid) {
          float v = acc[mi][nj][r];
          if (bias) v += bias[col];
          if (ACT==1) v = sigmoidf_(v);
          if (C)   C[(size_t)row*ldc + col] = v;
          if (Cbf) Cbf[(size_t)row*ldc + col] = f2bf(v);
        }
      }
    }
  }
}

// ---------------- depthwise conv (k=4) + SiLU -> fp32 + bf16 ----------------
__global__ __launch_bounds__(256) void conv_kernel(const float* __restrict__ xz,
    const float* __restrict__ cw, const float* __restrict__ cb,
    float* __restrict__ xc, u16* __restrict__ xc_bf) {
  int idx = blockIdx.x*256 + threadIdx.x;  // t*512 + d
  int d = idx & (DI-1);
  int t = idx >> 9;
  int l = t & (SEQ-1);
  float acc = cb[d];
  float w0=cw[d*4+0], w1=cw[d*4+1], w2=cw[d*4+2], w3=cw[d*4+3];
  const float* base = xz + (size_t)t*1024 + d;
  if (l>=3) acc += base[-3*1024]*w0;
  if (l>=2) acc += base[-2*1024]*w1;
  if (l>=1) acc += base[-1*1024]*w2;
  acc += base[0]*w3;
  float v = acc * sigmoidf_(acc);
  xc[idx] = v;
  xc_bf[idx] = f2bf(v);
}

// ---------------- dt = softplus(dbl[:,:16] @ W_dt + b_dt), wave per token ----------------
__global__ __launch_bounds__(256) void dt_kernel(const float* __restrict__ dbl,
    const float* __restrict__ Wdt, const float* __restrict__ bdt,
    float* __restrict__ dt) {
  __shared__ float sdbl[4][16];
  int wid = threadIdx.x>>6, lane = threadIdx.x&63;
  int token = blockIdx.x*4 + wid;
  if (lane < 16) sdbl[wid][lane] = dbl[(size_t)token*48 + lane];
  __syncthreads();
  float din[16];
#pragma unroll
  for (int k=0;k<16;++k) din[k] = sdbl[wid][k];
#pragma unroll
  for (int r=0;r<8;++r){
    int d = lane + r*64;
    float acc = bdt[d];
#pragma unroll
    for (int k=0;k<16;++k) acc += din[k]*Wdt[k*DI+d];
    float sp = (acc > 20.f) ? acc : log1pf(__expf(acc));
    dt[(size_t)token*DI+d] = sp;
  }
}

// ---------------- chunked selective scan, thread-per-channel ----------------
__global__ __launch_bounds__(512) void scan_p1(const float* __restrict__ xc,
    const float* __restrict__ dt, const float* __restrict__ dbl,
    const float* __restrict__ A_log, float* __restrict__ Pws, float* __restrict__ Hws) {
  __shared__ float sB[CL][16];
  int d = threadIdx.x;
  int bc = blockIdx.x;          // 0..255
  int b = bc >> 6, c = bc & 63;
  {
    int t = threadIdx.x >> 4, n = threadIdx.x & 15;
    sB[t][n] = dbl[((size_t)b*SEQ + c*CL + t)*48 + DTR + n];
  }
  __syncthreads();
  float An[16];
#pragma unroll
  for (int i=0;i<4;++i){
    float4 a = *(const float4*)&A_log[d*16 + i*4];
    An[i*4+0] = -__expf(a.x); An[i*4+1] = -__expf(a.y);
    An[i*4+2] = -__expf(a.z); An[i*4+3] = -__expf(a.w);
  }
  float h[16] = {};
  float P[16];
#pragma unroll
  for (int n=0;n<16;++n) P[n] = 1.f;
  size_t tok = (size_t)b*SEQ + c*CL;
  for (int t=0;t<CL;++t,++tok){
    float dtv = dt[tok*DI+d];
    float xcv = xc[tok*DI+d];
    float u = dtv*xcv;
    float4 B0 = *(float4*)&sB[t][0];
    float4 B1 = *(float4*)&sB[t][4];
    float4 B2 = *(float4*)&sB[t][8];
    float4 B3 = *(float4*)&sB[t][12];
    float Bv[16] = {B0.x,B0.y,B0.z,B0.w,B1.x,B1.y,B1.z,B1.w,
                    B2.x,B2.y,B2.z,B2.w,B3.x,B3.y,B3.z,B3.w};
#pragma unroll
    for (int n=0;n<16;++n){
      float e = __expf(dtv*An[n]);
      P[n] *= e;
      h[n] = e*h[n] + u*Bv[n];
    }
  }
  size_t base = (((size_t)b*NCH + c)*DI + d)*16;
#pragma unroll
  for (int n=0;n<16;++n){ Pws[base+n] = P[n]; Hws[base+n] = h[n]; }
}

__global__ __launch_bounds__(256) void scan_combine(const float* __restrict__ Pws,
    const float* __restrict__ Hws, float* __restrict__ H0ws) {
  int gid = blockIdx.x*256 + threadIdx.x;  // 0..32767 = (b, d*16+n)
  int b  = gid >> 13;
  int dn = gid & 8191;
  float h0 = 0.f;
#pragma unroll 4
  for (int c=0;c<NCH;++c){
    size_t idx = ((size_t)(b*NCH+c)<<13) + dn;
    H0ws[idx] = h0;
    h0 = Pws[idx]*h0 + Hws[idx];
  }
}

__global__ __launch_bounds__(512) void scan_p2(const float* __restrict__ xc,
    const float* __restrict__ dt, const float* __restrict__ dbl,
    const float* __restrict__ A_log, const float* __restrict__ Dp,
    const float* __restrict__ xz, const float* __restrict__ H0ws,
    u16* __restrict__ ygate_bf) {
  __shared__ float sBC[CL][32];
  int d = threadIdx.x;
  int bc = blockIdx.x;
  int b = bc >> 6, c = bc & 63;
#pragma unroll
  for (int i=0;i<2;++i){
    int idx = i*512 + threadIdx.x;
    int t = idx >> 5, q = idx & 31;
    sBC[t][q] = dbl[((size_t)b*SEQ + c*CL + t)*48 + DTR + q];
  }
  __syncthreads();
  float An[16];
#pragma unroll
  for (int i=0;i<4;++i){
    float4 a = *(const float4*)&A_log[d*16 + i*4];
    An[i*4+0] = -__expf(a.x); An[i*4+1] = -__expf(a.y);
    An[i*4+2] = -__expf(a.z); An[i*4+3] = -__expf(a.w);
  }
  float Dd = Dp[d];
  float h[16];
  size_t base = (((size_t)b*NCH + c)*DI + d)*16;
#pragma unroll
  for (int i=0;i<4;++i){
    float4 h4 = *(const float4*)&H0ws[base + i*4];
    h[i*4+0]=h4.x; h[i*4+1]=h4.y; h[i*4+2]=h4.z; h[i*4+3]=h4.w;
  }
  size_t tok = (size_t)b*SEQ + c*CL;
  for (int t=0;t<CL;++t,++tok){
    float dtv = dt[tok*DI+d];
    float xcv = xc[tok*DI+d];
    float zv  = xz[tok*1024 + DI + d];
    float u = dtv*xcv;
    float4 B0 = *(float4*)&sBC[t][0];
    float4 B1 = *(float4*)&sBC[t][4];
    float4 B2 = *(float4*)&sBC[t][8];
    float4 B3 = *(float4*)&sBC[t][12];
    float4 C0 = *(float4*)&sBC[t][16];
    float4 C1 = *(float4*)&sBC[t][20];
    float4 C2 = *(float4*)&sBC[t][24];
    float4 C3 = *(float4*)&sBC[t][28];
    float Bv[16] = {B0.x,B0.y,B0.z,B0.w,B1.x,B1.y,B1.z,B1.w,
                    B2.x,B2.y,B2.z,B2.w,B3.x,B3.y,B3.z,B3.w};
    float Cv[16] = {C0.x,C0.y,C0.z,C0.w,C1.x,C1.y,C1.z,C1.w,
                    C2.x,C2.y,C2.z,C2.w,C3.x,C3.y,C3.z,C3.w};
    float y = 0.f;
#pragma unroll
    for (int n=0;n<16;++n){
      float e = __expf(dtv*An[n]);
      h[n] = e*h[n] + u*Bv[n];
      y += h[n]*Cv[n];
    }
    y += xcv*Dd;
    ygate_bf[tok*DI + d] = f2bf(y * (zv*sigmoidf_(zv)));
  }
}

// ---------------- V transpose: vT[bh][d][seq] = qkv_bf V part ----------------
__global__ __launch_bounds__(256) void vt_kernel(const u16* __restrict__ qkvb,
    u16* __restrict__ vT) {
  int bh = blockIdx.y; int b = bh>>2, h = bh&3;
  int l0 = blockIdx.x*64;
  int d = threadIdx.x & 63;
  int oct = threadIdx.x >> 6;   // 0..3
  u16 tmp[16];
#pragma unroll
  for (int i=0;i<16;++i){
    int l = l0 + oct*16 + i;
    tmp[i] = qkvb[((size_t)b*SEQ + l)*768 + 512 + h*HD + d];
  }
  size_t dst = ((size_t)bh*HD + d)*SEQ + l0 + oct*16;
  *(bf16x8*)&vT[dst]   = *(bf16x8*)&tmp[0];
  *(bf16x8*)&vT[dst+8] = *(bf16x8*)&tmp[8];
}

// ---------------- MFMA bf16 flash attention (S^T form), KV-split 4 ----------------
__global__ __launch_bounds__(256) void attn_mfma_kernel(const u16* __restrict__ qkvb,
    const u16* __restrict__ vT,
    float* __restrict__ Opart, float* __restrict__ ml) {
  __shared__ u16 lds[12288];   // K 64x64 @0, V_T 64x64 @4096, P[w] 16x64 @8192+w*1024
  int bh = blockIdx.y; int b = bh>>2, h = bh&3;
  int s = blockIdx.z;
  int tid = threadIdx.x;
  int w = tid>>6, l = tid&63;
  int lq = l & 15;
  int lg = l >> 4;
  size_t bbase = (size_t)b*SEQ;
  size_t vbase = (size_t)bh*HD*SEQ;
  int q0 = blockIdx.x*64 + w*16;

  bf16x8 qf[2];
#pragma unroll
  for (int dsl=0; dsl<2; ++dsl)
    qf[dsl] = *(const bf16x8*)&qkvb[(bbase + q0 + lq)*768 + h*HD + lg*8 + dsl*32];

  float m_ = -1e30f, l_ = 0.f;
  f32x4 oacc[4] = {{0,0,0,0},{0,0,0,0},{0,0,0,0},{0,0,0,0}};
  int pbase = 8192 + w*1024;

  for (int kt=s*8; kt<s*8+8; ++kt){
    __syncthreads();
#pragma unroll
    for (int i=0;i<2;++i){
      int gid = i*256 + tid;
      int row = gid>>3, g = gid&7;
      *(bf16x8*)&lds[row*64 + ((g ^ (row&7))*8)] =
          *(const bf16x8*)&qkvb[(bbase + kt*64 + row)*768 + 256 + h*HD + g*8];
    }
#pragma unroll
    for (int i=0;i<2;++i){
      int gid = i*256 + tid;
      int row = gid>>3, g = gid&7;
      *(bf16x8*)&lds[4096 + row*64 + ((g ^ (row&7))*8)] =
          *(const bf16x8*)&vT[vbase + (size_t)row*SEQ + kt*64 + g*8];
    }
    __syncthreads();

    f32x4 sacc[4] = {{0,0,0,0},{0,0,0,0},{0,0,0,0},{0,0,0,0}};
    __builtin_amdgcn_s_setprio(1);
#pragma unroll
    for (int kg=0;kg<4;++kg){
#pragma unroll
      for (int dsl=0;dsl<2;++dsl){
        int row = kg*16 + lq;
        bf16x8 kf = *(bf16x8*)&lds[row*64 + (((dsl*4 + lg) ^ (row&7))*8)];
        sacc[kg] = __builtin_amdgcn_mfma_f32_16x16x32_bf16(kf, qf[dsl], sacc[kg], 0,0,0);
      }
    }
    __builtin_amdgcn_s_setprio(0);

    float tm = sacc[0][0];
#pragma unroll
    for (int kg=0;kg<4;++kg){
      float a = fmaxf(fmaxf(sacc[kg][0],sacc[kg][1]),fmaxf(sacc[kg][2],sacc[kg][3]));
      tm = fmaxf(tm, a);
    }
    tm *= 0.125f;
    tm = fmaxf(tm, __shfl_xor(tm,16));
    tm = fmaxf(tm, __shfl_xor(tm,32));
    float mn = fmaxf(m_, tm);
    float sc = __expf(m_ - mn);
    m_ = mn;
    float p[4][4];
    float ps = 0.f;
#pragma unroll
    for (int kg=0;kg<4;++kg)
#pragma unroll
      for (int r=0;r<4;++r){
        float pe = __expf(sacc[kg][r]*0.125f - mn);
        p[kg][r] = pe;
        ps += pe;
      }
    ps += __shfl_xor(ps,16);
    ps += __shfl_xor(ps,32);
    l_ = l_*sc + ps;
#pragma unroll
    for (int dg=0;dg<4;++dg){
      oacc[dg][0]*=sc; oacc[dg][1]*=sc; oacc[dg][2]*=sc; oacc[dg][3]*=sc;
    }

#pragma unroll
    for (int kg=0;kg<4;++kg)
#pragma unroll
      for (int rp=0;rp<2;++rp){
        unsigned pk = (unsigned)f2bf(p[kg][2*rp]) | ((unsigned)f2bf(p[kg][2*rp+1])<<16);
        int off = pbase + lq*64 + (((2*kg + (lg>>1)) ^ (lq&7))*8) + 4*(lg&1) + 2*rp;
        *(unsigned*)&lds[off] = pk;
      }

    __builtin_amdgcn_s_setprio(1);
#pragma unroll
    for (int ks=0;ks<2;++ks){
      bf16x8 pf = *(bf16x8*)&lds[pbase + lq*64 + (((ks*4 + lg) ^ (lq&7))*8)];
#pragma unroll
      for (int dg=0;dg<4;++dg){
        int row = dg*16 + lq;
        bf16x8 vf = *(bf16x8*)&lds[4096 + row*64 + (((ks*4 + lg) ^ (row&7))*8)];
        oacc[dg] = __builtin_amdgcn_mfma_f32_16x16x32_bf16(vf, pf, oacc[dg], 0,0,0);
      }
    }
    __builtin_amdgcn_s_setprio(0);
  }

  int sidx = bh*4 + s;
  size_t rb = ((size_t)sidx*SEQ + q0 + lq)*64;
#pragma unroll
  for (int dg=0;dg<4;++dg)
#pragma unroll
    for (int r=0;r<4;++r)
      Opart[rb + dg*16 + lg*4 + r] = oacc[dg][r];
  if (lg==0){
    ml[((size_t)sidx*SEQ + q0 + lq)*2    ] = m_;
    ml[((size_t)sidx*SEQ + q0 + lq)*2 + 1] = l_;
  }
}

// ---------------- merge 4 KV-chunk partials -> bf16 attn_o ----------------
__global__ __launch_bounds__(256) void attn_merge_kernel(const float* __restrict__ Opart,
    const float* __restrict__ ml, u16* __restrict__ attn_bf) {
  int w = threadIdx.x>>6, lane = threadIdx.x&63;
  int R = blockIdx.x*4 + w;        // 0..32767
  int bh = R>>11, q = R&2047;
  float m[4], lv[4];
#pragma unroll
  for (int s=0;s<4;++s){
    m[s]  = ml[((size_t)(bh*4+s)*SEQ + q)*2];
    lv[s] = ml[((size_t)(bh*4+s)*SEQ + q)*2 + 1];
  }
  float ms = fmaxf(fmaxf(m[0],m[1]),fmaxf(m[2],m[3]));
  float o = 0.f, lsum = 0.f;
#pragma unroll
  for (int s=0;s<4;++s){
    float wsc = __expf(m[s]-ms);
    lsum += wsc*lv[s];
    o += wsc*Opart[((size_t)(bh*4+s)*SEQ + q)*64 + lane];
  }
  size_t token = (size_t)(bh>>2)*SEQ + q;
  attn_bf[token*DM + (bh&3)*HD + lane] = f2bf(o/lsum);
}

// ---------------- final: out = x + g*ssm + (1-g)*attn ----------------
__global__ __launch_bounds__(256) void final_kernel(const float* __restrict__ x,
    const float* __restrict__ cat, const float* __restrict__ gate,
    float* __restrict__ out) {
  int idx = blockIdx.x*256 + threadIdx.x;
  int token = idx >> 6;
  int q = (idx & 63)*4;
  float4 g4 = *(const float4*)&gate[(size_t)token*DM + q];
  float4 s4 = *(const float4*)&cat[(size_t)token*512 + q];
  float4 a4 = *(const float4*)&cat[(size_t)token*512 + 256 + q];
  float4 x4 = *(const float4*)&x[(size_t)token*DM + q];
  float4 o;
  o.x = x4.x + g4.x*s4.x + (1.f-g4.x)*a4.x;
  o.y = x4.y + g4.y*s4.y + (1.f-g4.y)*a4.y;
  o.z = x4.z + g4.z*s4.z + (1.f-g4.z)*a4.z;
  o.w = x4.w + g4.w*s4.w + (1.f-g4.w)*a4.w;
  *(float4*)&out[(size_t)token*DM + q] = o;
}

extern "C" void kernel_launch(void* const* d_in, const int* in_sizes, int n_in,
                              void* d_out, int out_size, void* d_ws, size_t ws_size,
                              hipStream_t stream) {
  const float* x      = (const float*)d_in[0];
  const float* ln_g   = (const float*)d_in[1];
  const float* ln_b   = (const float*)d_in[2];
  const float* W_in   = (const float*)d_in[3];
  const float* conv_w = (const float*)d_in[4];
  const float* conv_b = (const float*)d_in[5];
  const float* W_xproj= (const float*)d_in[6];
  const float* W_dt   = (const float*)d_in[7];
  const float* b_dt   = (const float*)d_in[8];
  const float* A_log  = (const float*)d_in[9];
  const float* Dp     = (const float*)d_in[10];
  const float* W_out_m= (const float*)d_in[11];
  const float* W_qkv  = (const float*)d_in[12];
  const float* b_qkv  = (const float*)d_in[13];
  const float* W_o    = (const float*)d_in[14];
  const float* b_o    = (const float*)d_in[15];
  const float* W_gate = (const float*)d_in[16];
  const float* b_gate = (const float*)d_in[17];
  float* out = (float*)d_out;

  float* ws = (float*)d_ws;
  u16*   xn_bf   = (u16*)(ws);                       // 2,097,152 u
  float* xz      = ws + 1048576;                     // 8,388,608 f
  u16*   qkv_bf  = (u16*)(ws + 9437184);             // 6,291,456 u
  float* xc      = ws + 12582912;                    // 4,194,304
  float* dblb    = ws + 16777216;                    //   393,216
  float* dtb     = ws + 17170432;                    // 4,194,304
  u16*   ygate_bf= (u16*)(ws + 21364736);            // 4,194,304 u
  u16*   attn_bf = (u16*)(ws + 23461888);            // 2,097,152 u
  float* catb    = ws + 24510464;                    // 4,194,304
  u16*   catb_bf = (u16*)(ws + 28704768);            // 4,194,304 u
  float* gateb   = ws + 30801920;                    // 2,097,152
  u16*   Wt_all  = (u16*)(ws + 32899072);            //   819,200 u
  // aliases (lifetime-disjoint):
  float* Opart = xz;                 // attention partials after xz dead (post scan_p2)
  float* mlb   = (float*)xn_bf;      // after xn_bf dead (post qkv gemm)
  u16*   vTb   = (u16*)dtb;          // after dtb dead (post scan_p2)
  u16*   xc_bf = ygate_bf;           // conv->xproj gemm; dead before scan_p2 writes ygate
  float* Pws   = catb;               // scan summaries before catb written
  float* Hws   = catb + 2097152;
  float* H0ws  = catb + 4194304;

  u16* Wt_in   = Wt_all;             // 1024x256
  u16* Wt_qkv  = Wt_all + 262144;    // 768x256
  u16* Wt_out  = Wt_all + 458752;    // 256x512
  u16* Wt_o    = Wt_all + 589824;    // 256x256
  u16* Wt_gate = Wt_all + 655360;    // 256x512
  u16* Wt_xp   = Wt_all + 786432;    // 64x512 (48 valid + 16 zero rows)

  tcvt_kernel<<<dim3(16,256), 64, 0, stream>>>(W_in,    Wt_in,   1024, 256);
  tcvt_kernel<<<dim3(12,256), 64, 0, stream>>>(W_qkv,   Wt_qkv,   768, 256);
  tcvt_kernel<<<dim3(4,512),  64, 0, stream>>>(W_out_m, Wt_out,   256, 512);
  tcvt_kernel<<<dim3(4,256),  64, 0, stream>>>(W_o,     Wt_o,     256, 256);
  tcvt_kernel<<<dim3(4,512),  64, 0, stream>>>(W_gate,  Wt_gate,  256, 512);
  tcvt_pad_kernel<<<dim3(1,512), 64, 0, stream>>>(W_xproj, Wt_xp, 512, 48);

  ln_kernel<<<T_TOK/4, 256, 0, stream>>>(x, ln_g, ln_b, xn_bf);
  gemm_mfma<0><<<dim3(16,64), 256, 0, stream>>>(xn_bf, Wt_in, nullptr, xz, nullptr, 256, 1024, 1024);
  gemm_mfma<0><<<dim3(12,64), 256, 0, stream>>>(xn_bf, Wt_qkv, b_qkv, nullptr, qkv_bf, 256, 768, 768);
  conv_kernel<<<T_TOK*DI/256, 256, 0, stream>>>(xz, conv_w, conv_b, xc, xc_bf);
  gemm_mfma<0><<<dim3(1,64), 256, 0, stream>>>(xc_bf, Wt_xp, nullptr, dblb, nullptr, 512, 48, 48);
  dt_kernel<<<T_TOK/4, 256, 0, stream>>>(dblb, W_dt, b_dt, dtb);
  scan_p1<<<B_SZ*NCH, 512, 0, stream>>>(xc, dtb, dblb, A_log, Pws, Hws);
  scan_combine<<<128, 256, 0, stream>>>(Pws, Hws, H0ws);
  scan_p2<<<B_SZ*NCH, 512, 0, stream>>>(xc, dtb, dblb, A_log, Dp, xz, H0ws, ygate_bf);
  vt_kernel<<<dim3(SEQ/64, 16), 256, 0, stream>>>(qkv_bf, vTb);
  attn_mfma_kernel<<<dim3(SEQ/64, 16, 4), 256, 0, stream>>>(qkv_bf, vTb, Opart, mlb);
  attn_merge_kernel<<<8192, 256, 0, stream>>>(Opart, mlb, attn_bf);
  gemm_mfma<0><<<dim3(4,64), 256, 0, stream>>>(ygate_bf, Wt_out, nullptr, catb, catb_bf, 512, 512, 256);
  gemm_mfma<0><<<dim3(4,64), 256, 0, stream>>>(attn_bf, Wt_o, b_o, catb+256, catb_bf+256, 256, 512, 256);
  gemm_mfma<1><<<dim3(4,64), 256, 0, stream>>>(catb_bf, Wt_gate, b_gate, gateb, nullptr, 512, 256, 256);
  final_kernel<<<T_TOK*64/256, 256, 0, stream>>>(x, catb, gateb, out);
}

// Round 8
// 260.338 us; speedup vs baseline: 9.3854x; 1.0166x over previous
//
#include <hip/hip_runtime.h>
#include <math.h>

#define B_SZ 4
#define SEQ 2048
#define DM 256
#define DI 512
#define DS 16
#define DTR 16
#define NH 4
#define HD 64
#define T_TOK (B_SZ*SEQ)   // 8192
#define NCH 64             // scan time-chunks
#define CL (SEQ/NCH)       // 32
#define QSCALE 0.18033688f // 0.125 * log2(e)

typedef short bf16x8 __attribute__((ext_vector_type(8)));
typedef float f32x4  __attribute__((ext_vector_type(4)));
typedef unsigned short u16;

__device__ __forceinline__ float sigmoidf_(float x){ return 1.f/(1.f+__expf(-x)); }
__device__ __forceinline__ u16 f2bf(float x){
  unsigned int u = __float_as_uint(x);
  u += 0x7fffu + ((u>>16)&1u);
  return (u16)(u>>16);
}
__device__ __forceinline__ float bf2f(u16 u){ return __uint_as_float(((unsigned)u)<<16); }
__device__ __forceinline__ unsigned cvt_pk_bf16(float lo, float hi){
  unsigned r;
  asm("v_cvt_pk_bf16_f32 %0, %1, %2" : "=v"(r) : "v"(lo), "v"(hi));
  return r;
}

// ---------------- weight transpose+convert: dst[n][k] = bf16(src[k][n]) ----------------
__global__ __launch_bounds__(64) void tcvt_kernel(const float* __restrict__ src,
    u16* __restrict__ dst, int N, int K) {
  int n = blockIdx.x*64 + threadIdx.x;
  int k = blockIdx.y;
  dst[(size_t)n*K + k] = f2bf(src[(size_t)k*N + n]);
}

__global__ __launch_bounds__(64) void tcvt_pad_kernel(const float* __restrict__ src,
    u16* __restrict__ dst, int K, int Nvalid) {
  int n = threadIdx.x;
  int k = blockIdx.y;
  dst[(size_t)n*K + k] = (n < Nvalid) ? f2bf(src[(size_t)k*Nvalid + n]) : (u16)0;
}

// ---------------- LayerNorm: one wave per token -> bf16 ----------------
__global__ __launch_bounds__(256) void ln_kernel(const float* __restrict__ x,
    const float* __restrict__ g, const float* __restrict__ b,
    u16* __restrict__ xn_bf) {
  int wid = threadIdx.x >> 6;
  int lane = threadIdx.x & 63;
  int token = blockIdx.x*4 + wid;
  const float* xr = x + (size_t)token*DM;
  float4 v = *(const float4*)&xr[lane*4];
  float s  = v.x+v.y+v.z+v.w;
  float ss = v.x*v.x+v.y*v.y+v.z*v.z+v.w*v.w;
  for (int m=1;m<64;m<<=1){ s += __shfl_xor(s,m); ss += __shfl_xor(ss,m); }
  float mu  = s * (1.f/DM);
  float var = ss*(1.f/DM) - mu*mu;
  float rs  = rsqrtf(var + 1e-5f);
  float4 gv = *(const float4*)&g[lane*4];
  float4 bv = *(const float4*)&b[lane*4];
  uint2 o;
  o.x = cvt_pk_bf16((v.x-mu)*rs*gv.x + bv.x, (v.y-mu)*rs*gv.y + bv.y);
  o.y = cvt_pk_bf16((v.z-mu)*rs*gv.z + bv.z, (v.w-mu)*rs*gv.w + bv.w);
  *(uint2*)&xn_bf[(size_t)token*DM + lane*4] = o;
}

// ---------------- MFMA bf16 GEMM: C[M,N] = A[M,K](bf16) @ Wt[N,K](bf16) ----------------
// ACT: 0=none, 1=sigmoid, 2=gate-fused final (out = x + g*ssm + (1-g)*attn)
template<int ACT>
__global__ __launch_bounds__(256) void gemm_mfma(const u16* __restrict__ A,
    const u16* __restrict__ Wt, const float* __restrict__ bias,
    float* __restrict__ C, u16* __restrict__ Cbf, int K, int ldc, int nvalid,
    int qcols, float qscale, const float* __restrict__ xres,
    const float* __restrict__ cat2) {
  __shared__ u16 lds[12288];    // As 128x64 @0 (8192), Bs 64x64 @8192 (4096)
  int tid = threadIdx.x;
  int m0 = blockIdx.y*128, n0 = blockIdx.x*64;
  int w = tid>>6, l = tid&63, lq = l&15, lg = l>>4;
  int wm = w>>1, wn = w&1;
  f32x4 acc[4][2] = {};
  for (int k0 = 0; k0 < K; k0 += 64) {
#pragma unroll
    for (int i=0;i<4;++i){
      int gid = i*256 + tid;
      int row = gid>>3, g = gid&7;
      *(bf16x8*)&lds[row*64 + ((g ^ (row&7))*8)] =
          *(const bf16x8*)&A[(size_t)(m0+row)*K + k0 + g*8];
    }
#pragma unroll
    for (int i=0;i<2;++i){
      int gid = i*256 + tid;
      int row = gid>>3, g = gid&7;
      *(bf16x8*)&lds[8192 + row*64 + ((g ^ (row&7))*8)] =
          *(const bf16x8*)&Wt[(size_t)(n0+row)*K + k0 + g*8];
    }
    __syncthreads();
#pragma unroll
    for (int ks=0;ks<2;++ks){
      bf16x8 af[4], bfv[2];
#pragma unroll
      for (int mi=0;mi<4;++mi){
        int row = wm*64 + mi*16 + lq;
        af[mi] = *(bf16x8*)&lds[row*64 + (((ks*4+lg) ^ (row&7))*8)];
      }
#pragma unroll
      for (int nj=0;nj<2;++nj){
        int row = wn*32 + nj*16 + lq;
        bfv[nj] = *(bf16x8*)&lds[8192 + row*64 + (((ks*4+lg) ^ (row&7))*8)];
      }
#pragma unroll
      for (int mi=0;mi<4;++mi)
#pragma unroll
        for (int nj=0;nj<2;++nj)
          acc[mi][nj] = __builtin_amdgcn_mfma_f32_16x16x32_bf16(af[mi], bfv[nj], acc[mi][nj], 0,0,0);
    }
    __syncthreads();
  }
#pragma unroll
  for (int mi=0;mi<4;++mi){
#pragma unroll
    for (int nj=0;nj<2;++nj){
#pragma unroll
      for (int r=0;r<4;++r){
        int row = m0 + wm*64 + mi*16 + lg*4 + r;
        int col = n0 + wn*32 + nj*16 + lq;
        if (col < nvalid) {
          float v = acc[mi][nj][r];
          if (bias) v += bias[col];
          if (col < qcols) v *= qscale;
          if (ACT==2) {
            float g = sigmoidf_(v);
            float sv = cat2[(size_t)row*512 + col];
            float av = cat2[(size_t)row*512 + 256 + col];
            C[(size_t)row*256 + col] = xres[(size_t)row*256 + col] + g*sv + (1.f-g)*av;
          } else {
            if (ACT==1) v = sigmoidf_(v);
            if (C)   C[(size_t)row*ldc + col] = v;
            if (Cbf) Cbf[(size_t)row*ldc + col] = f2bf(v);
          }
        }
      }
    }
  }
}

// ---------------- depthwise conv (k=4) + SiLU: bf16 in -> bf16 out (2 d per thread) ----------------
__global__ __launch_bounds__(256) void conv_kernel(const u16* __restrict__ xzb,
    const float* __restrict__ cw, const float* __restrict__ cb,
    u16* __restrict__ xc_bf) {
  int idx = blockIdx.x*256 + threadIdx.x;   // over T_TOK*256
  int d2 = (idx & 255)*2;
  int t = idx >> 8;
  int l = t & (SEQ-1);
  float acc0 = cb[d2], acc1 = cb[d2+1];
  float4 wA = *(const float4*)&cw[d2*4];
  float4 wB = *(const float4*)&cw[d2*4+4];
  const u16* base = xzb + (size_t)t*1024 + d2;
  ushort2 v;
  if (l>=3){ v = *(const ushort2*)&base[-3*1024]; acc0 += bf2f(v.x)*wA.x; acc1 += bf2f(v.y)*wB.x; }
  if (l>=2){ v = *(const ushort2*)&base[-2*1024]; acc0 += bf2f(v.x)*wA.y; acc1 += bf2f(v.y)*wB.y; }
  if (l>=1){ v = *(const ushort2*)&base[-1*1024]; acc0 += bf2f(v.x)*wA.z; acc1 += bf2f(v.y)*wB.z; }
  v = *(const ushort2*)&base[0];
  acc0 += bf2f(v.x)*wA.w; acc1 += bf2f(v.y)*wB.w;
  float r0 = acc0 * sigmoidf_(acc0);
  float r1 = acc1 * sigmoidf_(acc1);
  *(unsigned*)&xc_bf[(size_t)t*DI + d2] = cvt_pk_bf16(r0, r1);
}

// ---------------- dt = softplus(dbl[:,:16] @ W_dt + b_dt), wave per token ----------------
__global__ __launch_bounds__(256) void dt_kernel(const float* __restrict__ dbl,
    const float* __restrict__ Wdt, const float* __restrict__ bdt,
    float* __restrict__ dt) {
  __shared__ float sdbl[4][16];
  int wid = threadIdx.x>>6, lane = threadIdx.x&63;
  int token = blockIdx.x*4 + wid;
  if (lane < 16) sdbl[wid][lane] = dbl[(size_t)token*48 + lane];
  __syncthreads();
  float din[16];
#pragma unroll
  for (int k=0;k<16;++k) din[k] = sdbl[wid][k];
#pragma unroll
  for (int r=0;r<8;++r){
    int d = lane + r*64;
    float acc = bdt[d];
#pragma unroll
    for (int k=0;k<16;++k) acc += din[k]*Wdt[k*DI+d];
    float sp = (acc > 20.f) ? acc : log1pf(__expf(acc));
    dt[(size_t)token*DI+d] = sp;
  }
}

// ---------------- chunked selective scan, thread-per-channel ----------------
__global__ __launch_bounds__(512) void scan_p1(const u16* __restrict__ xc_bf,
    const float* __restrict__ dt, const float* __restrict__ dbl,
    const float* __restrict__ A_log, float* __restrict__ Pws, float* __restrict__ Hws) {
  __shared__ float sB[CL][16];
  int d = threadIdx.x;
  int bc = blockIdx.x;          // 0..255
  int b = bc >> 6, c = bc & 63;
  {
    int t = threadIdx.x >> 4, n = threadIdx.x & 15;
    sB[t][n] = dbl[((size_t)b*SEQ + c*CL + t)*48 + DTR + n];
  }
  __syncthreads();
  float An[16];
#pragma unroll
  for (int i=0;i<4;++i){
    float4 a = *(const float4*)&A_log[d*16 + i*4];
    An[i*4+0] = -__expf(a.x); An[i*4+1] = -__expf(a.y);
    An[i*4+2] = -__expf(a.z); An[i*4+3] = -__expf(a.w);
  }
  float h[16] = {};
  float P[16];
#pragma unroll
  for (int n=0;n<16;++n) P[n] = 1.f;
  size_t tok = (size_t)b*SEQ + c*CL;
  for (int t=0;t<CL;++t,++tok){
    float dtv = dt[tok*DI+d];
    float xcv = bf2f(xc_bf[tok*DI+d]);
    float u = dtv*xcv;
    float4 B0 = *(float4*)&sB[t][0];
    float4 B1 = *(float4*)&sB[t][4];
    float4 B2 = *(float4*)&sB[t][8];
    float4 B3 = *(float4*)&sB[t][12];
    float Bv[16] = {B0.x,B0.y,B0.z,B0.w,B1.x,B1.y,B1.z,B1.w,
                    B2.x,B2.y,B2.z,B2.w,B3.x,B3.y,B3.z,B3.w};
#pragma unroll
    for (int n=0;n<16;++n){
      float e = __expf(dtv*An[n]);
      P[n] *= e;
      h[n] = e*h[n] + u*Bv[n];
    }
  }
  size_t base = (((size_t)b*NCH + c)*DI + d)*16;
#pragma unroll
  for (int n=0;n<16;++n){ Pws[base+n] = P[n]; Hws[base+n] = h[n]; }
}

__global__ __launch_bounds__(256) void scan_combine(const float* __restrict__ Pws,
    const float* __restrict__ Hws, float* __restrict__ H0ws) {
  int gid = blockIdx.x*256 + threadIdx.x;  // 0..32767 = (b, d*16+n)
  int b  = gid >> 13;
  int dn = gid & 8191;
  float h0 = 0.f;
#pragma unroll 4
  for (int c=0;c<NCH;++c){
    size_t idx = ((size_t)(b*NCH+c)<<13) + dn;
    H0ws[idx] = h0;
    h0 = Pws[idx]*h0 + Hws[idx];
  }
}

__global__ __launch_bounds__(512) void scan_p2(const u16* __restrict__ xc_bf,
    const float* __restrict__ dt, const float* __restrict__ dbl,
    const float* __restrict__ A_log, const float* __restrict__ Dp,
    const u16* __restrict__ xzb, const float* __restrict__ H0ws,
    u16* __restrict__ ygate_bf) {
  __shared__ float sBC[CL][32];
  int d = threadIdx.x;
  int bc = blockIdx.x;
  int b = bc >> 6, c = bc & 63;
#pragma unroll
  for (int i=0;i<2;++i){
    int idx = i*512 + threadIdx.x;
    int t = idx >> 5, q = idx & 31;
    sBC[t][q] = dbl[((size_t)b*SEQ + c*CL + t)*48 + DTR + q];
  }
  __syncthreads();
  float An[16];
#pragma unroll
  for (int i=0;i<4;++i){
    float4 a = *(const float4*)&A_log[d*16 + i*4];
    An[i*4+0] = -__expf(a.x); An[i*4+1] = -__expf(a.y);
    An[i*4+2] = -__expf(a.z); An[i*4+3] = -__expf(a.w);
  }
  float Dd = Dp[d];
  float h[16];
  size_t base = (((size_t)b*NCH + c)*DI + d)*16;
#pragma unroll
  for (int i=0;i<4;++i){
    float4 h4 = *(const float4*)&H0ws[base + i*4];
    h[i*4+0]=h4.x; h[i*4+1]=h4.y; h[i*4+2]=h4.z; h[i*4+3]=h4.w;
  }
  size_t tok = (size_t)b*SEQ + c*CL;
  for (int t=0;t<CL;++t,++tok){
    float dtv = dt[tok*DI+d];
    float xcv = bf2f(xc_bf[tok*DI+d]);
    float zv  = bf2f(xzb[tok*1024 + DI + d]);
    float u = dtv*xcv;
    float4 B0 = *(float4*)&sBC[t][0];
    float4 B1 = *(float4*)&sBC[t][4];
    float4 B2 = *(float4*)&sBC[t][8];
    float4 B3 = *(float4*)&sBC[t][12];
    float4 C0 = *(float4*)&sBC[t][16];
    float4 C1 = *(float4*)&sBC[t][20];
    float4 C2 = *(float4*)&sBC[t][24];
    float4 C3 = *(float4*)&sBC[t][28];
    float Bv[16] = {B0.x,B0.y,B0.z,B0.w,B1.x,B1.y,B1.z,B1.w,
                    B2.x,B2.y,B2.z,B2.w,B3.x,B3.y,B3.z,B3.w};
    float Cv[16] = {C0.x,C0.y,C0.z,C0.w,C1.x,C1.y,C1.z,C1.w,
                    C2.x,C2.y,C2.z,C2.w,C3.x,C3.y,C3.z,C3.w};
    float y = 0.f;
#pragma unroll
    for (int n=0;n<16;++n){
      float e = __expf(dtv*An[n]);
      h[n] = e*h[n] + u*Bv[n];
      y += h[n]*Cv[n];
    }
    y += xcv*Dd;
    ygate_bf[tok*DI + d] = f2bf(y * (zv*sigmoidf_(zv)));
  }
}

// ---------------- V transpose: vT[bh][d][seq] ----------------
__global__ __launch_bounds__(256) void vt_kernel(const u16* __restrict__ qkvb,
    u16* __restrict__ vT) {
  int bh = blockIdx.y; int b = bh>>2, h = bh&3;
  int l0 = blockIdx.x*64;
  int d = threadIdx.x & 63;
  int oct = threadIdx.x >> 6;   // 0..3
  u16 tmp[16];
#pragma unroll
  for (int i=0;i<16;++i){
    int l = l0 + oct*16 + i;
    tmp[i] = qkvb[((size_t)b*SEQ + l)*768 + 512 + h*HD + d];
  }
  size_t dst = ((size_t)bh*HD + d)*SEQ + l0 + oct*16;
  *(bf16x8*)&vT[dst]   = *(bf16x8*)&tmp[0];
  *(bf16x8*)&vT[dst+8] = *(bf16x8*)&tmp[8];
}

// ---------------- MFMA bf16 flash attention (S^T form, exp2 domain), KV-split 4 ----------------
// XCD-swizzled: each (bh,s) group's 32 q-blocks land on one XCD.
__global__ __launch_bounds__(256) void attn_mfma_kernel(const u16* __restrict__ qkvb,
    const u16* __restrict__ vT,
    float* __restrict__ Opart, float* __restrict__ ml) {
  __shared__ u16 lds[12288];   // K 64x64 @0, V_T 64x64 @4096, P[w] 16x64 @8192+w*1024
  int H = blockIdx.x + 32*blockIdx.y + 512*(int)blockIdx.z;
  int cx = H & 7, k = H >> 3;
  int xq = k & 31;
  int G  = cx*8 + (k >> 5);        // 0..63, contiguous per XCD
  int bh = G & 15, s = G >> 4;
  int b = bh>>2, h = bh&3;
  int tid = threadIdx.x;
  int w = tid>>6, l = tid&63;
  int lq = l & 15;
  int lg = l >> 4;
  size_t bbase = (size_t)b*SEQ;
  size_t vbase = (size_t)bh*HD*SEQ;
  int q0 = xq*64 + w*16;

  bf16x8 qf[2];   // Q pre-scaled by 0.125*log2e in qkv GEMM
#pragma unroll
  for (int dsl=0; dsl<2; ++dsl)
    qf[dsl] = *(const bf16x8*)&qkvb[(bbase + q0 + lq)*768 + h*HD + lg*8 + dsl*32];

  float m_ = -1e30f, l_ = 0.f;
  f32x4 oacc[4] = {{0,0,0,0},{0,0,0,0},{0,0,0,0},{0,0,0,0}};
  int pbase = 8192 + w*1024;

  for (int kt=s*8; kt<s*8+8; ++kt){
    __syncthreads();
#pragma unroll
    for (int i=0;i<2;++i){
      int gid = i*256 + tid;
      int row = gid>>3, g = gid&7;
      *(bf16x8*)&lds[row*64 + ((g ^ (row&7))*8)] =
          *(const bf16x8*)&qkvb[(bbase + kt*64 + row)*768 + 256 + h*HD + g*8];
    }
#pragma unroll
    for (int i=0;i<2;++i){
      int gid = i*256 + tid;
      int row = gid>>3, g = gid&7;
      *(bf16x8*)&lds[4096 + row*64 + ((g ^ (row&7))*8)] =
          *(const bf16x8*)&vT[vbase + (size_t)row*SEQ + kt*64 + g*8];
    }
    __syncthreads();

    f32x4 sacc[4] = {{0,0,0,0},{0,0,0,0},{0,0,0,0},{0,0,0,0}};
    __builtin_amdgcn_s_setprio(1);
#pragma unroll
    for (int kg=0;kg<4;++kg){
#pragma unroll
      for (int dsl=0;dsl<2;++dsl){
        int row = kg*16 + lq;
        bf16x8 kf = *(bf16x8*)&lds[row*64 + (((dsl*4 + lg) ^ (row&7))*8)];
        sacc[kg] = __builtin_amdgcn_mfma_f32_16x16x32_bf16(kf, qf[dsl], sacc[kg], 0,0,0);
      }
    }
    __builtin_amdgcn_s_setprio(0);

    // scores already in log2 domain
    float tm = sacc[0][0];
#pragma unroll
    for (int kg=0;kg<4;++kg){
      float a = fmaxf(fmaxf(sacc[kg][0],sacc[kg][1]),fmaxf(sacc[kg][2],sacc[kg][3]));
      tm = fmaxf(tm, a);
    }
    tm = fmaxf(tm, __shfl_xor(tm,16));
    tm = fmaxf(tm, __shfl_xor(tm,32));
    if (__any(tm - m_ > 8.f)) {      // defer-max: rescale only on real growth
      float mn = fmaxf(m_, tm);
      float sc = exp2f(m_ - mn);
      m_ = mn;
      l_ *= sc;
#pragma unroll
      for (int dg=0;dg<4;++dg){
        oacc[dg][0]*=sc; oacc[dg][1]*=sc; oacc[dg][2]*=sc; oacc[dg][3]*=sc;
      }
    }
    float p[4][4];
    float ps = 0.f;
#pragma unroll
    for (int kg=0;kg<4;++kg)
#pragma unroll
      for (int r=0;r<4;++r){
        float pe = exp2f(sacc[kg][r] - m_);
        p[kg][r] = pe;
        ps += pe;
      }
    ps += __shfl_xor(ps,16);
    ps += __shfl_xor(ps,32);
    l_ += ps;

#pragma unroll
    for (int kg=0;kg<4;++kg)
#pragma unroll
      for (int rp=0;rp<2;++rp){
        unsigned pk = cvt_pk_bf16(p[kg][2*rp], p[kg][2*rp+1]);
        int off = pbase + lq*64 + (((2*kg + (lg>>1)) ^ (lq&7))*8) + 4*(lg&1) + 2*rp;
        *(unsigned*)&lds[off] = pk;
      }

    __builtin_amdgcn_s_setprio(1);
#pragma unroll
    for (int ks=0;ks<2;++ks){
      bf16x8 pf = *(bf16x8*)&lds[pbase + lq*64 + (((ks*4 + lg) ^ (lq&7))*8)];
#pragma unroll
      for (int dg=0;dg<4;++dg){
        int row = dg*16 + lq;
        bf16x8 vf = *(bf16x8*)&lds[4096 + row*64 + (((ks*4 + lg) ^ (row&7))*8)];
        oacc[dg] = __builtin_amdgcn_mfma_f32_16x16x32_bf16(vf, pf, oacc[dg], 0,0,0);
      }
    }
    __builtin_amdgcn_s_setprio(0);
  }

  int sidx = bh*4 + s;
  size_t rb = ((size_t)sidx*SEQ + q0 + lq)*64;
#pragma unroll
  for (int dg=0;dg<4;++dg)
#pragma unroll
    for (int r=0;r<4;++r)
      Opart[rb + dg*16 + lg*4 + r] = oacc[dg][r];
  if (lg==0){
    ml[((size_t)sidx*SEQ + q0 + lq)*2    ] = m_;
    ml[((size_t)sidx*SEQ + q0 + lq)*2 + 1] = l_;
  }
}

// ---------------- merge 4 KV-chunk partials (log2 domain) -> bf16 attn_o ----------------
__global__ __launch_bounds__(256) void attn_merge_kernel(const float* __restrict__ Opart,
    const float* __restrict__ ml, u16* __restrict__ attn_bf) {
  int w = threadIdx.x>>6, lane = threadIdx.x&63;
  int R = blockIdx.x*4 + w;        // 0..32767
  int bh = R>>11, q = R&2047;
  float m[4], lv[4];
#pragma unroll
  for (int s=0;s<4;++s){
    m[s]  = ml[((size_t)(bh*4+s)*SEQ + q)*2];
    lv[s] = ml[((size_t)(bh*4+s)*SEQ + q)*2 + 1];
  }
  float ms = fmaxf(fmaxf(m[0],m[1]),fmaxf(m[2],m[3]));
  float o = 0.f, lsum = 0.f;
#pragma unroll
  for (int s=0;s<4;++s){
    float wsc = exp2f(m[s]-ms);
    lsum += wsc*lv[s];
    o += wsc*Opart[((size_t)(bh*4+s)*SEQ + q)*64 + lane];
  }
  size_t token = (size_t)(bh>>2)*SEQ + q;
  attn_bf[token*DM + (bh&3)*HD + lane] = f2bf(o/lsum);
}

extern "C" void kernel_launch(void* const* d_in, const int* in_sizes, int n_in,
                              void* d_out, int out_size, void* d_ws, size_t ws_size,
                              hipStream_t stream) {
  const float* x      = (const float*)d_in[0];
  const float* ln_g   = (const float*)d_in[1];
  const float* ln_b   = (const float*)d_in[2];
  const float* W_in   = (const float*)d_in[3];
  const float* conv_w = (const float*)d_in[4];
  const float* conv_b = (const float*)d_in[5];
  const float* W_xproj= (const float*)d_in[6];
  const float* W_dt   = (const float*)d_in[7];
  const float* b_dt   = (const float*)d_in[8];
  const float* A_log  = (const float*)d_in[9];
  const float* Dp     = (const float*)d_in[10];
  const float* W_out_m= (const float*)d_in[11];
  const float* W_qkv  = (const float*)d_in[12];
  const float* b_qkv  = (const float*)d_in[13];
  const float* W_o    = (const float*)d_in[14];
  const float* b_o    = (const float*)d_in[15];
  const float* W_gate = (const float*)d_in[16];
  const float* b_gate = (const float*)d_in[17];
  float* out = (float*)d_out;

  float* ws = (float*)d_ws;
  u16*   xn_bf   = (u16*)(ws);                       // 2,097,152 u
  u16*   xzb     = (u16*)(ws + 1048576);             // bf16 xz: 8,388,608 u (region 8.4M f)
  u16*   qkv_bf  = (u16*)(ws + 9437184);             // 6,291,456 u
  u16*   xc_bf   = (u16*)(ws + 12582912);            // 4,194,304 u
  float* dblb    = ws + 16777216;                    //   393,216
  float* dtb     = ws + 17170432;                    // 4,194,304
  u16*   ygate_bf= (u16*)(ws + 21364736);            // 4,194,304 u
  u16*   attn_bf = (u16*)(ws + 23461888);            // 2,097,152 u
  float* catb    = ws + 24510464;                    // 4,194,304
  u16*   catb_bf = (u16*)(ws + 28704768);            // 4,194,304 u
  float* gateb   = ws + 30801920;                    // 2,097,152 (unused now)
  u16*   Wt_all  = (u16*)(ws + 32899072);            //   819,200 u
  // aliases (lifetime-disjoint):
  float* Opart = ws + 1048576;       // attn partials after xzb dead (post scan_p2)
  float* mlb   = (float*)xn_bf;      // after xn_bf dead (post qkv gemm)
  u16*   vTb   = (u16*)dtb;          // after dtb dead (post scan_p2)
  float* Pws   = catb;               // scan summaries before catb written
  float* Hws   = catb + 2097152;
  float* H0ws  = catb + 4194304;
  (void)gateb;

  u16* Wt_in   = Wt_all;             // 1024x256
  u16* Wt_qkv  = Wt_all + 262144;    // 768x256
  u16* Wt_out  = Wt_all + 458752;    // 256x512
  u16* Wt_o    = Wt_all + 589824;    // 256x256
  u16* Wt_gate = Wt_all + 655360;    // 256x512
  u16* Wt_xp   = Wt_all + 786432;    // 64x512 (48 valid + 16 zero rows)

  tcvt_kernel<<<dim3(16,256), 64, 0, stream>>>(W_in,    Wt_in,   1024, 256);
  tcvt_kernel<<<dim3(12,256), 64, 0, stream>>>(W_qkv,   Wt_qkv,   768, 256);
  tcvt_kernel<<<dim3(4,512),  64, 0, stream>>>(W_out_m, Wt_out,   256, 512);
  tcvt_kernel<<<dim3(4,256),  64, 0, stream>>>(W_o,     Wt_o,     256, 256);
  tcvt_kernel<<<dim3(4,512),  64, 0, stream>>>(W_gate,  Wt_gate,  256, 512);
  tcvt_pad_kernel<<<dim3(1,512), 64, 0, stream>>>(W_xproj, Wt_xp, 512, 48);

  ln_kernel<<<T_TOK/4, 256, 0, stream>>>(x, ln_g, ln_b, xn_bf);
  gemm_mfma<0><<<dim3(16,64), 256, 0, stream>>>(xn_bf, Wt_in, nullptr, nullptr, xzb, 256, 1024, 1024, 0, 1.f, nullptr, nullptr);
  gemm_mfma<0><<<dim3(12,64), 256, 0, stream>>>(xn_bf, Wt_qkv, b_qkv, nullptr, qkv_bf, 256, 768, 768, 256, QSCALE, nullptr, nullptr);
  conv_kernel<<<T_TOK, 256, 0, stream>>>(xzb, conv_w, conv_b, xc_bf);
  gemm_mfma<0><<<dim3(1,64), 256, 0, stream>>>(xc_bf, Wt_xp, nullptr, dblb, nullptr, 512, 48, 48, 0, 1.f, nullptr, nullptr);
  dt_kernel<<<T_TOK/4, 256, 0, stream>>>(dblb, W_dt, b_dt, dtb);
  scan_p1<<<B_SZ*NCH, 512, 0, stream>>>(xc_bf, dtb, dblb, A_log, Pws, Hws);
  scan_combine<<<128, 256, 0, stream>>>(Pws, Hws, H0ws);
  scan_p2<<<B_SZ*NCH, 512, 0, stream>>>(xc_bf, dtb, dblb, A_log, Dp, xzb, H0ws, ygate_bf);
  vt_kernel<<<dim3(SEQ/64, 16), 256, 0, stream>>>(qkv_bf, vTb);
  attn_mfma_kernel<<<dim3(SEQ/64, 16, 4), 256, 0, stream>>>(qkv_bf, vTb, Opart, mlb);
  attn_merge_kernel<<<8192, 256, 0, stream>>>(Opart, mlb, attn_bf);
  gemm_mfma<0><<<dim3(4,64), 256, 0, stream>>>(ygate_bf, Wt_out, nullptr, catb, catb_bf, 512, 512, 256, 0, 1.f, nullptr, nullptr);
  gemm_mfma<0><<<dim3(4,64), 256, 0, stream>>>(attn_bf, Wt_o, b_o, catb+256, catb_bf+256, 256, 512, 256, 0, 1.f, nullptr, nullptr);
  gemm_mfma<2><<<dim3(4,64), 256, 0, stream>>>(catb_bf, Wt_gate, b_gate, out, nullptr, 512, 256, 256, 0, 1.f, x, catb);
}

// Round 9
// 252.519 us; speedup vs baseline: 9.6761x; 1.0310x over previous
//
#include <hip/hip_runtime.h>
#include <math.h>

#define B_SZ 4
#define SEQ 2048
#define DM 256
#define DI 512
#define DS 16
#define DTR 16
#define NH 4
#define HD 64
#define T_TOK (B_SZ*SEQ)   // 8192
#define NCH 64             // scan time-chunks
#define CL (SEQ/NCH)       // 32
#define QSCALE 0.18033688f // 0.125 * log2(e)

typedef short bf16x8 __attribute__((ext_vector_type(8)));
typedef float f32x4  __attribute__((ext_vector_type(4)));
typedef unsigned short u16;

__device__ __forceinline__ float sigmoidf_(float x){ return 1.f/(1.f+__expf(-x)); }
__device__ __forceinline__ u16 f2bf(float x){
  unsigned int u = __float_as_uint(x);
  u += 0x7fffu + ((u>>16)&1u);
  return (u16)(u>>16);
}
__device__ __forceinline__ float bf2f(u16 u){ return __uint_as_float(((unsigned)u)<<16); }
__device__ __forceinline__ unsigned cvt_pk_bf16(float lo, float hi){
  unsigned r;
  asm("v_cvt_pk_bf16_f32 %0, %1, %2" : "=v"(r) : "v"(lo), "v"(hi));
  return r;
}

// ---------------- all weight transposes in one kernel: dst[n][k] = bf16(src[k][n]) ----------------
struct TcvtArgs {
  const float* src[6];
  u16* dst[6];
  int K[6];
  int Nvalid[6];
  int Npad[6];
};
__global__ __launch_bounds__(256) void tcvt_all(TcvtArgs a) {
  int wi = blockIdx.z;
  int K = a.K[wi], Nv = a.Nvalid[wi], Np = a.Npad[wi];
  int k0 = blockIdx.x*64, n0 = blockIdx.y*64;
  if (k0 >= K || n0 >= Np) return;
  __shared__ u16 tile[64][65];
  const float* src = a.src[wi];
  u16* dst = a.dst[wi];
  int tn = threadIdx.x & 63, tq = threadIdx.x >> 6;
#pragma unroll
  for (int j=0;j<16;++j){
    int kk = j*4 + tq;
    int n = n0 + tn;
    tile[tn][kk] = (n < Nv) ? f2bf(src[(size_t)(k0+kk)*Nv + n]) : (u16)0;
  }
  __syncthreads();
#pragma unroll
  for (int j=0;j<16;++j){
    int nn = j*4 + tq;
    dst[(size_t)(n0+nn)*K + k0 + tn] = tile[nn][tn];
  }
}

// ---------------- LayerNorm: one wave per token -> bf16 ----------------
__global__ __launch_bounds__(256) void ln_kernel(const float* __restrict__ x,
    const float* __restrict__ g, const float* __restrict__ b,
    u16* __restrict__ xn_bf) {
  int wid = threadIdx.x >> 6;
  int lane = threadIdx.x & 63;
  int token = blockIdx.x*4 + wid;
  const float* xr = x + (size_t)token*DM;
  float4 v = *(const float4*)&xr[lane*4];
  float s  = v.x+v.y+v.z+v.w;
  float ss = v.x*v.x+v.y*v.y+v.z*v.z+v.w*v.w;
  for (int m=1;m<64;m<<=1){ s += __shfl_xor(s,m); ss += __shfl_xor(ss,m); }
  float mu  = s * (1.f/DM);
  float var = ss*(1.f/DM) - mu*mu;
  float rs  = rsqrtf(var + 1e-5f);
  float4 gv = *(const float4*)&g[lane*4];
  float4 bv = *(const float4*)&b[lane*4];
  uint2 o;
  o.x = cvt_pk_bf16((v.x-mu)*rs*gv.x + bv.x, (v.y-mu)*rs*gv.y + bv.y);
  o.y = cvt_pk_bf16((v.z-mu)*rs*gv.z + bv.z, (v.w-mu)*rs*gv.w + bv.w);
  *(uint2*)&xn_bf[(size_t)token*DM + lane*4] = o;
}

// ---------------- MFMA bf16 GEMM: C[M,N] = A[M,K](bf16) @ Wt[N,K](bf16) ----------------
// ACT: 0=none, 1=sigmoid, 2=gate-fused final, 3=qkv (qscale cols<256, vT scatter cols>=512)
template<int ACT>
__global__ __launch_bounds__(256) void gemm_mfma(const u16* __restrict__ A,
    const u16* __restrict__ Wt, const float* __restrict__ bias,
    float* __restrict__ C, u16* __restrict__ Cbf, int K, int ldc, int nvalid,
    int qcols, float qscale, const float* __restrict__ xres,
    const float* __restrict__ cat2, u16* __restrict__ vTout) {
  __shared__ u16 lds[12288];    // As 128x64 @0 (8192), Bs 64x64 @8192 (4096)
  int tid = threadIdx.x;
  int m0 = blockIdx.y*128, n0 = blockIdx.x*64;
  int w = tid>>6, l = tid&63, lq = l&15, lg = l>>4;
  int wm = w>>1, wn = w&1;
  f32x4 acc[4][2] = {};
  for (int k0 = 0; k0 < K; k0 += 64) {
#pragma unroll
    for (int i=0;i<4;++i){
      int gid = i*256 + tid;
      int row = gid>>3, g = gid&7;
      *(bf16x8*)&lds[row*64 + ((g ^ (row&7))*8)] =
          *(const bf16x8*)&A[(size_t)(m0+row)*K + k0 + g*8];
    }
#pragma unroll
    for (int i=0;i<2;++i){
      int gid = i*256 + tid;
      int row = gid>>3, g = gid&7;
      *(bf16x8*)&lds[8192 + row*64 + ((g ^ (row&7))*8)] =
          *(const bf16x8*)&Wt[(size_t)(n0+row)*K + k0 + g*8];
    }
    __syncthreads();
#pragma unroll
    for (int ks=0;ks<2;++ks){
      bf16x8 af[4], bfv[2];
#pragma unroll
      for (int mi=0;mi<4;++mi){
        int row = wm*64 + mi*16 + lq;
        af[mi] = *(bf16x8*)&lds[row*64 + (((ks*4+lg) ^ (row&7))*8)];
      }
#pragma unroll
      for (int nj=0;nj<2;++nj){
        int row = wn*32 + nj*16 + lq;
        bfv[nj] = *(bf16x8*)&lds[8192 + row*64 + (((ks*4+lg) ^ (row&7))*8)];
      }
#pragma unroll
      for (int mi=0;mi<4;++mi)
#pragma unroll
        for (int nj=0;nj<2;++nj)
          acc[mi][nj] = __builtin_amdgcn_mfma_f32_16x16x32_bf16(af[mi], bfv[nj], acc[mi][nj], 0,0,0);
    }
    __syncthreads();
  }
#pragma unroll
  for (int mi=0;mi<4;++mi){
#pragma unroll
    for (int nj=0;nj<2;++nj){
#pragma unroll
      for (int r=0;r<4;++r){
        int row = m0 + wm*64 + mi*16 + lg*4 + r;
        int col = n0 + wn*32 + nj*16 + lq;
        if (col < nvalid) {
          float v = acc[mi][nj][r];
          if (bias) v += bias[col];
          if (col < qcols) v *= qscale;
          if (ACT==2) {
            float g = sigmoidf_(v);
            float sv = cat2[(size_t)row*512 + col];
            float av = cat2[(size_t)row*512 + 256 + col];
            C[(size_t)row*256 + col] = xres[(size_t)row*256 + col] + g*sv + (1.f-g)*av;
          } else if (ACT==3) {
            Cbf[(size_t)row*ldc + col] = f2bf(v);
            if (col >= 512) {
              int bb = row>>11, ll = row&2047;
              int hh = (col-512)>>6, dd = (col-512)&63;
              vTout[(((size_t)(bb*4+hh))*64 + dd)*SEQ + ll] = f2bf(v);
            }
          } else {
            if (ACT==1) v = sigmoidf_(v);
            if (C)   C[(size_t)row*ldc + col] = v;
            if (Cbf) Cbf[(size_t)row*ldc + col] = f2bf(v);
          }
        }
      }
    }
  }
}

// ---------------- depthwise conv (k=4) + SiLU: bf16 in -> bf16 out ----------------
__global__ __launch_bounds__(256) void conv_kernel(const u16* __restrict__ xzb,
    const float* __restrict__ cw, const float* __restrict__ cb,
    u16* __restrict__ xc_bf) {
  int idx = blockIdx.x*256 + threadIdx.x;   // over T_TOK*256
  int d2 = (idx & 255)*2;
  int t = idx >> 8;
  int l = t & (SEQ-1);
  float acc0 = cb[d2], acc1 = cb[d2+1];
  float4 wA = *(const float4*)&cw[d2*4];
  float4 wB = *(const float4*)&cw[d2*4+4];
  const u16* base = xzb + (size_t)t*1024 + d2;
  ushort2 v;
  if (l>=3){ v = *(const ushort2*)&base[-3*1024]; acc0 += bf2f(v.x)*wA.x; acc1 += bf2f(v.y)*wB.x; }
  if (l>=2){ v = *(const ushort2*)&base[-2*1024]; acc0 += bf2f(v.x)*wA.y; acc1 += bf2f(v.y)*wB.y; }
  if (l>=1){ v = *(const ushort2*)&base[-1*1024]; acc0 += bf2f(v.x)*wA.z; acc1 += bf2f(v.y)*wB.z; }
  v = *(const ushort2*)&base[0];
  acc0 += bf2f(v.x)*wA.w; acc1 += bf2f(v.y)*wB.w;
  float r0 = acc0 * sigmoidf_(acc0);
  float r1 = acc1 * sigmoidf_(acc1);
  *(unsigned*)&xc_bf[(size_t)t*DI + d2] = cvt_pk_bf16(r0, r1);
}

// ---------------- dt = softplus(dbl[:,:16] @ W_dt + b_dt), wave per token ----------------
__global__ __launch_bounds__(256) void dt_kernel(const float* __restrict__ dbl,
    const float* __restrict__ Wdt, const float* __restrict__ bdt,
    float* __restrict__ dt) {
  __shared__ float sdbl[4][16];
  int wid = threadIdx.x>>6, lane = threadIdx.x&63;
  int token = blockIdx.x*4 + wid;
  if (lane < 16) sdbl[wid][lane] = dbl[(size_t)token*48 + lane];
  __syncthreads();
  float din[16];
#pragma unroll
  for (int k=0;k<16;++k) din[k] = sdbl[wid][k];
#pragma unroll
  for (int r=0;r<8;++r){
    int d = lane + r*64;
    float acc = bdt[d];
#pragma unroll
    for (int k=0;k<16;++k) acc += din[k]*Wdt[k*DI+d];
    float sp = (acc > 20.f) ? acc : log1pf(__expf(acc));
    dt[(size_t)token*DI+d] = sp;
  }
}

// ---------------- chunked selective scan, thread-per-channel ----------------
__global__ __launch_bounds__(512) void scan_p1(const u16* __restrict__ xc_bf,
    const float* __restrict__ dt, const float* __restrict__ dbl,
    const float* __restrict__ A_log, float* __restrict__ Pws, float* __restrict__ Hws) {
  __shared__ float sB[CL][16];
  int d = threadIdx.x;
  int bc = blockIdx.x;          // 0..255
  int b = bc >> 6, c = bc & 63;
  {
    int t = threadIdx.x >> 4, n = threadIdx.x & 15;
    sB[t][n] = dbl[((size_t)b*SEQ + c*CL + t)*48 + DTR + n];
  }
  __syncthreads();
  float An[16];
#pragma unroll
  for (int i=0;i<4;++i){
    float4 a = *(const float4*)&A_log[d*16 + i*4];
    An[i*4+0] = -__expf(a.x); An[i*4+1] = -__expf(a.y);
    An[i*4+2] = -__expf(a.z); An[i*4+3] = -__expf(a.w);
  }
  float h[16] = {};
  float P[16];
#pragma unroll
  for (int n=0;n<16;++n) P[n] = 1.f;
  size_t tok = (size_t)b*SEQ + c*CL;
  for (int t=0;t<CL;++t,++tok){
    float dtv = dt[tok*DI+d];
    float xcv = bf2f(xc_bf[tok*DI+d]);
    float u = dtv*xcv;
    float4 B0 = *(float4*)&sB[t][0];
    float4 B1 = *(float4*)&sB[t][4];
    float4 B2 = *(float4*)&sB[t][8];
    float4 B3 = *(float4*)&sB[t][12];
    float Bv[16] = {B0.x,B0.y,B0.z,B0.w,B1.x,B1.y,B1.z,B1.w,
                    B2.x,B2.y,B2.z,B2.w,B3.x,B3.y,B3.z,B3.w};
#pragma unroll
    for (int n=0;n<16;++n){
      float e = __expf(dtv*An[n]);
      P[n] *= e;
      h[n] = e*h[n] + u*Bv[n];
    }
  }
  size_t base = (((size_t)b*NCH + c)*DI + d)*16;
#pragma unroll
  for (int n=0;n<16;++n){ Pws[base+n] = P[n]; Hws[base+n] = h[n]; }
}

__global__ __launch_bounds__(256) void scan_combine(const float* __restrict__ Pws,
    const float* __restrict__ Hws, float* __restrict__ H0ws) {
  int gid = blockIdx.x*256 + threadIdx.x;  // 0..32767 = (b, d*16+n)
  int b  = gid >> 13;
  int dn = gid & 8191;
  float h0 = 0.f;
#pragma unroll 4
  for (int c=0;c<NCH;++c){
    size_t idx = ((size_t)(b*NCH+c)<<13) + dn;
    H0ws[idx] = h0;
    h0 = Pws[idx]*h0 + Hws[idx];
  }
}

__global__ __launch_bounds__(512) void scan_p2(const u16* __restrict__ xc_bf,
    const float* __restrict__ dt, const float* __restrict__ dbl,
    const float* __restrict__ A_log, const float* __restrict__ Dp,
    const u16* __restrict__ xzb, const float* __restrict__ H0ws,
    u16* __restrict__ ygate_bf) {
  __shared__ float sBC[CL][32];
  int d = threadIdx.x;
  int bc = blockIdx.x;
  int b = bc >> 6, c = bc & 63;
#pragma unroll
  for (int i=0;i<2;++i){
    int idx = i*512 + threadIdx.x;
    int t = idx >> 5, q = idx & 31;
    sBC[t][q] = dbl[((size_t)b*SEQ + c*CL + t)*48 + DTR + q];
  }
  __syncthreads();
  float An[16];
#pragma unroll
  for (int i=0;i<4;++i){
    float4 a = *(const float4*)&A_log[d*16 + i*4];
    An[i*4+0] = -__expf(a.x); An[i*4+1] = -__expf(a.y);
    An[i*4+2] = -__expf(a.z); An[i*4+3] = -__expf(a.w);
  }
  float Dd = Dp[d];
  float h[16];
  size_t base = (((size_t)b*NCH + c)*DI + d)*16;
#pragma unroll
  for (int i=0;i<4;++i){
    float4 h4 = *(const float4*)&H0ws[base + i*4];
    h[i*4+0]=h4.x; h[i*4+1]=h4.y; h[i*4+2]=h4.z; h[i*4+3]=h4.w;
  }
  size_t tok = (size_t)b*SEQ + c*CL;
  for (int t=0;t<CL;++t,++tok){
    float dtv = dt[tok*DI+d];
    float xcv = bf2f(xc_bf[tok*DI+d]);
    float zv  = bf2f(xzb[tok*1024 + DI + d]);
    float u = dtv*xcv;
    float4 B0 = *(float4*)&sBC[t][0];
    float4 B1 = *(float4*)&sBC[t][4];
    float4 B2 = *(float4*)&sBC[t][8];
    float4 B3 = *(float4*)&sBC[t][12];
    float4 C0 = *(float4*)&sBC[t][16];
    float4 C1 = *(float4*)&sBC[t][20];
    float4 C2 = *(float4*)&sBC[t][24];
    float4 C3 = *(float4*)&sBC[t][28];
    float Bv[16] = {B0.x,B0.y,B0.z,B0.w,B1.x,B1.y,B1.z,B1.w,
                    B2.x,B2.y,B2.z,B2.w,B3.x,B3.y,B3.z,B3.w};
    float Cv[16] = {C0.x,C0.y,C0.z,C0.w,C1.x,C1.y,C1.z,C1.w,
                    C2.x,C2.y,C2.z,C2.w,C3.x,C3.y,C3.z,C3.w};
    float y = 0.f;
#pragma unroll
    for (int n=0;n<16;++n){
      float e = __expf(dtv*An[n]);
      h[n] = e*h[n] + u*Bv[n];
      y += h[n]*Cv[n];
    }
    y += xcv*Dd;
    ygate_bf[tok*DI + d] = f2bf(y * (zv*sigmoidf_(zv)));
  }
}

// ---------------- MFMA bf16 flash attention: 128-q blocks, dbuf LDS, async stage ----------------
// grid (16,16,4); 4 waves x 32 q (2 groups of 16); KV tiles of 64; KV-split 4.
__global__ __launch_bounds__(256) void attn_mfma_kernel(const u16* __restrict__ qkvb,
    const u16* __restrict__ vT,
    float* __restrict__ Opart, float* __restrict__ ml) {
  __shared__ u16 lds[24576];   // K dbuf @0/@4096, V dbuf @8192/@12288, P @16384 + w*2048 + qg*1024
  int H = blockIdx.x + 16*blockIdx.y + 256*(int)blockIdx.z;
  int cx = H & 7, k = H >> 3;
  int xq = k & 15;
  int G  = cx*8 + (k >> 4);        // 0..63, contiguous per XCD
  int bh = G & 15, s = G >> 4;
  int b = bh>>2, h = bh&3;
  int tid = threadIdx.x;
  int w = tid>>6, l = tid&63;
  int lq = l & 15;
  int lg = l >> 4;
  size_t bbase = (size_t)b*SEQ;
  size_t vbase = (size_t)bh*HD*SEQ;
  int q0 = xq*128 + w*32;

  bf16x8 qf[2][2];   // [qg][dsl], Q pre-scaled by 0.125*log2e
#pragma unroll
  for (int qg=0; qg<2; ++qg)
#pragma unroll
    for (int dsl=0; dsl<2; ++dsl)
      qf[qg][dsl] = *(const bf16x8*)&qkvb[(bbase + q0 + qg*16 + lq)*768 + h*HD + lg*8 + dsl*32];

  float m_[2] = {-1e30f,-1e30f}, l_[2] = {0.f,0.f};
  f32x4 oacc[2][4] = {};
  int pbase = 16384 + w*2048;

  int srow = tid>>3, sg = tid&7;        // staging: this thread's rows srow, srow+32
  int kt0 = s*8;
  bf16x8 kreg[2], vreg[2];

#define LOADT(kt) { \
  kreg[0] = *(const bf16x8*)&qkvb[(bbase + (size_t)(kt)*64 + srow)*768 + 256 + h*HD + sg*8]; \
  kreg[1] = *(const bf16x8*)&qkvb[(bbase + (size_t)(kt)*64 + srow + 32)*768 + 256 + h*HD + sg*8]; \
  vreg[0] = *(const bf16x8*)&vT[vbase + (size_t)srow*SEQ + (kt)*64 + sg*8]; \
  vreg[1] = *(const bf16x8*)&vT[vbase + (size_t)(srow+32)*SEQ + (kt)*64 + sg*8]; }
#define STORET(bi) { \
  *(bf16x8*)&lds[(bi)*4096 + srow*64 + ((sg ^ (srow&7))*8)] = kreg[0]; \
  *(bf16x8*)&lds[(bi)*4096 + (srow+32)*64 + ((sg ^ ((srow+32)&7))*8)] = kreg[1]; \
  *(bf16x8*)&lds[8192 + (bi)*4096 + srow*64 + ((sg ^ (srow&7))*8)] = vreg[0]; \
  *(bf16x8*)&lds[8192 + (bi)*4096 + (srow+32)*64 + ((sg ^ ((srow+32)&7))*8)] = vreg[1]; }

  LOADT(kt0);
  STORET(0);
  __syncthreads();
  int cur = 0;

  for (int it=0; it<8; ++it){
    if (it < 7) LOADT(kt0+it+1);

    int kb = cur*4096, vb = 8192 + cur*4096;
    f32x4 sacc[2][4] = {};
    __builtin_amdgcn_s_setprio(1);
#pragma unroll
    for (int kg=0;kg<4;++kg){
#pragma unroll
      for (int dsl=0;dsl<2;++dsl){
        int row = kg*16 + lq;
        bf16x8 kf = *(bf16x8*)&lds[kb + row*64 + (((dsl*4 + lg) ^ (row&7))*8)];
        sacc[0][kg] = __builtin_amdgcn_mfma_f32_16x16x32_bf16(kf, qf[0][dsl], sacc[0][kg], 0,0,0);
        sacc[1][kg] = __builtin_amdgcn_mfma_f32_16x16x32_bf16(kf, qf[1][dsl], sacc[1][kg], 0,0,0);
      }
    }
    __builtin_amdgcn_s_setprio(0);

#pragma unroll
    for (int qg=0;qg<2;++qg){
      float tm = sacc[qg][0][0];
#pragma unroll
      for (int kg=0;kg<4;++kg){
        float a = fmaxf(fmaxf(sacc[qg][kg][0],sacc[qg][kg][1]),
                        fmaxf(sacc[qg][kg][2],sacc[qg][kg][3]));
        tm = fmaxf(tm, a);
      }
      tm = fmaxf(tm, __shfl_xor(tm,16));
      tm = fmaxf(tm, __shfl_xor(tm,32));
      if (__any(tm - m_[qg] > 8.f)) {
        float mn = fmaxf(m_[qg], tm);
        float sc = exp2f(m_[qg] - mn);
        m_[qg] = mn;
        l_[qg] *= sc;
#pragma unroll
        for (int dg=0;dg<4;++dg){
          oacc[qg][dg][0]*=sc; oacc[qg][dg][1]*=sc; oacc[qg][dg][2]*=sc; oacc[qg][dg][3]*=sc;
        }
      }
      float ps = 0.f;
#pragma unroll
      for (int kg=0;kg<4;++kg){
        float p0 = exp2f(sacc[qg][kg][0] - m_[qg]);
        float p1 = exp2f(sacc[qg][kg][1] - m_[qg]);
        float p2 = exp2f(sacc[qg][kg][2] - m_[qg]);
        float p3 = exp2f(sacc[qg][kg][3] - m_[qg]);
        ps += (p0+p1)+(p2+p3);
        int off = pbase + qg*1024 + lq*64 + (((2*kg + (lg>>1)) ^ (lq&7))*8) + 4*(lg&1);
        *(unsigned*)&lds[off]   = cvt_pk_bf16(p0, p1);
        *(unsigned*)&lds[off+2] = cvt_pk_bf16(p2, p3);
      }
      ps += __shfl_xor(ps,16);
      ps += __shfl_xor(ps,32);
      l_[qg] += ps;
    }

    __builtin_amdgcn_s_setprio(1);
#pragma unroll
    for (int ks=0;ks<2;++ks){
      bf16x8 pf0 = *(bf16x8*)&lds[pbase        + lq*64 + (((ks*4 + lg) ^ (lq&7))*8)];
      bf16x8 pf1 = *(bf16x8*)&lds[pbase + 1024 + lq*64 + (((ks*4 + lg) ^ (lq&7))*8)];
#pragma unroll
      for (int dg=0;dg<4;++dg){
        int row = dg*16 + lq;
        bf16x8 vf = *(bf16x8*)&lds[vb + row*64 + (((ks*4 + lg) ^ (row&7))*8)];
        oacc[0][dg] = __builtin_amdgcn_mfma_f32_16x16x32_bf16(vf, pf0, oacc[0][dg], 0,0,0);
        oacc[1][dg] = __builtin_amdgcn_mfma_f32_16x16x32_bf16(vf, pf1, oacc[1][dg], 0,0,0);
      }
    }
    __builtin_amdgcn_s_setprio(0);

    if (it < 7) STORET(cur^1);
    __syncthreads();
    cur ^= 1;
  }
#undef LOADT
#undef STORET

  int sidx = bh*4 + s;
#pragma unroll
  for (int qg=0;qg<2;++qg){
    size_t rb = ((size_t)sidx*SEQ + q0 + qg*16 + lq)*64;
#pragma unroll
    for (int dg=0;dg<4;++dg)
#pragma unroll
      for (int r=0;r<4;++r)
        Opart[rb + dg*16 + lg*4 + r] = oacc[qg][dg][r];
    if (lg==0){
      ml[((size_t)sidx*SEQ + q0 + qg*16 + lq)*2    ] = m_[qg];
      ml[((size_t)sidx*SEQ + q0 + qg*16 + lq)*2 + 1] = l_[qg];
    }
  }
}

// ---------------- merge 4 KV-chunk partials (log2 domain) -> bf16 attn_o ----------------
__global__ __launch_bounds__(256) void attn_merge_kernel(const float* __restrict__ Opart,
    const float* __restrict__ ml, u16* __restrict__ attn_bf) {
  int w = threadIdx.x>>6, lane = threadIdx.x&63;
  int R = blockIdx.x*4 + w;        // 0..32767
  int bh = R>>11, q = R&2047;
  float m[4], lv[4];
#pragma unroll
  for (int s=0;s<4;++s){
    m[s]  = ml[((size_t)(bh*4+s)*SEQ + q)*2];
    lv[s] = ml[((size_t)(bh*4+s)*SEQ + q)*2 + 1];
  }
  float ms = fmaxf(fmaxf(m[0],m[1]),fmaxf(m[2],m[3]));
  float o = 0.f, lsum = 0.f;
#pragma unroll
  for (int s=0;s<4;++s){
    float wsc = exp2f(m[s]-ms);
    lsum += wsc*lv[s];
    o += wsc*Opart[((size_t)(bh*4+s)*SEQ + q)*64 + lane];
  }
  size_t token = (size_t)(bh>>2)*SEQ + q;
  attn_bf[token*DM + (bh&3)*HD + lane] = f2bf(o/lsum);
}

extern "C" void kernel_launch(void* const* d_in, const int* in_sizes, int n_in,
                              void* d_out, int out_size, void* d_ws, size_t ws_size,
                              hipStream_t stream) {
  const float* x      = (const float*)d_in[0];
  const float* ln_g   = (const float*)d_in[1];
  const float* ln_b   = (const float*)d_in[2];
  const float* W_in   = (const float*)d_in[3];
  const float* conv_w = (const float*)d_in[4];
  const float* conv_b = (const float*)d_in[5];
  const float* W_xproj= (const float*)d_in[6];
  const float* W_dt   = (const float*)d_in[7];
  const float* b_dt   = (const float*)d_in[8];
  const float* A_log  = (const float*)d_in[9];
  const float* Dp     = (const float*)d_in[10];
  const float* W_out_m= (const float*)d_in[11];
  const float* W_qkv  = (const float*)d_in[12];
  const float* b_qkv  = (const float*)d_in[13];
  const float* W_o    = (const float*)d_in[14];
  const float* b_o    = (const float*)d_in[15];
  const float* W_gate = (const float*)d_in[16];
  const float* b_gate = (const float*)d_in[17];
  float* out = (float*)d_out;

  float* ws = (float*)d_ws;
  u16*   xn_bf   = (u16*)(ws);                       // 2,097,152 u
  u16*   xzb     = (u16*)(ws + 1048576);             // bf16 xz (region 8.4M f)
  u16*   qkv_bf  = (u16*)(ws + 9437184);             // 6,291,456 u
  u16*   xc_bf   = (u16*)(ws + 12582912);            // 4,194,304 u
  float* dblb    = ws + 16777216;                    //   393,216
  float* dtb     = ws + 17170432;                    // 4,194,304
  u16*   ygate_bf= (u16*)(ws + 21364736);            // 4,194,304 u
  u16*   attn_bf = (u16*)(ws + 23461888);            // 2,097,152 u
  float* catb    = ws + 24510464;                    // 4,194,304
  u16*   catb_bf = (u16*)(ws + 28704768);            // 4,194,304 u
  float* gateb   = ws + 30801920;                    // 2,097,152
  u16*   Wt_all  = (u16*)(ws + 32899072);            //   819,200 u
  // aliases (lifetime-disjoint):
  float* Opart = ws + 1048576;       // attn partials after xzb dead (post scan_p2)
  float* mlb   = (float*)xn_bf;      // after xn_bf dead (post qkv gemm)
  u16*   vTb   = (u16*)gateb;        // 4,194,304 u16 — written by qkv gemm epilogue
  float* Pws   = catb;               // scan summaries before catb written
  float* Hws   = catb + 2097152;
  float* H0ws  = catb + 4194304;

  u16* Wt_in   = Wt_all;             // 1024x256
  u16* Wt_qkv  = Wt_all + 262144;    // 768x256
  u16* Wt_out  = Wt_all + 458752;    // 256x512
  u16* Wt_o    = Wt_all + 589824;    // 256x256
  u16* Wt_gate = Wt_all + 655360;    // 256x512
  u16* Wt_xp   = Wt_all + 786432;    // 64x512 (48 valid + 16 zero rows)

  TcvtArgs ta;
  ta.src[0]=W_in;    ta.dst[0]=Wt_in;   ta.K[0]=256; ta.Nvalid[0]=1024; ta.Npad[0]=1024;
  ta.src[1]=W_qkv;   ta.dst[1]=Wt_qkv;  ta.K[1]=256; ta.Nvalid[1]=768;  ta.Npad[1]=768;
  ta.src[2]=W_out_m; ta.dst[2]=Wt_out;  ta.K[2]=512; ta.Nvalid[2]=256;  ta.Npad[2]=256;
  ta.src[3]=W_o;     ta.dst[3]=Wt_o;    ta.K[3]=256; ta.Nvalid[3]=256;  ta.Npad[3]=256;
  ta.src[4]=W_gate;  ta.dst[4]=Wt_gate; ta.K[4]=512; ta.Nvalid[4]=256;  ta.Npad[4]=256;
  ta.src[5]=W_xproj; ta.dst[5]=Wt_xp;   ta.K[5]=512; ta.Nvalid[5]=48;   ta.Npad[5]=64;
  tcvt_all<<<dim3(8,16,6), 256, 0, stream>>>(ta);

  ln_kernel<<<T_TOK/4, 256, 0, stream>>>(x, ln_g, ln_b, xn_bf);
  gemm_mfma<0><<<dim3(16,64), 256, 0, stream>>>(xn_bf, Wt_in, nullptr, nullptr, xzb, 256, 1024, 1024, 0, 1.f, nullptr, nullptr, nullptr);
  gemm_mfma<3><<<dim3(12,64), 256, 0, stream>>>(xn_bf, Wt_qkv, b_qkv, nullptr, qkv_bf, 256, 768, 768, 256, QSCALE, nullptr, nullptr, vTb);
  conv_kernel<<<T_TOK, 256, 0, stream>>>(xzb, conv_w, conv_b, xc_bf);
  gemm_mfma<0><<<dim3(1,64), 256, 0, stream>>>(xc_bf, Wt_xp, nullptr, dblb, nullptr, 512, 48, 48, 0, 1.f, nullptr, nullptr, nullptr);
  dt_kernel<<<T_TOK/4, 256, 0, stream>>>(dblb, W_dt, b_dt, dtb);
  scan_p1<<<B_SZ*NCH, 512, 0, stream>>>(xc_bf, dtb, dblb, A_log, Pws, Hws);
  scan_combine<<<128, 256, 0, stream>>>(Pws, Hws, H0ws);
  scan_p2<<<B_SZ*NCH, 512, 0, stream>>>(xc_bf, dtb, dblb, A_log, Dp, xzb, H0ws, ygate_bf);
  attn_mfma_kernel<<<dim3(16, 16, 4), 256, 0, stream>>>(qkv_bf, vTb, Opart, mlb);
  attn_merge_kernel<<<8192, 256, 0, stream>>>(Opart, mlb, attn_bf);
  gemm_mfma<0><<<dim3(4,64), 256, 0, stream>>>(ygate_bf, Wt_out, nullptr, catb, catb_bf, 512, 512, 256, 0, 1.f, nullptr, nullptr, nullptr);
  gemm_mfma<0><<<dim3(4,64), 256, 0, stream>>>(attn_bf, Wt_o, b_o, catb+256, catb_bf+256, 256, 512, 256, 0, 1.f, nullptr, nullptr, nullptr);
  gemm_mfma<2><<<dim3(4,64), 256, 0, stream>>>(catb_bf, Wt_gate, b_gate, out, nullptr, 512, 256, 256, 0, 1.f, x, catb, nullptr);
}

// Round 10
// 248.711 us; speedup vs baseline: 9.8242x; 1.0153x over previous
//
#include <hip/hip_runtime.h>
#include <math.h>

#define B_SZ 4
#define SEQ 2048
#define DM 256
#define DI 512
#define DS 16
#define DTR 16
#define NH 4
#define HD 64
#define T_TOK (B_SZ*SEQ)   // 8192
#define NCH 64             // scan time-chunks
#define CL (SEQ/NCH)       // 32
#define QSCALE 0.18033688f // 0.125 * log2(e)

typedef short bf16x8 __attribute__((ext_vector_type(8)));
typedef float f32x4  __attribute__((ext_vector_type(4)));
typedef float f32x16 __attribute__((ext_vector_type(16)));
typedef unsigned short u16;

__device__ __forceinline__ float sigmoidf_(float x){ return 1.f/(1.f+__expf(-x)); }
__device__ __forceinline__ u16 f2bf(float x){
  unsigned int u = __float_as_uint(x);
  u += 0x7fffu + ((u>>16)&1u);
  return (u16)(u>>16);
}
__device__ __forceinline__ float bf2f(u16 u){ return __uint_as_float(((unsigned)u)<<16); }
__device__ __forceinline__ unsigned cvt_pk_bf16(float lo, float hi){
  unsigned r;
  asm("v_cvt_pk_bf16_f32 %0, %1, %2" : "=v"(r) : "v"(lo), "v"(hi));
  return r;
}

// ---------------- all weight transposes in one kernel: dst[n][k] = bf16(src[k][n]) ----------------
struct TcvtArgs {
  const float* src[6];
  u16* dst[6];
  int K[6];
  int Nvalid[6];
  int Npad[6];
};
__global__ __launch_bounds__(256) void tcvt_all(TcvtArgs a) {
  int wi = blockIdx.z;
  int K = a.K[wi], Nv = a.Nvalid[wi], Np = a.Npad[wi];
  int k0 = blockIdx.x*64, n0 = blockIdx.y*64;
  if (k0 >= K || n0 >= Np) return;
  __shared__ u16 tile[64][65];
  const float* src = a.src[wi];
  u16* dst = a.dst[wi];
  int tn = threadIdx.x & 63, tq = threadIdx.x >> 6;
#pragma unroll
  for (int j=0;j<16;++j){
    int kk = j*4 + tq;
    int n = n0 + tn;
    tile[tn][kk] = (n < Nv) ? f2bf(src[(size_t)(k0+kk)*Nv + n]) : (u16)0;
  }
  __syncthreads();
#pragma unroll
  for (int j=0;j<16;++j){
    int nn = j*4 + tq;
    dst[(size_t)(n0+nn)*K + k0 + tn] = tile[nn][tn];
  }
}

// ---------------- LayerNorm: one wave per token -> bf16 ----------------
__global__ __launch_bounds__(256) void ln_kernel(const float* __restrict__ x,
    const float* __restrict__ g, const float* __restrict__ b,
    u16* __restrict__ xn_bf) {
  int wid = threadIdx.x >> 6;
  int lane = threadIdx.x & 63;
  int token = blockIdx.x*4 + wid;
  const float* xr = x + (size_t)token*DM;
  float4 v = *(const float4*)&xr[lane*4];
  float s  = v.x+v.y+v.z+v.w;
  float ss = v.x*v.x+v.y*v.y+v.z*v.z+v.w*v.w;
  for (int m=1;m<64;m<<=1){ s += __shfl_xor(s,m); ss += __shfl_xor(ss,m); }
  float mu  = s * (1.f/DM);
  float var = ss*(1.f/DM) - mu*mu;
  float rs  = rsqrtf(var + 1e-5f);
  float4 gv = *(const float4*)&g[lane*4];
  float4 bv = *(const float4*)&b[lane*4];
  uint2 o;
  o.x = cvt_pk_bf16((v.x-mu)*rs*gv.x + bv.x, (v.y-mu)*rs*gv.y + bv.y);
  o.y = cvt_pk_bf16((v.z-mu)*rs*gv.z + bv.z, (v.w-mu)*rs*gv.w + bv.w);
  *(uint2*)&xn_bf[(size_t)token*DM + lane*4] = o;
}

// ---------------- MFMA bf16 GEMM: C[M,N] = A[M,K](bf16) @ Wt[N,K](bf16) ----------------
// ACT: 0=none, 1=sigmoid, 2=gate-fused final, 3=qkv (qscale cols<256, vT scatter cols>=512)
template<int ACT>
__global__ __launch_bounds__(256) void gemm_mfma(const u16* __restrict__ A,
    const u16* __restrict__ Wt, const float* __restrict__ bias,
    float* __restrict__ C, u16* __restrict__ Cbf, int K, int ldc, int nvalid,
    int qcols, float qscale, const float* __restrict__ xres,
    const float* __restrict__ cat2, u16* __restrict__ vTout) {
  __shared__ u16 lds[12288];    // As 128x64 @0 (8192), Bs 64x64 @8192 (4096)
  int tid = threadIdx.x;
  int m0 = blockIdx.y*128, n0 = blockIdx.x*64;
  int w = tid>>6, l = tid&63, lq = l&15, lg = l>>4;
  int wm = w>>1, wn = w&1;
  f32x4 acc[4][2] = {};
  for (int k0 = 0; k0 < K; k0 += 64) {
#pragma unroll
    for (int i=0;i<4;++i){
      int gid = i*256 + tid;
      int row = gid>>3, g = gid&7;
      *(bf16x8*)&lds[row*64 + ((g ^ (row&7))*8)] =
          *(const bf16x8*)&A[(size_t)(m0+row)*K + k0 + g*8];
    }
#pragma unroll
    for (int i=0;i<2;++i){
      int gid = i*256 + tid;
      int row = gid>>3, g = gid&7;
      *(bf16x8*)&lds[8192 + row*64 + ((g ^ (row&7))*8)] =
          *(const bf16x8*)&Wt[(size_t)(n0+row)*K + k0 + g*8];
    }
    __syncthreads();
#pragma unroll
    for (int ks=0;ks<2;++ks){
      bf16x8 af[4], bfv[2];
#pragma unroll
      for (int mi=0;mi<4;++mi){
        int row = wm*64 + mi*16 + lq;
        af[mi] = *(bf16x8*)&lds[row*64 + (((ks*4+lg) ^ (row&7))*8)];
      }
#pragma unroll
      for (int nj=0;nj<2;++nj){
        int row = wn*32 + nj*16 + lq;
        bfv[nj] = *(bf16x8*)&lds[8192 + row*64 + (((ks*4+lg) ^ (row&7))*8)];
      }
#pragma unroll
      for (int mi=0;mi<4;++mi)
#pragma unroll
        for (int nj=0;nj<2;++nj)
          acc[mi][nj] = __builtin_amdgcn_mfma_f32_16x16x32_bf16(af[mi], bfv[nj], acc[mi][nj], 0,0,0);
    }
    __syncthreads();
  }
#pragma unroll
  for (int mi=0;mi<4;++mi){
#pragma unroll
    for (int nj=0;nj<2;++nj){
#pragma unroll
      for (int r=0;r<4;++r){
        int row = m0 + wm*64 + mi*16 + lg*4 + r;
        int col = n0 + wn*32 + nj*16 + lq;
        if (col < nvalid) {
          float v = acc[mi][nj][r];
          if (bias) v += bias[col];
          if (col < qcols) v *= qscale;
          if (ACT==2) {
            float g = sigmoidf_(v);
            float sv = cat2[(size_t)row*512 + col];
            float av = cat2[(size_t)row*512 + 256 + col];
            C[(size_t)row*256 + col] = xres[(size_t)row*256 + col] + g*sv + (1.f-g)*av;
          } else if (ACT==3) {
            Cbf[(size_t)row*ldc + col] = f2bf(v);
            if (col >= 512) {
              int bb = row>>11, ll = row&2047;
              int hh = (col-512)>>6, dd = (col-512)&63;
              vTout[(((size_t)(bb*4+hh))*64 + dd)*SEQ + ll] = f2bf(v);
            }
          } else {
            if (ACT==1) v = sigmoidf_(v);
            if (C)   C[(size_t)row*ldc + col] = v;
            if (Cbf) Cbf[(size_t)row*ldc + col] = f2bf(v);
          }
        }
      }
    }
  }
}

// ---------------- depthwise conv (k=4) + SiLU: bf16 in -> bf16 out ----------------
__global__ __launch_bounds__(256) void conv_kernel(const u16* __restrict__ xzb,
    const float* __restrict__ cw, const float* __restrict__ cb,
    u16* __restrict__ xc_bf) {
  int idx = blockIdx.x*256 + threadIdx.x;   // over T_TOK*256
  int d2 = (idx & 255)*2;
  int t = idx >> 8;
  int l = t & (SEQ-1);
  float acc0 = cb[d2], acc1 = cb[d2+1];
  float4 wA = *(const float4*)&cw[d2*4];
  float4 wB = *(const float4*)&cw[d2*4+4];
  const u16* base = xzb + (size_t)t*1024 + d2;
  ushort2 v;
  if (l>=3){ v = *(const ushort2*)&base[-3*1024]; acc0 += bf2f(v.x)*wA.x; acc1 += bf2f(v.y)*wB.x; }
  if (l>=2){ v = *(const ushort2*)&base[-2*1024]; acc0 += bf2f(v.x)*wA.y; acc1 += bf2f(v.y)*wB.y; }
  if (l>=1){ v = *(const ushort2*)&base[-1*1024]; acc0 += bf2f(v.x)*wA.z; acc1 += bf2f(v.y)*wB.z; }
  v = *(const ushort2*)&base[0];
  acc0 += bf2f(v.x)*wA.w; acc1 += bf2f(v.y)*wB.w;
  float r0 = acc0 * sigmoidf_(acc0);
  float r1 = acc1 * sigmoidf_(acc1);
  *(unsigned*)&xc_bf[(size_t)t*DI + d2] = cvt_pk_bf16(r0, r1);
}

// ---------------- dt = softplus(dbl[:,:16] @ W_dt + b_dt), wave per token ----------------
__global__ __launch_bounds__(256) void dt_kernel(const float* __restrict__ dbl,
    const float* __restrict__ Wdt, const float* __restrict__ bdt,
    float* __restrict__ dt) {
  __shared__ float sdbl[4][16];
  int wid = threadIdx.x>>6, lane = threadIdx.x&63;
  int token = blockIdx.x*4 + wid;
  if (lane < 16) sdbl[wid][lane] = dbl[(size_t)token*48 + lane];
  __syncthreads();
  float din[16];
#pragma unroll
  for (int k=0;k<16;++k) din[k] = sdbl[wid][k];
#pragma unroll
  for (int r=0;r<8;++r){
    int d = lane + r*64;
    float acc = bdt[d];
#pragma unroll
    for (int k=0;k<16;++k) acc += din[k]*Wdt[k*DI+d];
    float sp = (acc > 20.f) ? acc : log1pf(__expf(acc));
    dt[(size_t)token*DI+d] = sp;
  }
}

// ---------------- chunked selective scan, thread-per-channel ----------------
__global__ __launch_bounds__(512) void scan_p1(const u16* __restrict__ xc_bf,
    const float* __restrict__ dt, const float* __restrict__ dbl,
    const float* __restrict__ A_log, float* __restrict__ Pws, float* __restrict__ Hws) {
  __shared__ float sB[CL][16];
  int d = threadIdx.x;
  int bc = blockIdx.x;          // 0..255
  int b = bc >> 6, c = bc & 63;
  {
    int t = threadIdx.x >> 4, n = threadIdx.x & 15;
    sB[t][n] = dbl[((size_t)b*SEQ + c*CL + t)*48 + DTR + n];
  }
  __syncthreads();
  float An[16];
#pragma unroll
  for (int i=0;i<4;++i){
    float4 a = *(const float4*)&A_log[d*16 + i*4];
    An[i*4+0] = -__expf(a.x); An[i*4+1] = -__expf(a.y);
    An[i*4+2] = -__expf(a.z); An[i*4+3] = -__expf(a.w);
  }
  float h[16] = {};
  float P[16];
#pragma unroll
  for (int n=0;n<16;++n) P[n] = 1.f;
  size_t tok = (size_t)b*SEQ + c*CL;
  for (int t=0;t<CL;++t,++tok){
    float dtv = dt[tok*DI+d];
    float xcv = bf2f(xc_bf[tok*DI+d]);
    float u = dtv*xcv;
    float4 B0 = *(float4*)&sB[t][0];
    float4 B1 = *(float4*)&sB[t][4];
    float4 B2 = *(float4*)&sB[t][8];
    float4 B3 = *(float4*)&sB[t][12];
    float Bv[16] = {B0.x,B0.y,B0.z,B0.w,B1.x,B1.y,B1.z,B1.w,
                    B2.x,B2.y,B2.z,B2.w,B3.x,B3.y,B3.z,B3.w};
#pragma unroll
    for (int n=0;n<16;++n){
      float e = __expf(dtv*An[n]);
      P[n] *= e;
      h[n] = e*h[n] + u*Bv[n];
    }
  }
  size_t base = (((size_t)b*NCH + c)*DI + d)*16;
#pragma unroll
  for (int n=0;n<16;++n){ Pws[base+n] = P[n]; Hws[base+n] = h[n]; }
}

__global__ __launch_bounds__(256) void scan_combine(const float* __restrict__ Pws,
    const float* __restrict__ Hws, float* __restrict__ H0ws) {
  int gid = blockIdx.x*256 + threadIdx.x;  // 0..32767 = (b, d*16+n)
  int b  = gid >> 13;
  int dn = gid & 8191;
  float h0 = 0.f;
#pragma unroll 4
  for (int c=0;c<NCH;++c){
    size_t idx = ((size_t)(b*NCH+c)<<13) + dn;
    H0ws[idx] = h0;
    h0 = Pws[idx]*h0 + Hws[idx];
  }
}

__global__ __launch_bounds__(512) void scan_p2(const u16* __restrict__ xc_bf,
    const float* __restrict__ dt, const float* __restrict__ dbl,
    const float* __restrict__ A_log, const float* __restrict__ Dp,
    const u16* __restrict__ xzb, const float* __restrict__ H0ws,
    u16* __restrict__ ygate_bf) {
  __shared__ float sBC[CL][32];
  int d = threadIdx.x;
  int bc = blockIdx.x;
  int b = bc >> 6, c = bc & 63;
#pragma unroll
  for (int i=0;i<2;++i){
    int idx = i*512 + threadIdx.x;
    int t = idx >> 5, q = idx & 31;
    sBC[t][q] = dbl[((size_t)b*SEQ + c*CL + t)*48 + DTR + q];
  }
  __syncthreads();
  float An[16];
#pragma unroll
  for (int i=0;i<4;++i){
    float4 a = *(const float4*)&A_log[d*16 + i*4];
    An[i*4+0] = -__expf(a.x); An[i*4+1] = -__expf(a.y);
    An[i*4+2] = -__expf(a.z); An[i*4+3] = -__expf(a.w);
  }
  float Dd = Dp[d];
  float h[16];
  size_t base = (((size_t)b*NCH + c)*DI + d)*16;
#pragma unroll
  for (int i=0;i<4;++i){
    float4 h4 = *(const float4*)&H0ws[base + i*4];
    h[i*4+0]=h4.x; h[i*4+1]=h4.y; h[i*4+2]=h4.z; h[i*4+3]=h4.w;
  }
  size_t tok = (size_t)b*SEQ + c*CL;
  for (int t=0;t<CL;++t,++tok){
    float dtv = dt[tok*DI+d];
    float xcv = bf2f(xc_bf[tok*DI+d]);
    float zv  = bf2f(xzb[tok*1024 + DI + d]);
    float u = dtv*xcv;
    float4 B0 = *(float4*)&sBC[t][0];
    float4 B1 = *(float4*)&sBC[t][4];
    float4 B2 = *(float4*)&sBC[t][8];
    float4 B3 = *(float4*)&sBC[t][12];
    float4 C0 = *(float4*)&sBC[t][16];
    float4 C1 = *(float4*)&sBC[t][20];
    float4 C2 = *(float4*)&sBC[t][24];
    float4 C3 = *(float4*)&sBC[t][28];
    float Bv[16] = {B0.x,B0.y,B0.z,B0.w,B1.x,B1.y,B1.z,B1.w,
                    B2.x,B2.y,B2.z,B2.w,B3.x,B3.y,B3.z,B3.w};
    float Cv[16] = {C0.x,C0.y,C0.z,C0.w,C1.x,C1.y,C1.z,C1.w,
                    C2.x,C2.y,C2.z,C2.w,C3.x,C3.y,C3.z,C3.w};
    float y = 0.f;
#pragma unroll
    for (int n=0;n<16;++n){
      float e = __expf(dtv*An[n]);
      h[n] = e*h[n] + u*Bv[n];
      y += h[n]*Cv[n];
    }
    y += xcv*Dd;
    ygate_bf[tok*DI + d] = f2bf(y * (zv*sigmoidf_(zv)));
  }
}

// ---------------- MFMA 32x32 flash attention, P in registers, KV-split 4 ----------------
// grid (16,16,4); 4 waves x 32 q; lane owns q = lane&31 (half-lanes paired).
// S^T = mfma32(K, Q^T); softmax in-lane + shfl_xor(32); P^T B-frag built via
// cvt_pk + shfl_xor(32) exchange (zero LDS for P); O^T += mfma32(V^T, P^T).
__global__ __launch_bounds__(256) void attn_mfma_kernel(const u16* __restrict__ qkvb,
    const u16* __restrict__ vT,
    float* __restrict__ Opart, float* __restrict__ ml) {
  __shared__ u16 lds[8192];   // K [64 key][64 d] @0, V^T [64 d][64 key] @4096 (u16 units)
  int H = blockIdx.x + 16*blockIdx.y + 256*(int)blockIdx.z;
  int cx = H & 7, k = H >> 3;
  int xq = k & 15;
  int G  = cx*8 + (k >> 4);        // 0..63, contiguous per XCD
  int bh = G & 15, s = G >> 4;
  int b = bh>>2, h = bh&3;
  int tid = threadIdx.x;
  int w = tid>>6, l = tid&63;
  int lo32 = l & 31;
  int hi = l >> 5;
  size_t bbase = (size_t)b*SEQ;
  size_t vbase = (size_t)bh*HD*SEQ;
  int q0 = xq*128 + w*32;
  int q = q0 + lo32;

  // Q^T B-fragments: qf[dsl]: Q[q][d = dsl*16 + hi*8 + j], pre-scaled by 0.125*log2e
  bf16x8 qf[4];
#pragma unroll
  for (int dsl=0; dsl<4; ++dsl)
    qf[dsl] = *(const bf16x8*)&qkvb[(bbase + q)*768 + h*HD + dsl*16 + hi*8];

  float m_ = -1e30f, l_ = 0.f;
  f32x16 oacc[2] = {};

  int srow = tid>>3, sg = tid&7;
  int kt0 = s*8;
  bf16x8 kreg[2], vreg[2];

#define LOADT(kt) { \
  kreg[0] = *(const bf16x8*)&qkvb[(bbase + (size_t)(kt)*64 + srow)*768 + 256 + h*HD + sg*8]; \
  kreg[1] = *(const bf16x8*)&qkvb[(bbase + (size_t)(kt)*64 + srow + 32)*768 + 256 + h*HD + sg*8]; \
  vreg[0] = *(const bf16x8*)&vT[vbase + (size_t)srow*SEQ + (kt)*64 + sg*8]; \
  vreg[1] = *(const bf16x8*)&vT[vbase + (size_t)(srow+32)*SEQ + (kt)*64 + sg*8]; }
#define STORET() { \
  *(bf16x8*)&lds[srow*64 + ((sg ^ (srow&7))*8)] = kreg[0]; \
  *(bf16x8*)&lds[(srow+32)*64 + ((sg ^ ((srow+32)&7))*8)] = kreg[1]; \
  *(bf16x8*)&lds[4096 + srow*64 + ((sg ^ (srow&7))*8)] = vreg[0]; \
  *(bf16x8*)&lds[4096 + (srow+32)*64 + ((sg ^ ((srow+32)&7))*8)] = vreg[1]; }
// exchange: pair (X=pk(p[a],p[a+1]) from low key-group, Y=pk(p[a+4],p[a+5]) high group)
// -> s_own (j-low u32), s_oth (j-high u32) per B-frag layout
#define EXCH(X, Y, s_own, s_oth) { \
  unsigned give = (l < 32) ? (Y) : (X); \
  unsigned got = __shfl_xor(give, 32); \
  s_own = (l < 32) ? (X) : got; \
  s_oth = (l < 32) ? got : (Y); }

  LOADT(kt0);
  for (int it=0; it<8; ++it){
    __syncthreads();
    STORET();
    __syncthreads();
    if (it < 7) LOADT(kt0+it+1);

#pragma unroll
    for (int t32=0; t32<2; ++t32){
      // ---- S^T = K · Q^T over d ----
      f32x16 sacc = {0,0,0,0,0,0,0,0,0,0,0,0,0,0,0,0};
      __builtin_amdgcn_s_setprio(1);
#pragma unroll
      for (int dsl=0; dsl<4; ++dsl){
        int row = t32*32 + lo32;
        bf16x8 kf = *(bf16x8*)&lds[row*64 + (((dsl*2 + hi) ^ (row&7))*8)];
        sacc = __builtin_amdgcn_mfma_f32_32x32x16_bf16(kf, qf[dsl], sacc, 0,0,0);
      }
      __builtin_amdgcn_s_setprio(0);

      // ---- softmax (log2 domain), lane pair (l, l^32) shares q ----
      float tm = sacc[0];
#pragma unroll
      for (int r=1;r<16;++r) tm = fmaxf(tm, sacc[r]);
      tm = fmaxf(tm, __shfl_xor(tm, 32));
      if (__any(tm - m_ > 8.f)) {
        float mn = fmaxf(m_, tm);
        float sc = exp2f(m_ - mn);
        m_ = mn;
        l_ *= sc;
#pragma unroll
        for (int r=0;r<16;++r){ oacc[0][r] *= sc; oacc[1][r] *= sc; }
      }
      float p[16];
      float ps = 0.f;
#pragma unroll
      for (int r=0;r<16;++r){ p[r] = exp2f(sacc[r] - m_); ps += p[r]; }
      ps += __shfl_xor(ps, 32);
      l_ += ps;

      // ---- build P^T B-fragments in registers ----
      unsigned A0 = cvt_pk_bf16(p[0],p[1]),  A1 = cvt_pk_bf16(p[2],p[3]);
      unsigned B0 = cvt_pk_bf16(p[4],p[5]),  B1 = cvt_pk_bf16(p[6],p[7]);
      unsigned C0 = cvt_pk_bf16(p[8],p[9]),  C1 = cvt_pk_bf16(p[10],p[11]);
      unsigned D0 = cvt_pk_bf16(p[12],p[13]),D1 = cvt_pk_bf16(p[14],p[15]);
      unsigned s0,s1,s2,s3,s4,s5,s6,s7;
      EXCH(A0,B0,s0,s2); EXCH(A1,B1,s1,s3);
      EXCH(C0,D0,s4,s6); EXCH(C1,D1,s5,s7);
      bf16x8 pf0, pf1;
      ((unsigned*)&pf0)[0]=s0; ((unsigned*)&pf0)[1]=s1; ((unsigned*)&pf0)[2]=s2; ((unsigned*)&pf0)[3]=s3;
      ((unsigned*)&pf1)[0]=s4; ((unsigned*)&pf1)[1]=s5; ((unsigned*)&pf1)[2]=s6; ((unsigned*)&pf1)[3]=s7;

      // ---- O^T += V^T · P^T ----
      __builtin_amdgcn_s_setprio(1);
#pragma unroll
      for (int dtile=0; dtile<2; ++dtile){
        int row = dtile*32 + lo32;
        bf16x8 vf0 = *(bf16x8*)&lds[4096 + row*64 + (((t32*4 + 0 + hi) ^ (row&7))*8)];
        bf16x8 vf1 = *(bf16x8*)&lds[4096 + row*64 + (((t32*4 + 2 + hi) ^ (row&7))*8)];
        oacc[dtile] = __builtin_amdgcn_mfma_f32_32x32x16_bf16(vf0, pf0, oacc[dtile], 0,0,0);
        oacc[dtile] = __builtin_amdgcn_mfma_f32_32x32x16_bf16(vf1, pf1, oacc[dtile], 0,0,0);
      }
      __builtin_amdgcn_s_setprio(0);
    }
  }
#undef LOADT
#undef STORET
#undef EXCH

  // ---- write partials: lane holds O^T[d][q] for its q, d = dtile*32 + 8*rg + 4*hi + {0..3} ----
  int sidx = bh*4 + s;
  size_t rb = ((size_t)sidx*SEQ + q)*64;
#pragma unroll
  for (int dtile=0; dtile<2; ++dtile){
#pragma unroll
    for (int rg=0; rg<4; ++rg){
      float4 v4;
      v4.x = oacc[dtile][rg*4+0];
      v4.y = oacc[dtile][rg*4+1];
      v4.z = oacc[dtile][rg*4+2];
      v4.w = oacc[dtile][rg*4+3];
      *(float4*)&Opart[rb + dtile*32 + rg*8 + 4*hi] = v4;
    }
  }
  if (l < 32){
    ml[((size_t)sidx*SEQ + q)*2    ] = m_;
    ml[((size_t)sidx*SEQ + q)*2 + 1] = l_;
  }
}

// ---------------- merge 4 KV-chunk partials (log2 domain) -> bf16 attn_o ----------------
__global__ __launch_bounds__(256) void attn_merge_kernel(const float* __restrict__ Opart,
    const float* __restrict__ ml, u16* __restrict__ attn_bf) {
  int w = threadIdx.x>>6, lane = threadIdx.x&63;
  int R = blockIdx.x*4 + w;        // 0..32767
  int bh = R>>11, q = R&2047;
  float m[4], lv[4];
#pragma unroll
  for (int s=0;s<4;++s){
    m[s]  = ml[((size_t)(bh*4+s)*SEQ + q)*2];
    lv[s] = ml[((size_t)(bh*4+s)*SEQ + q)*2 + 1];
  }
  float ms = fmaxf(fmaxf(m[0],m[1]),fmaxf(m[2],m[3]));
  float o = 0.f, lsum = 0.f;
#pragma unroll
  for (int s=0;s<4;++s){
    float wsc = exp2f(m[s]-ms);
    lsum += wsc*lv[s];
    o += wsc*Opart[((size_t)(bh*4+s)*SEQ + q)*64 + lane];
  }
  size_t token = (size_t)(bh>>2)*SEQ + q;
  attn_bf[token*DM + (bh&3)*HD + lane] = f2bf(o/lsum);
}

extern "C" void kernel_launch(void* const* d_in, const int* in_sizes, int n_in,
                              void* d_out, int out_size, void* d_ws, size_t ws_size,
                              hipStream_t stream) {
  const float* x      = (const float*)d_in[0];
  const float* ln_g   = (const float*)d_in[1];
  const float* ln_b   = (const float*)d_in[2];
  const float* W_in   = (const float*)d_in[3];
  const float* conv_w = (const float*)d_in[4];
  const float* conv_b = (const float*)d_in[5];
  const float* W_xproj= (const float*)d_in[6];
  const float* W_dt   = (const float*)d_in[7];
  const float* b_dt   = (const float*)d_in[8];
  const float* A_log  = (const float*)d_in[9];
  const float* Dp     = (const float*)d_in[10];
  const float* W_out_m= (const float*)d_in[11];
  const float* W_qkv  = (const float*)d_in[12];
  const float* b_qkv  = (const float*)d_in[13];
  const float* W_o    = (const float*)d_in[14];
  const float* b_o    = (const float*)d_in[15];
  const float* W_gate = (const float*)d_in[16];
  const float* b_gate = (const float*)d_in[17];
  float* out = (float*)d_out;

  float* ws = (float*)d_ws;
  u16*   xn_bf   = (u16*)(ws);                       // 2,097,152 u
  u16*   xzb     = (u16*)(ws + 1048576);             // bf16 xz (region 8.4M f)
  u16*   qkv_bf  = (u16*)(ws + 9437184);             // 6,291,456 u
  u16*   xc_bf   = (u16*)(ws + 12582912);            // 4,194,304 u
  float* dblb    = ws + 16777216;                    //   393,216
  float* dtb     = ws + 17170432;                    // 4,194,304
  u16*   ygate_bf= (u16*)(ws + 21364736);            // 4,194,304 u
  u16*   attn_bf = (u16*)(ws + 23461888);            // 2,097,152 u
  float* catb    = ws + 24510464;                    // 4,194,304
  u16*   catb_bf = (u16*)(ws + 28704768);            // 4,194,304 u
  float* gateb   = ws + 30801920;                    // 2,097,152
  u16*   Wt_all  = (u16*)(ws + 32899072);            //   819,200 u
  // aliases (lifetime-disjoint):
  float* Opart = ws + 1048576;       // attn partials after xzb dead (post scan_p2)
  float* mlb   = (float*)xn_bf;      // after xn_bf dead (post qkv gemm)
  u16*   vTb   = (u16*)gateb;        // 4,194,304 u16 — written by qkv gemm epilogue
  float* Pws   = catb;               // scan summaries before catb written
  float* Hws   = catb + 2097152;
  float* H0ws  = catb + 4194304;

  u16* Wt_in   = Wt_all;             // 1024x256
  u16* Wt_qkv  = Wt_all + 262144;    // 768x256
  u16* Wt_out  = Wt_all + 458752;    // 256x512
  u16* Wt_o    = Wt_all + 589824;    // 256x256
  u16* Wt_gate = Wt_all + 655360;    // 256x512
  u16* Wt_xp   = Wt_all + 786432;    // 64x512 (48 valid + 16 zero rows)

  TcvtArgs ta;
  ta.src[0]=W_in;    ta.dst[0]=Wt_in;   ta.K[0]=256; ta.Nvalid[0]=1024; ta.Npad[0]=1024;
  ta.src[1]=W_qkv;   ta.dst[1]=Wt_qkv;  ta.K[1]=256; ta.Nvalid[1]=768;  ta.Npad[1]=768;
  ta.src[2]=W_out_m; ta.dst[2]=Wt_out;  ta.K[2]=512; ta.Nvalid[2]=256;  ta.Npad[2]=256;
  ta.src[3]=W_o;     ta.dst[3]=Wt_o;    ta.K[3]=256; ta.Nvalid[3]=256;  ta.Npad[3]=256;
  ta.src[4]=W_gate;  ta.dst[4]=Wt_gate; ta.K[4]=512; ta.Nvalid[4]=256;  ta.Npad[4]=256;
  ta.src[5]=W_xproj; ta.dst[5]=Wt_xp;   ta.K[5]=512; ta.Nvalid[5]=48;   ta.Npad[5]=64;
  tcvt_all<<<dim3(8,16,6), 256, 0, stream>>>(ta);

  ln_kernel<<<T_TOK/4, 256, 0, stream>>>(x, ln_g, ln_b, xn_bf);
  gemm_mfma<0><<<dim3(16,64), 256, 0, stream>>>(xn_bf, Wt_in, nullptr, nullptr, xzb, 256, 1024, 1024, 0, 1.f, nullptr, nullptr, nullptr);
  gemm_mfma<3><<<dim3(12,64), 256, 0, stream>>>(xn_bf, Wt_qkv, b_qkv, nullptr, qkv_bf, 256, 768, 768, 256, QSCALE, nullptr, nullptr, vTb);
  conv_kernel<<<T_TOK, 256, 0, stream>>>(xzb, conv_w, conv_b, xc_bf);
  gemm_mfma<0><<<dim3(1,64), 256, 0, stream>>>(xc_bf, Wt_xp, nullptr, dblb, nullptr, 512, 48, 48, 0, 1.f, nullptr, nullptr, nullptr);
  dt_kernel<<<T_TOK/4, 256, 0, stream>>>(dblb, W_dt, b_dt, dtb);
  scan_p1<<<B_SZ*NCH, 512, 0, stream>>>(xc_bf, dtb, dblb, A_log, Pws, Hws);
  scan_combine<<<128, 256, 0, stream>>>(Pws, Hws, H0ws);
  scan_p2<<<B_SZ*NCH, 512, 0, stream>>>(xc_bf, dtb, dblb, A_log, Dp, xzb, H0ws, ygate_bf);
  attn_mfma_kernel<<<dim3(16, 16, 4), 256, 0, stream>>>(qkv_bf, vTb, Opart, mlb);
  attn_merge_kernel<<<8192, 256, 0, stream>>>(Opart, mlb, attn_bf);
  gemm_mfma<0><<<dim3(4,64), 256, 0, stream>>>(ygate_bf, Wt_out, nullptr, catb, catb_bf, 512, 512, 256, 0, 1.f, nullptr, nullptr, nullptr);
  gemm_mfma<0><<<dim3(4,64), 256, 0, stream>>>(attn_bf, Wt_o, b_o, catb+256, catb_bf+256, 256, 512, 256, 0, 1.f, nullptr, nullptr, nullptr);
  gemm_mfma<2><<<dim3(4,64), 256, 0, stream>>>(catb_bf, Wt_gate, b_gate, out, nullptr, 512, 256, 256, 0, 1.f, x, catb, nullptr);
}